// Round 2
// baseline (1986.993 us; speedup 1.0000x reference)
//
#include <hip/hip_runtime.h>
#include <hip/hip_bf16.h>
#include <math.h>

typedef __attribute__((ext_vector_type(8))) short short8;
typedef __attribute__((ext_vector_type(4))) short short4v;
typedef __attribute__((ext_vector_type(4))) float floatx4;

// ---------- type helpers ----------
__device__ __forceinline__ float ldf(const float* p) { return *p; }
__device__ __forceinline__ float ldf(const __hip_bfloat16* p) { return __bfloat162float(*p); }
__device__ __forceinline__ void stf(float* p, float v) { *p = v; }
__device__ __forceinline__ void stf(__hip_bfloat16* p, float v) { *p = __float2bfloat16(v); }
__device__ __forceinline__ float gelu1(float v) {
    return 0.5f * v * (1.f + erff(v * 0.70710678118654752f));
}
__device__ __forceinline__ short f2bf(float f) {
    unsigned int u = __float_as_uint(f);
    unsigned int r = (u + 0x7FFFu + ((u >> 16) & 1u)) >> 16;
    return (short)r;
}
__device__ __forceinline__ void load16bf(const __hip_bfloat16* p, float* o) {
    const uint4* u = (const uint4*)p;
    uint4 w0 = u[0], w1 = u[1];
    unsigned int ws[8] = {w0.x, w0.y, w0.z, w0.w, w1.x, w1.y, w1.z, w1.w};
    #pragma unroll
    for (int i = 0; i < 8; i++) {
        o[2 * i]     = __uint_as_float(ws[i] << 16);
        o[2 * i + 1] = __uint_as_float(ws[i] & 0xFFFF0000u);
    }
}

// ---------- weight pack: W[K,N] f32 -> Wt[N,K] bf16 (batched over grid.z) ----------
__global__ void pack_wt(const float* __restrict__ W, __hip_bfloat16* __restrict__ Wt,
                        int K, int N) {
    __shared__ float tile[32][33];
    long b = blockIdx.z;
    const float* Wb = W + b * K * N;
    __hip_bfloat16* Wtb = Wt + b * K * N;
    int k0 = blockIdx.y * 32, n0 = blockIdx.x * 32;
    int tx = threadIdx.x, ty = threadIdx.y;  // 32 x 8
    #pragma unroll
    for (int i = 0; i < 32; i += 8) {
        int k = k0 + ty + i, n = n0 + tx;
        tile[ty + i][tx] = (k < K && n < N) ? Wb[(long)k * N + n] : 0.f;
    }
    __syncthreads();
    #pragma unroll
    for (int i = 0; i < 32; i += 8) {
        int n = n0 + ty + i, k = k0 + tx;
        if (n < N && k < K) Wtb[(long)n * K + k] = __float2bfloat16(tile[tx][ty + i]);
    }
}

// ---------- MFMA GEMM: C[M,N] = act(A[M,K]f32 @ B + bias) (+ gated skip) ----------
// Bt[N,K] bf16 pre-transposed. N%64==0, K%64==0. Block=128 thr (2 waves),
// BM=128 BN=64 BK=64; wave w covers rows w*64..+63, all 64 cols (4x4 mfma tiles).
template <typename TC>
__global__ __launch_bounds__(128)
void gemm_mfma(const float* __restrict__ A, const __hip_bfloat16* __restrict__ Bt,
               const float* __restrict__ bias, TC* __restrict__ C,
               int M, int N, int K, int act,
               const TC* __restrict__ res, const float* __restrict__ skip_arr, int t) {
    __shared__ short As[128][72];  // +8 pad: 2-way bank alias only (free)
    __shared__ short Bs[64][72];
    int tid = threadIdx.x;
    int row0 = blockIdx.y * 128, col0 = blockIdx.x * 64;
    int wave = tid >> 6, lane = tid & 63;
    int wm = wave * 64;
    int lm = lane & 15, kg = lane >> 4;
    floatx4 acc[4][4];
    #pragma unroll
    for (int i = 0; i < 4; i++)
        #pragma unroll
        for (int j = 0; j < 4; j++) acc[i][j] = floatx4{0.f, 0.f, 0.f, 0.f};

    for (int k0 = 0; k0 < K; k0 += 64) {
        for (int p = 0; p < 16; p++) {
            int q = p * 128 + tid;
            int r = q >> 4, c = (q & 15) * 4;
            int grow = row0 + r;
            float4 v = make_float4(0.f, 0.f, 0.f, 0.f);
            if (grow < M) v = *(const float4*)(A + (long)grow * K + k0 + c);
            short4v s;
            s.x = f2bf(v.x); s.y = f2bf(v.y); s.z = f2bf(v.z); s.w = f2bf(v.w);
            *(short4v*)&As[r][c] = s;
        }
        #pragma unroll
        for (int p = 0; p < 4; p++) {
            int q = p * 128 + tid;
            int r = q >> 3, c = (q & 7) * 8;
            *(short8*)&Bs[r][c] = *(const short8*)(Bt + (long)(col0 + r) * K + k0 + c);
        }
        __syncthreads();
        #pragma unroll
        for (int kk = 0; kk < 2; kk++) {
            int kb = kk * 32 + kg * 8;
            short8 a[4], b[4];
            #pragma unroll
            for (int mt = 0; mt < 4; mt++) a[mt] = *(short8*)&As[wm + mt * 16 + lm][kb];
            #pragma unroll
            for (int nt = 0; nt < 4; nt++) b[nt] = *(short8*)&Bs[nt * 16 + lm][kb];
            #pragma unroll
            for (int mt = 0; mt < 4; mt++)
                #pragma unroll
                for (int nt = 0; nt < 4; nt++)
                    acc[mt][nt] = __builtin_amdgcn_mfma_f32_16x16x32_bf16(
                        a[mt], b[nt], acc[mt][nt], 0, 0, 0);
        }
        __syncthreads();
    }
    float aval = 0.f;
    bool do_res = (res != nullptr);
    if (do_res) { float s = skip_arr[t]; aval = 1.f / (1.f + __expf(-s)); }
    int rg = (lane >> 4) * 4;  // C/D: col=lane&15, row=(lane>>4)*4+reg
    #pragma unroll
    for (int mt = 0; mt < 4; mt++) {
        #pragma unroll
        for (int nt = 0; nt < 4; nt++) {
            int col = col0 + nt * 16 + lm;
            float bsv = bias[col];
            #pragma unroll
            for (int r = 0; r < 4; r++) {
                int row = row0 + wm + mt * 16 + rg + r;
                if (row < M) {
                    float v = acc[mt][nt][r] + bsv;
                    if (act == 1) v = fmaxf(v, 0.f);
                    if (do_res) v = aval * v + (1.f - aval) * ldf(res + (long)row * N + col);
                    stf(C + (long)row * N + col, v);
                }
            }
        }
    }
}

// ---------- small utils ----------
__global__ void fill_u32(unsigned int* __restrict__ p, unsigned int v, int n) {
    int i = blockIdx.x * blockDim.x + threadIdx.x;
    if (i < n) p[i] = v;
}
__global__ void copy_u32(const int* __restrict__ a, int* __restrict__ b, int n) {
    int i = blockIdx.x * blockDim.x + threadIdx.x;
    if (i < n) b[i] = a[i];
}

// ---------- CSR build ----------
__global__ void count_edges(const int* __restrict__ dst, int E, int* __restrict__ counts) {
    int i = blockIdx.x * blockDim.x + threadIdx.x;
    if (i < E) atomicAdd(&counts[dst[i]], 1);
}

// Parallel 3-phase exclusive scan.
__global__ __launch_bounds__(256) void scan_local(const int* __restrict__ counts,
                                                  int* __restrict__ rowptr,
                                                  int* __restrict__ bsums, int n) {
    __shared__ int sh[256];
    int t = threadIdx.x;
    int base = blockIdx.x * 1024;
    int lv[4]; int s = 0;
    #pragma unroll
    for (int q = 0; q < 4; q++) {
        int i = base + t * 4 + q;
        lv[q] = (i < n) ? counts[i] : 0;
        s += lv[q];
    }
    sh[t] = s;
    __syncthreads();
    #pragma unroll
    for (int off = 1; off < 256; off <<= 1) {
        int add = (t >= off) ? sh[t - off] : 0;
        __syncthreads();
        sh[t] += add;
        __syncthreads();
    }
    int excl = sh[t] - s;
    if (t == 255) bsums[blockIdx.x] = sh[255];
    #pragma unroll
    for (int q = 0; q < 4; q++) {
        int i = base + t * 4 + q;
        if (i < n) rowptr[i] = excl;
        excl += lv[q];
    }
}
__global__ __launch_bounds__(256) void scan_bsums(int* __restrict__ bsums, int nb) {
    __shared__ int sh[256];
    int t = threadIdx.x;
    int v = (t < nb) ? bsums[t] : 0;
    sh[t] = v;
    __syncthreads();
    #pragma unroll
    for (int off = 1; off < 256; off <<= 1) {
        int add = (t >= off) ? sh[t - off] : 0;
        __syncthreads();
        sh[t] += add;
        __syncthreads();
    }
    if (t < nb) bsums[t] = sh[t] - v;
    if (t == nb - 1) bsums[nb] = sh[t];
}
__global__ void scan_add(int* __restrict__ rowptr, const int* __restrict__ bsums,
                         int n, int nb) {
    int i = blockIdx.x * blockDim.x + threadIdx.x;
    if (i < n) rowptr[i] += bsums[i >> 10];
    if (i == 0) rowptr[n] = bsums[nb];
}

__global__ void scatter_edges(const int* __restrict__ src, const int* __restrict__ dst, int E,
                              int* __restrict__ cursor, int2* __restrict__ recs,
                              int srow_base, int etl) {
    int i = blockIdx.x * blockDim.x + threadIdx.x;
    if (i >= E) return;
    int pos = atomicAdd(&cursor[dst[i]], 1);
    recs[pos] = make_int2(srow_base + src[i], (etl << 28) | i);
}

// ---------- relation transform ----------
__global__ void rel_transform(const __hip_bfloat16* __restrict__ in, long in_row_off,
                              int in_stride, int nrows, int H, int fout,
                              const float* __restrict__ rel, const float* __restrict__ prel,
                              float scale, __hip_bfloat16* __restrict__ outp) {
    __shared__ float sR[2048];
    int nl = H * 256;
    for (int i = threadIdx.x; i < nl; i += blockDim.x) {
        float f = (prel != nullptr) ? prel[i >> 8] * scale : 1.f;
        sR[i] = rel[i] * f;
    }
    __syncthreads();
    int per = blockDim.x / fout;
    int slot = threadIdx.x / fout;
    int j = threadIdx.x - slot * fout;
    int h = j >> 4;
    const float* rp = sR + h * 256 + (j & 15);
    for (long d = (long)blockIdx.x * per + slot; d < nrows; d += (long)gridDim.x * per) {
        float xv[16];
        load16bf(in + in_row_off + d * in_stride + h * 16, xv);
        float acc = 0.f;
        #pragma unroll
        for (int i = 0; i < 16; i++) acc = fmaf(xv[i], rp[i * 16], acc);
        outp[d * fout + j] = __float2bfloat16(acc);
    }
}

// ---------- scores from precomputed k_rel ----------
__global__ void edge_score_pre(const __hip_bfloat16* __restrict__ krelbuf, int ro,
                               const __hip_bfloat16* __restrict__ Qdst,
                               int stride, int H, int fout,
                               const int* __restrict__ src, const int* __restrict__ dst, int E,
                               float* __restrict__ sc_out) {
    long tid = blockIdx.x * (long)blockDim.x + threadIdx.x;
    if (tid >= (long)E * H) return;
    int e = (int)(tid / H);
    int h = (int)(tid - (long)e * H);
    float kv[16], qv[16];
    load16bf(krelbuf + ((long)ro + src[e]) * fout + h * 16, kv);
    load16bf(Qdst + (long)dst[e] * stride + h * 16, qv);
    float acc = 0.f;
    #pragma unroll
    for (int i = 0; i < 16; i++) acc = fmaf(kv[i], qv[i], acc);
    sc_out[tid] = acc;
}

// ---------- segment softmax: one thread per (dst, head); overwrites scores with alpha ----------
// Removes the 16x-redundant exp work from the gather kernel (alpha depends only on (dst,h),
// but gather threads are per-(dst,channel)). In-place: each score slot belongs to exactly
// one (dst,h) -> no races.
__global__ __launch_bounds__(256)
void edge_alpha(const int2* __restrict__ recs, const int* __restrict__ rowptr,
                int tb, int ndst, int H,
                float* __restrict__ sc, int sb0, int sb1) {
    int per = blockDim.x / H;
    int slot = threadIdx.x / H;
    int h = threadIdx.x - slot * H;
    int d = blockIdx.x * per + slot;
    if (d >= ndst) return;
    int r0 = rowptr[tb + d], r1 = rowptr[tb + d + 1];
    float m = -1e30f, l = 0.f;
    for (int idx = r0; idx < r1; ++idx) {
        int2 rec = recs[idx];
        int etl = rec.y >> 28;
        int ei = rec.y & 0x0FFFFFFF;
        float s = sc[(long)(etl ? sb1 : sb0) + (long)ei * H + h];
        float mn = fmaxf(m, s);
        float r = __expf(m - mn);
        float w = __expf(s - mn);
        l = fmaf(l, r, w);
        m = mn;
    }
    float inv = (l > 0.f) ? 1.f / l : 0.f;
    for (int idx = r0; idx < r1; ++idx) {
        int2 rec = recs[idx];
        int etl = rec.y >> 28;
        int ei = rec.y & 0x0FFFFFFF;
        long pos = (long)(etl ? sb1 : sb0) + (long)ei * H + h;
        sc[pos] = __expf(sc[pos] - m) * inv;
    }
}

// ---------- gather of precomputed v_rel weighted by precomputed alpha ----------
// Pure weighted sum now: no exp/rescale chain -> loads pipeline; 2 independent accumulators.
__global__ void gather_agg_pre(const __hip_bfloat16* __restrict__ vrelbuf, int H, int fout,
                               const int2* __restrict__ recs, const int* __restrict__ rowptr,
                               int tb, int ndst,
                               const float* __restrict__ sc, int sb0, int sb1,
                               int ro0, int ro1, int nb0, int nb1,
                               float* __restrict__ agg) {
    int per = blockDim.x / fout;
    int slot = threadIdx.x / fout;
    int j = threadIdx.x - slot * fout;
    int d = blockIdx.x * per + slot;
    if (d >= ndst) return;
    int h = j >> 4;
    int r0 = rowptr[tb + d], r1 = rowptr[tb + d + 1];
    float acc0 = 0.f, acc1 = 0.f;
    int idx = r0;
    for (; idx + 1 < r1; idx += 2) {
        int2 ra = recs[idx];
        int2 rb = recs[idx + 1];
        int ea = ra.y >> 28, eb = rb.y >> 28;
        float a0 = sc[(long)(ea ? sb1 : sb0) + (long)(ra.y & 0x0FFFFFFF) * H + h];
        float a1 = sc[(long)(eb ? sb1 : sb0) + (long)(rb.y & 0x0FFFFFFF) * H + h];
        long rowa = (ea ? ro1 : ro0) + (long)(ra.x - (ea ? nb1 : nb0));
        long rowb = (eb ? ro1 : ro0) + (long)(rb.x - (eb ? nb1 : nb0));
        float v0 = ldf(vrelbuf + rowa * fout + j);
        float v1 = ldf(vrelbuf + rowb * fout + j);
        acc0 = fmaf(a0, v0, acc0);
        acc1 = fmaf(a1, v1, acc1);
    }
    if (idx < r1) {
        int2 ra = recs[idx];
        int ea = ra.y >> 28;
        float a0 = sc[(long)(ea ? sb1 : sb0) + (long)(ra.y & 0x0FFFFFFF) * H + h];
        long rowa = (ea ? ro1 : ro0) + (long)(ra.x - (ea ? nb1 : nb0));
        acc0 = fmaf(a0, ldf(vrelbuf + rowa * fout + j), acc0);
    }
    agg[(long)d * fout + j] = gelu1(acc0 + acc1);
}

// ---------- orchestration ----------
static const int ET_src[5] = {1, 0, 0, 1, 2};
static const int ET_dst[5] = {0, 0, 1, 2, 1};
static const int ET_E[5]   = {250000, 250000, 200000, 100000, 100000};
static const int NT[3]     = {100000, 50000, 5000};
static const long NPRE[3]  = {0, 100000, 150000};
static const int TB[3]     = {0, 100000, 150000};
static const int NTOT      = 155000;

template <typename TO>
static void hgt_layer_run(hipStream_t stream, const int* const* ei,
                          const float* xs, __hip_bfloat16* kqvB, float* scB,
                          const int* rowptr, const int2* recs, float* aggB,
                          __hip_bfloat16* krelB, __hip_bfloat16* vrelB,
                          const __hip_bfloat16* wt_kqv, const float* kqv_b,
                          const float* krel, const float* vrel, const float* prel,
                          const __hip_bfloat16* wt_out, const float* out_b,
                          const float* skip_arr,
                          int H, int fout, bool do_skip, TO* const* outs) {
    const int F3 = 3 * fout;
    for (int t = 0; t < 3; t++) {
        dim3 grid(F3 / 64, (NT[t] + 127) / 128);
        gemm_mfma<__hip_bfloat16><<<grid, 128, 0, stream>>>(
            xs + NPRE[t] * 128, wt_kqv + (long)t * 128 * F3, kqv_b + t * F3,
            kqvB + NPRE[t] * F3, NT[t], F3, 128, 0,
            (__hip_bfloat16*)nullptr, nullptr, 0);
    }
    for (int t = 0; t < 3; t++) {
        int el[2], ne = 0;
        for (int e = 0; e < 5; e++) if (ET_dst[e] == t) el[ne++] = e;
        long scoff = 0;
        int sb[2] = {0, 0}, ro[2] = {0, 0}, nb[2] = {0, 0};
        int rocur = 0;
        for (int i = 0; i < ne; i++) {
            int e = el[i], ts = ET_src[e];
            int E = ET_E[e];
            long tot = (long)E * H;
            sb[i] = (int)scoff; ro[i] = rocur; nb[i] = (int)NPRE[ts];
            int per = 256 / fout;
            int tg = (NT[ts] + per - 1) / per; if (tg > 2048) tg = 2048;
            rel_transform<<<tg, 256, 0, stream>>>(
                kqvB, NPRE[ts] * F3 + 2 * fout, F3, NT[ts], H, fout,
                vrel + (long)e * H * 256, nullptr, 1.f, vrelB + (long)rocur * fout);
            rel_transform<<<tg, 256, 0, stream>>>(
                kqvB, NPRE[ts] * F3, F3, NT[ts], H, fout,
                krel + (long)e * H * 256, prel + e * H, 0.25f,
                krelB + (long)rocur * fout);
            edge_score_pre<<<(int)((tot + 255) / 256), 256, 0, stream>>>(
                krelB, ro[i], kqvB + NPRE[t] * F3 + fout, F3, H, fout,
                ei[e], ei[e] + E, E, scB + scoff);
            scoff += tot;
            rocur += NT[ts];
        }
        if (ne == 1) { sb[1] = sb[0]; ro[1] = ro[0]; nb[1] = nb[0]; }
        // segment softmax -> alpha (in place over scB)
        int perA = 256 / H;
        edge_alpha<<<(NT[t] + perA - 1) / perA, 256, 0, stream>>>(
            recs, rowptr, TB[t], NT[t], H, scB, sb[0], sb[1]);
        int per = 256 / fout;
        gather_agg_pre<<<(NT[t] + per - 1) / per, 256, 0, stream>>>(
            vrelB, H, fout, recs, rowptr, TB[t], NT[t],
            scB, sb[0], sb[1], ro[0], ro[1], nb[0], nb[1], aggB);
        dim3 grid2(fout / 64, (NT[t] + 127) / 128);
        gemm_mfma<TO><<<grid2, 128, 0, stream>>>(
            aggB, wt_out + (long)t * fout * fout, out_b + t * fout, outs[t],
            NT[t], fout, fout, 0,
            do_skip ? outs[t] : (TO*)nullptr, skip_arr, t);
    }
}

extern "C" void kernel_launch(void* const* d_in, const int* in_sizes, int n_in,
                              void* d_out, int out_size, void* d_ws, size_t ws_size,
                              hipStream_t stream) {
    const float* x_paper  = (const float*)d_in[0];
    const float* x_author = (const float*)d_in[1];
    const float* x_inst   = (const float*)d_in[2];
    const int* ei[5];
    for (int e = 0; e < 5; e++) ei[e] = (const int*)d_in[3 + e];
    const float* lin_w[3] = {(const float*)d_in[8], (const float*)d_in[10], (const float*)d_in[12]};
    const float* lin_b[3] = {(const float*)d_in[9], (const float*)d_in[11], (const float*)d_in[13]};
    const float* kqv_w1 = (const float*)d_in[14];
    const float* kqv_b1 = (const float*)d_in[15];
    const float* krel1  = (const float*)d_in[16];
    const float* vrel1  = (const float*)d_in[17];
    const float* prel1  = (const float*)d_in[18];
    const float* out_w1 = (const float*)d_in[19];
    const float* out_b1 = (const float*)d_in[20];
    const float* skip1  = (const float*)d_in[21];
    const float* kqv_w2 = (const float*)d_in[22];
    const float* kqv_b2 = (const float*)d_in[23];
    const float* krel2  = (const float*)d_in[24];
    const float* vrel2  = (const float*)d_in[25];
    const float* prel2  = (const float*)d_in[26];
    const float* out_w2 = (const float*)d_in[27];
    const float* out_b2 = (const float*)d_in[28];
    const float* skip2  = (const float*)d_in[29];

    // workspace carve (all offsets 16B-aligned); total 351,520,000 B (<= ws, >=352MB per R4)
    char* p = (char*)d_ws;
    float* xs = (float*)p;                      p += 19840000L * 4;
    __hip_bfloat16* kqvB = (__hip_bfloat16*)p;  p += 59520000L * 2;
    float* scB = (float*)p;                     p += 4000000L * 4;
    float* aggB = (float*)p;                    p += 12800000L * 4;
    int* rowptr = (int*)p;                      p += 155008L * 4;
    int* cursor = (int*)p;                      p += 155008L * 4;
    int2* recs = (int2*)p;                      p += 900000L * 8;
    __hip_bfloat16* vrelB = (__hip_bfloat16*)p; p += 19200000L * 2;
    __hip_bfloat16* krelB = (__hip_bfloat16*)p; p += 19200000L * 2;
    __hip_bfloat16* wtA = (__hip_bfloat16*)p;

    __hip_bfloat16* wt_lin[3] = {wtA, wtA + 32768, wtA + 49152};
    __hip_bfloat16* wt_kqv1 = wtA + 57344;
    __hip_bfloat16* wt_out1 = wtA + 204800;
    __hip_bfloat16* wt_kqv2 = wtA + 253952;
    __hip_bfloat16* wt_out2 = wtA + 327680;

    dim3 pb(32, 8);
    pack_wt<<<dim3(4, 8, 1), pb, 0, stream>>>(lin_w[0], wt_lin[0], 256, 128);
    pack_wt<<<dim3(4, 4, 1), pb, 0, stream>>>(lin_w[1], wt_lin[1], 128, 128);
    pack_wt<<<dim3(4, 2, 1), pb, 0, stream>>>(lin_w[2], wt_lin[2], 64, 128);
    pack_wt<<<dim3(12, 4, 3), pb, 0, stream>>>(kqv_w1, wt_kqv1, 128, 384);
    pack_wt<<<dim3(4, 4, 3), pb, 0, stream>>>(out_w1, wt_out1, 128, 128);
    pack_wt<<<dim3(6, 4, 3), pb, 0, stream>>>(kqv_w2, wt_kqv2, 128, 192);
    pack_wt<<<dim3(2, 2, 3), pb, 0, stream>>>(out_w2, wt_out2, 64, 64);

    // input projections (ReLU). N=128 for all; K = 256 / 128 / 64.
    gemm_mfma<float><<<dim3(2, 782), 128, 0, stream>>>(
        x_paper, wt_lin[0], lin_b[0], xs, 100000, 128, 256, 1, (float*)nullptr, nullptr, 0);
    gemm_mfma<float><<<dim3(2, 391), 128, 0, stream>>>(
        x_author, wt_lin[1], lin_b[1], xs + 100000L * 128, 50000, 128, 128, 1,
        (float*)nullptr, nullptr, 0);
    gemm_mfma<float><<<dim3(2, 40), 128, 0, stream>>>(
        x_inst, wt_lin[2], lin_b[2], xs + 150000L * 128, 5000, 128, 64, 1,
        (float*)nullptr, nullptr, 0);

    // CSR build (shared by both layers)
    fill_u32<<<(NTOT + 255) / 256, 256, 0, stream>>>((unsigned int*)cursor, 0u, NTOT);
    for (int e = 0; e < 5; e++)
        count_edges<<<(ET_E[e] + 255) / 256, 256, 0, stream>>>(
            ei[e] + ET_E[e], ET_E[e], cursor + TB[ET_dst[e]]);
    // parallel 3-phase exclusive scan; block-sum scratch aliases aggB (dead here)
    {
        int* bsums = (int*)aggB;
        int nb = (NTOT + 1023) / 1024;  // 152
        scan_local<<<nb, 256, 0, stream>>>(cursor, rowptr, bsums, NTOT);
        scan_bsums<<<1, 256, 0, stream>>>(bsums, nb);
        scan_add<<<(NTOT + 255) / 256, 256, 0, stream>>>(rowptr, bsums, NTOT, nb);
    }
    copy_u32<<<(NTOT + 255) / 256, 256, 0, stream>>>(rowptr, cursor, NTOT);
    static const int ET_ETL[5] = {0, 1, 0, 0, 1};
    for (int e = 0; e < 5; e++)
        scatter_edges<<<(ET_E[e] + 255) / 256, 256, 0, stream>>>(
            ei[e], ei[e] + ET_E[e], ET_E[e], cursor + TB[ET_dst[e]], recs,
            (int)NPRE[ET_src[e]], ET_ETL[e]);

    // layer 1 (output in-place over xs; gated skip fused into out-GEMM)
    float* outs1[3] = {xs, xs + 100000L * 128, xs + 150000L * 128};
    hgt_layer_run<float>(stream, ei, xs, kqvB, scB, rowptr, recs, aggB, krelB, vrelB,
                         wt_kqv1, kqv_b1, krel1, vrel1, prel1, wt_out1, out_b1, skip1,
                         8, 128, true, outs1);

    float* out = (float*)d_out;
    float* outs2[3] = {out, out + 100000L * 64, out + 150000L * 64};
    hgt_layer_run<float>(stream, ei, xs, kqvB, scB, rowptr, recs, aggB, krelB, vrelB,
                         wt_kqv2, kqv_b2, krel2, vrel2, prel2, wt_out2, out_b2, skip2,
                         4, 64, false, outs2);
}

// Round 3
// 1752.536 us; speedup vs baseline: 1.1338x; 1.1338x over previous
//
#include <hip/hip_runtime.h>
#include <hip/hip_bf16.h>
#include <math.h>

typedef __attribute__((ext_vector_type(8))) short short8;
typedef __attribute__((ext_vector_type(4))) short short4v;
typedef __attribute__((ext_vector_type(4))) float floatx4;

// ---------- type helpers ----------
__device__ __forceinline__ float ldf(const float* p) { return *p; }
__device__ __forceinline__ float ldf(const __hip_bfloat16* p) { return __bfloat162float(*p); }
__device__ __forceinline__ void stf(float* p, float v) { *p = v; }
__device__ __forceinline__ void stf(__hip_bfloat16* p, float v) { *p = __float2bfloat16(v); }
__device__ __forceinline__ float gelu1(float v) {
    return 0.5f * v * (1.f + erff(v * 0.70710678118654752f));
}
__device__ __forceinline__ short f2bf(float f) {
    unsigned int u = __float_as_uint(f);
    unsigned int r = (u + 0x7FFFu + ((u >> 16) & 1u)) >> 16;
    return (short)r;
}
__device__ __forceinline__ void load16bf(const __hip_bfloat16* p, float* o) {
    const uint4* u = (const uint4*)p;
    uint4 w0 = u[0], w1 = u[1];
    unsigned int ws[8] = {w0.x, w0.y, w0.z, w0.w, w1.x, w1.y, w1.z, w1.w};
    #pragma unroll
    for (int i = 0; i < 8; i++) {
        o[2 * i]     = __uint_as_float(ws[i] << 16);
        o[2 * i + 1] = __uint_as_float(ws[i] & 0xFFFF0000u);
    }
}

// ---------- weight pack: W[K,N] f32 -> Wt[N,K] bf16 (batched over grid.z) ----------
__global__ void pack_wt(const float* __restrict__ W, __hip_bfloat16* __restrict__ Wt,
                        int K, int N) {
    __shared__ float tile[32][33];
    long b = blockIdx.z;
    const float* Wb = W + b * K * N;
    __hip_bfloat16* Wtb = Wt + b * K * N;
    int k0 = blockIdx.y * 32, n0 = blockIdx.x * 32;
    int tx = threadIdx.x, ty = threadIdx.y;  // 32 x 8
    #pragma unroll
    for (int i = 0; i < 32; i += 8) {
        int k = k0 + ty + i, n = n0 + tx;
        tile[ty + i][tx] = (k < K && n < N) ? Wb[(long)k * N + n] : 0.f;
    }
    __syncthreads();
    #pragma unroll
    for (int i = 0; i < 32; i += 8) {
        int n = n0 + ty + i, k = k0 + tx;
        if (n < N && k < K) Wtb[(long)n * K + k] = __float2bfloat16(tile[tx][ty + i]);
    }
}

// ---------- MFMA GEMM (generic K, used only for K=256 paper projection) ----------
template <typename TC>
__global__ __launch_bounds__(128)
void gemm_mfma(const float* __restrict__ A, const __hip_bfloat16* __restrict__ Bt,
               const float* __restrict__ bias, TC* __restrict__ C,
               int M, int N, int K, int act,
               const TC* __restrict__ res, const float* __restrict__ skip_arr, int t) {
    __shared__ short As[128][72];
    __shared__ short Bs[64][72];
    int tid = threadIdx.x;
    int row0 = blockIdx.y * 128, col0 = blockIdx.x * 64;
    int wave = tid >> 6, lane = tid & 63;
    int wm = wave * 64;
    int lm = lane & 15, kg = lane >> 4;
    floatx4 acc[4][4];
    #pragma unroll
    for (int i = 0; i < 4; i++)
        #pragma unroll
        for (int j = 0; j < 4; j++) acc[i][j] = floatx4{0.f, 0.f, 0.f, 0.f};

    for (int k0 = 0; k0 < K; k0 += 64) {
        for (int p = 0; p < 16; p++) {
            int q = p * 128 + tid;
            int r = q >> 4, c = (q & 15) * 4;
            int grow = row0 + r;
            float4 v = make_float4(0.f, 0.f, 0.f, 0.f);
            if (grow < M) v = *(const float4*)(A + (long)grow * K + k0 + c);
            short4v s;
            s.x = f2bf(v.x); s.y = f2bf(v.y); s.z = f2bf(v.z); s.w = f2bf(v.w);
            *(short4v*)&As[r][c] = s;
        }
        #pragma unroll
        for (int p = 0; p < 4; p++) {
            int q = p * 128 + tid;
            int r = q >> 3, c = (q & 7) * 8;
            *(short8*)&Bs[r][c] = *(const short8*)(Bt + (long)(col0 + r) * K + k0 + c);
        }
        __syncthreads();
        #pragma unroll
        for (int kk = 0; kk < 2; kk++) {
            int kb = kk * 32 + kg * 8;
            short8 a[4], b[4];
            #pragma unroll
            for (int mt = 0; mt < 4; mt++) a[mt] = *(short8*)&As[wm + mt * 16 + lm][kb];
            #pragma unroll
            for (int nt = 0; nt < 4; nt++) b[nt] = *(short8*)&Bs[nt * 16 + lm][kb];
            #pragma unroll
            for (int mt = 0; mt < 4; mt++)
                #pragma unroll
                for (int nt = 0; nt < 4; nt++)
                    acc[mt][nt] = __builtin_amdgcn_mfma_f32_16x16x32_bf16(
                        a[mt], b[nt], acc[mt][nt], 0, 0, 0);
        }
        __syncthreads();
    }
    float aval = 0.f;
    bool do_res = (res != nullptr);
    if (do_res) { float s = skip_arr[t]; aval = 1.f / (1.f + __expf(-s)); }
    int rg = (lane >> 4) * 4;
    #pragma unroll
    for (int mt = 0; mt < 4; mt++) {
        #pragma unroll
        for (int nt = 0; nt < 4; nt++) {
            int col = col0 + nt * 16 + lm;
            float bsv = bias[col];
            #pragma unroll
            for (int r = 0; r < 4; r++) {
                int row = row0 + wm + mt * 16 + rg + r;
                if (row < M) {
                    float v = acc[mt][nt][r] + bsv;
                    if (act == 1) v = fmaxf(v, 0.f);
                    if (do_res) v = aval * v + (1.f - aval) * ldf(res + (long)row * N + col);
                    stf(C + (long)row * N + col, v);
                }
            }
        }
    }
}

// ---------- MFMA GEMM, full-K A staged once, N-loop inside block (K<=128) ----------
// Eliminates the grid.x-fold A re-fetch that made the kqv GEMM HBM-traffic-bound
// (FETCH 150MB vs 51MB ideal). Block = 256 thr (4 waves); BM=128; A-tile [128][K]
// staged once; loop N in chunks of 64. Wave w: rows (w>>1)*64, cols (w&1)*32.
template <typename TC, int K>
__global__ __launch_bounds__(256)
void gemm_mfma_nl(const float* __restrict__ A, const __hip_bfloat16* __restrict__ Bt,
                  const float* __restrict__ bias, TC* __restrict__ C,
                  int M, int N, int act,
                  const TC* __restrict__ res, const float* __restrict__ skip_arr, int t) {
    constexpr int KP = K + 8;
    __shared__ short As[128][KP];   // K=128: 34.8KB
    __shared__ short Bs[64][KP];    // K=128: 17.4KB  -> 52KB total, 3 blocks/CU
    int tid = threadIdx.x;
    int row0 = blockIdx.x * 128;
    int wave = tid >> 6, lane = tid & 63;
    int rw = (wave >> 1) * 64, cw = (wave & 1) * 32;
    int lm = lane & 15, kg = lane >> 4;
    // stage A fully (f32 -> bf16)
    constexpr int KD4 = K / 4;
    #pragma unroll
    for (int p = 0; p < 128 * KD4 / 256; p++) {
        int q = p * 256 + tid;
        int r = q / KD4, c = (q % KD4) * 4;
        int grow = row0 + r;
        float4 v = make_float4(0.f, 0.f, 0.f, 0.f);
        if (grow < M) v = *(const float4*)(A + (long)grow * K + c);
        short4v s;
        s.x = f2bf(v.x); s.y = f2bf(v.y); s.z = f2bf(v.z); s.w = f2bf(v.w);
        *(short4v*)&As[r][c] = s;
    }
    float aval = 0.f;
    bool do_res = (res != nullptr);
    if (do_res) { float s = skip_arr[t]; aval = 1.f / (1.f + __expf(-s)); }
    int rg = (lane >> 4) * 4;
    constexpr int KD8 = K / 8;

    for (int n0 = 0; n0 < N; n0 += 64) {
        #pragma unroll
        for (int p = 0; p < 64 * KD8 / 256; p++) {
            int q = p * 256 + tid;
            int r = q / KD8, c = (q % KD8) * 8;
            *(short8*)&Bs[r][c] = *(const short8*)(Bt + (long)(n0 + r) * K + c);
        }
        __syncthreads();  // covers A-stage (first iter) + B-stage
        floatx4 acc[4][2];
        #pragma unroll
        for (int i = 0; i < 4; i++)
            #pragma unroll
            for (int j = 0; j < 2; j++) acc[i][j] = floatx4{0.f, 0.f, 0.f, 0.f};
        #pragma unroll
        for (int kk = 0; kk < K / 32; kk++) {
            int kb = kk * 32 + kg * 8;
            short8 a[4], b[2];
            #pragma unroll
            for (int mt = 0; mt < 4; mt++) a[mt] = *(short8*)&As[rw + mt * 16 + lm][kb];
            #pragma unroll
            for (int nt = 0; nt < 2; nt++) b[nt] = *(short8*)&Bs[cw + nt * 16 + lm][kb];
            #pragma unroll
            for (int mt = 0; mt < 4; mt++)
                #pragma unroll
                for (int nt = 0; nt < 2; nt++)
                    acc[mt][nt] = __builtin_amdgcn_mfma_f32_16x16x32_bf16(
                        a[mt], b[nt], acc[mt][nt], 0, 0, 0);
        }
        #pragma unroll
        for (int mt = 0; mt < 4; mt++) {
            #pragma unroll
            for (int nt = 0; nt < 2; nt++) {
                int col = n0 + cw + nt * 16 + lm;
                float bsv = bias[col];
                #pragma unroll
                for (int r = 0; r < 4; r++) {
                    int row = row0 + rw + mt * 16 + rg + r;
                    if (row < M) {
                        float v = acc[mt][nt][r] + bsv;
                        if (act == 1) v = fmaxf(v, 0.f);
                        if (do_res) v = aval * v + (1.f - aval) * ldf(res + (long)row * N + col);
                        stf(C + (long)row * N + col, v);
                    }
                }
            }
        }
        __syncthreads();  // Bs reused next chunk
    }
}

// ---------- small utils ----------
__global__ void fill_u32(unsigned int* __restrict__ p, unsigned int v, int n) {
    int i = blockIdx.x * blockDim.x + threadIdx.x;
    if (i < n) p[i] = v;
}
__global__ void copy_u32(const int* __restrict__ a, int* __restrict__ b, int n) {
    int i = blockIdx.x * blockDim.x + threadIdx.x;
    if (i < n) b[i] = a[i];
}

// ---------- CSR build ----------
__global__ void count_edges(const int* __restrict__ dst, int E, int* __restrict__ counts) {
    int i = blockIdx.x * blockDim.x + threadIdx.x;
    if (i < E) atomicAdd(&counts[dst[i]], 1);
}

__global__ __launch_bounds__(256) void scan_local(const int* __restrict__ counts,
                                                  int* __restrict__ rowptr,
                                                  int* __restrict__ bsums, int n) {
    __shared__ int sh[256];
    int t = threadIdx.x;
    int base = blockIdx.x * 1024;
    int lv[4]; int s = 0;
    #pragma unroll
    for (int q = 0; q < 4; q++) {
        int i = base + t * 4 + q;
        lv[q] = (i < n) ? counts[i] : 0;
        s += lv[q];
    }
    sh[t] = s;
    __syncthreads();
    #pragma unroll
    for (int off = 1; off < 256; off <<= 1) {
        int add = (t >= off) ? sh[t - off] : 0;
        __syncthreads();
        sh[t] += add;
        __syncthreads();
    }
    int excl = sh[t] - s;
    if (t == 255) bsums[blockIdx.x] = sh[255];
    #pragma unroll
    for (int q = 0; q < 4; q++) {
        int i = base + t * 4 + q;
        if (i < n) rowptr[i] = excl;
        excl += lv[q];
    }
}
__global__ __launch_bounds__(256) void scan_bsums(int* __restrict__ bsums, int nb) {
    __shared__ int sh[256];
    int t = threadIdx.x;
    int v = (t < nb) ? bsums[t] : 0;
    sh[t] = v;
    __syncthreads();
    #pragma unroll
    for (int off = 1; off < 256; off <<= 1) {
        int add = (t >= off) ? sh[t - off] : 0;
        __syncthreads();
        sh[t] += add;
        __syncthreads();
    }
    if (t < nb) bsums[t] = sh[t] - v;
    if (t == nb - 1) bsums[nb] = sh[t];
}
__global__ void scan_add(int* __restrict__ rowptr, const int* __restrict__ bsums,
                         int n, int nb) {
    int i = blockIdx.x * blockDim.x + threadIdx.x;
    if (i < n) rowptr[i] += bsums[i >> 10];
    if (i == 0) rowptr[n] = bsums[nb];
}

__global__ void scatter_edges(const int* __restrict__ src, const int* __restrict__ dst, int E,
                              int* __restrict__ cursor, int2* __restrict__ recs,
                              int srow_base, int etl) {
    int i = blockIdx.x * blockDim.x + threadIdx.x;
    if (i >= E) return;
    int pos = atomicAdd(&cursor[dst[i]], 1);
    recs[pos] = make_int2(srow_base + src[i], (etl << 28) | i);
}

// ---------- relation transform ----------
__global__ void rel_transform(const __hip_bfloat16* __restrict__ in, long in_row_off,
                              int in_stride, int nrows, int H, int fout,
                              const float* __restrict__ rel, const float* __restrict__ prel,
                              float scale, __hip_bfloat16* __restrict__ outp) {
    __shared__ float sR[2048];
    int nl = H * 256;
    for (int i = threadIdx.x; i < nl; i += blockDim.x) {
        float f = (prel != nullptr) ? prel[i >> 8] * scale : 1.f;
        sR[i] = rel[i] * f;
    }
    __syncthreads();
    int per = blockDim.x / fout;
    int slot = threadIdx.x / fout;
    int j = threadIdx.x - slot * fout;
    int h = j >> 4;
    const float* rp = sR + h * 256 + (j & 15);
    for (long d = (long)blockIdx.x * per + slot; d < nrows; d += (long)gridDim.x * per) {
        float xv[16];
        load16bf(in + in_row_off + d * in_stride + h * 16, xv);
        float acc = 0.f;
        #pragma unroll
        for (int i = 0; i < 16; i++) acc = fmaf(xv[i], rp[i * 16], acc);
        outp[d * fout + j] = __float2bfloat16(acc);
    }
}

// ---------- scores from precomputed k_rel ----------
__global__ void edge_score_pre(const __hip_bfloat16* __restrict__ krelbuf, int ro,
                               const __hip_bfloat16* __restrict__ Qdst,
                               int stride, int H, int fout,
                               const int* __restrict__ src, const int* __restrict__ dst, int E,
                               float* __restrict__ sc_out) {
    long tid = blockIdx.x * (long)blockDim.x + threadIdx.x;
    if (tid >= (long)E * H) return;
    int e = (int)(tid / H);
    int h = (int)(tid - (long)e * H);
    float kv[16], qv[16];
    load16bf(krelbuf + ((long)ro + src[e]) * fout + h * 16, kv);
    load16bf(Qdst + (long)dst[e] * stride + h * 16, qv);
    float acc = 0.f;
    #pragma unroll
    for (int i = 0; i < 16; i++) acc = fmaf(kv[i], qv[i], acc);
    sc_out[tid] = acc;
}

// ---------- segment softmax stats: single pass, one thread per (dst, head) ----------
// Emits (m, 1/l) per (dst,h); gather computes alpha = exp(s-m)/l inline (exp is
// trans-pipe cheap; the loop-carried rescale chain is what we keep out of gather).
__global__ __launch_bounds__(256)
void edge_alpha(const int2* __restrict__ recs, const int* __restrict__ rowptr,
                int tb, int ndst, int H,
                const float* __restrict__ sc, int sb0, int sb1,
                float2* __restrict__ ml) {
    int per = blockDim.x / H;
    int slot = threadIdx.x / H;
    int h = threadIdx.x - slot * H;
    int d = blockIdx.x * per + slot;
    if (d >= ndst) return;
    int r0 = rowptr[tb + d], r1 = rowptr[tb + d + 1];
    float m = -1e30f, l = 0.f;
    for (int idx = r0; idx < r1; ++idx) {
        int2 rec = recs[idx];
        int etl = rec.y >> 28;
        int ei = rec.y & 0x0FFFFFFF;
        float s = sc[(long)(etl ? sb1 : sb0) + (long)ei * H + h];
        float mn = fmaxf(m, s);
        float r = __expf(m - mn);
        float w = __expf(s - mn);
        l = fmaf(l, r, w);
        m = mn;
    }
    float inv = (l > 0.f) ? 1.f / l : 0.f;
    ml[(long)d * H + h] = make_float2(m, inv);
}

// ---------- gather of precomputed v_rel weighted by alpha = exp(s-m)*inv ----------
__global__ void gather_agg_pre(const __hip_bfloat16* __restrict__ vrelbuf, int H, int fout,
                               const int2* __restrict__ recs, const int* __restrict__ rowptr,
                               int tb, int ndst,
                               const float* __restrict__ sc, int sb0, int sb1,
                               int ro0, int ro1, int nb0, int nb1,
                               const float2* __restrict__ ml,
                               float* __restrict__ agg) {
    int per = blockDim.x / fout;
    int slot = threadIdx.x / fout;
    int j = threadIdx.x - slot * fout;
    int d = blockIdx.x * per + slot;
    if (d >= ndst) return;
    int h = j >> 4;
    float2 mh = ml[(long)d * H + h];
    int r0 = rowptr[tb + d], r1 = rowptr[tb + d + 1];
    float acc0 = 0.f, acc1 = 0.f;
    int idx = r0;
    for (; idx + 1 < r1; idx += 2) {
        int2 ra = recs[idx];
        int2 rb = recs[idx + 1];
        int ea = ra.y >> 28, eb = rb.y >> 28;
        float s0 = sc[(long)(ea ? sb1 : sb0) + (long)(ra.y & 0x0FFFFFFF) * H + h];
        float s1 = sc[(long)(eb ? sb1 : sb0) + (long)(rb.y & 0x0FFFFFFF) * H + h];
        long rowa = (ea ? ro1 : ro0) + (long)(ra.x - (ea ? nb1 : nb0));
        long rowb = (eb ? ro1 : ro0) + (long)(rb.x - (eb ? nb1 : nb0));
        float v0 = ldf(vrelbuf + rowa * fout + j);
        float v1 = ldf(vrelbuf + rowb * fout + j);
        acc0 = fmaf(__expf(s0 - mh.x) * mh.y, v0, acc0);
        acc1 = fmaf(__expf(s1 - mh.x) * mh.y, v1, acc1);
    }
    if (idx < r1) {
        int2 ra = recs[idx];
        int ea = ra.y >> 28;
        float s0 = sc[(long)(ea ? sb1 : sb0) + (long)(ra.y & 0x0FFFFFFF) * H + h];
        long rowa = (ea ? ro1 : ro0) + (long)(ra.x - (ea ? nb1 : nb0));
        acc0 = fmaf(__expf(s0 - mh.x) * mh.y, ldf(vrelbuf + rowa * fout + j), acc0);
    }
    agg[(long)d * fout + j] = gelu1(acc0 + acc1);
}

// ---------- orchestration ----------
static const int ET_src[5] = {1, 0, 0, 1, 2};
static const int ET_dst[5] = {0, 0, 1, 2, 1};
static const int ET_E[5]   = {250000, 250000, 200000, 100000, 100000};
static const int NT[3]     = {100000, 50000, 5000};
static const long NPRE[3]  = {0, 100000, 150000};
static const int TB[3]     = {0, 100000, 150000};
static const int NTOT      = 155000;

template <typename TO>
static void hgt_layer_run(hipStream_t stream, const int* const* ei,
                          const float* xs, __hip_bfloat16* kqvB, float* scB,
                          const int* rowptr, const int2* recs, float* aggB,
                          __hip_bfloat16* krelB, __hip_bfloat16* vrelB,
                          const __hip_bfloat16* wt_kqv, const float* kqv_b,
                          const float* krel, const float* vrel, const float* prel,
                          const __hip_bfloat16* wt_out, const float* out_b,
                          const float* skip_arr,
                          int H, int fout, bool do_skip, TO* const* outs) {
    const int F3 = 3 * fout;
    for (int t = 0; t < 3; t++) {
        int gb = (NT[t] + 127) / 128;
        gemm_mfma_nl<__hip_bfloat16, 128><<<gb, 256, 0, stream>>>(
            xs + NPRE[t] * 128, wt_kqv + (long)t * 128 * F3, kqv_b + t * F3,
            kqvB + NPRE[t] * F3, NT[t], F3, 0,
            (__hip_bfloat16*)nullptr, nullptr, 0);
    }
    for (int t = 0; t < 3; t++) {
        int el[2], ne = 0;
        for (int e = 0; e < 5; e++) if (ET_dst[e] == t) el[ne++] = e;
        long scoff = 0;
        int sb[2] = {0, 0}, ro[2] = {0, 0}, nb[2] = {0, 0};
        int rocur = 0;
        for (int i = 0; i < ne; i++) {
            int e = el[i], ts = ET_src[e];
            int E = ET_E[e];
            long tot = (long)E * H;
            sb[i] = (int)scoff; ro[i] = rocur; nb[i] = (int)NPRE[ts];
            int per = 256 / fout;
            int tg = (NT[ts] + per - 1) / per; if (tg > 2048) tg = 2048;
            rel_transform<<<tg, 256, 0, stream>>>(
                kqvB, NPRE[ts] * F3 + 2 * fout, F3, NT[ts], H, fout,
                vrel + (long)e * H * 256, nullptr, 1.f, vrelB + (long)rocur * fout);
            rel_transform<<<tg, 256, 0, stream>>>(
                kqvB, NPRE[ts] * F3, F3, NT[ts], H, fout,
                krel + (long)e * H * 256, prel + e * H, 0.25f,
                krelB + (long)rocur * fout);
            edge_score_pre<<<(int)((tot + 255) / 256), 256, 0, stream>>>(
                krelB, ro[i], kqvB + NPRE[t] * F3 + fout, F3, H, fout,
                ei[e], ei[e] + E, E, scB + scoff);
            scoff += tot;
            rocur += NT[ts];
        }
        if (ne == 1) { sb[1] = sb[0]; ro[1] = ro[0]; nb[1] = nb[0]; }
        // (m, 1/l) per (dst,h); buffer aliases krelB (dead after edge_score_pre)
        float2* ml = (float2*)krelB;
        int perA = 256 / H;
        edge_alpha<<<(NT[t] + perA - 1) / perA, 256, 0, stream>>>(
            recs, rowptr, TB[t], NT[t], H, scB, sb[0], sb[1], ml);
        int per = 256 / fout;
        gather_agg_pre<<<(NT[t] + per - 1) / per, 256, 0, stream>>>(
            vrelB, H, fout, recs, rowptr, TB[t], NT[t],
            scB, sb[0], sb[1], ro[0], ro[1], nb[0], nb[1], ml, aggB);
        int gb2 = (NT[t] + 127) / 128;
        if (fout == 128)
            gemm_mfma_nl<TO, 128><<<gb2, 256, 0, stream>>>(
                aggB, wt_out + (long)t * fout * fout, out_b + t * fout, outs[t],
                NT[t], fout, 0, do_skip ? outs[t] : (TO*)nullptr, skip_arr, t);
        else
            gemm_mfma_nl<TO, 64><<<gb2, 256, 0, stream>>>(
                aggB, wt_out + (long)t * fout * fout, out_b + t * fout, outs[t],
                NT[t], fout, 0, do_skip ? outs[t] : (TO*)nullptr, skip_arr, t);
    }
}

extern "C" void kernel_launch(void* const* d_in, const int* in_sizes, int n_in,
                              void* d_out, int out_size, void* d_ws, size_t ws_size,
                              hipStream_t stream) {
    const float* x_paper  = (const float*)d_in[0];
    const float* x_author = (const float*)d_in[1];
    const float* x_inst   = (const float*)d_in[2];
    const int* ei[5];
    for (int e = 0; e < 5; e++) ei[e] = (const int*)d_in[3 + e];
    const float* lin_w[3] = {(const float*)d_in[8], (const float*)d_in[10], (const float*)d_in[12]};
    const float* lin_b[3] = {(const float*)d_in[9], (const float*)d_in[11], (const float*)d_in[13]};
    const float* kqv_w1 = (const float*)d_in[14];
    const float* kqv_b1 = (const float*)d_in[15];
    const float* krel1  = (const float*)d_in[16];
    const float* vrel1  = (const float*)d_in[17];
    const float* prel1  = (const float*)d_in[18];
    const float* out_w1 = (const float*)d_in[19];
    const float* out_b1 = (const float*)d_in[20];
    const float* skip1  = (const float*)d_in[21];
    const float* kqv_w2 = (const float*)d_in[22];
    const float* kqv_b2 = (const float*)d_in[23];
    const float* krel2  = (const float*)d_in[24];
    const float* vrel2  = (const float*)d_in[25];
    const float* prel2  = (const float*)d_in[26];
    const float* out_w2 = (const float*)d_in[27];
    const float* out_b2 = (const float*)d_in[28];
    const float* skip2  = (const float*)d_in[29];

    // workspace carve (all offsets 16B-aligned); total 351,520,000 B
    char* p = (char*)d_ws;
    float* xs = (float*)p;                      p += 19840000L * 4;
    __hip_bfloat16* kqvB = (__hip_bfloat16*)p;  p += 59520000L * 2;
    float* scB = (float*)p;                     p += 4000000L * 4;
    float* aggB = (float*)p;                    p += 12800000L * 4;
    int* rowptr = (int*)p;                      p += 155008L * 4;
    int* cursor = (int*)p;                      p += 155008L * 4;
    int2* recs = (int2*)p;                      p += 900000L * 8;
    __hip_bfloat16* vrelB = (__hip_bfloat16*)p; p += 19200000L * 2;
    __hip_bfloat16* krelB = (__hip_bfloat16*)p; p += 19200000L * 2;
    __hip_bfloat16* wtA = (__hip_bfloat16*)p;

    __hip_bfloat16* wt_lin[3] = {wtA, wtA + 32768, wtA + 49152};
    __hip_bfloat16* wt_kqv1 = wtA + 57344;
    __hip_bfloat16* wt_out1 = wtA + 204800;
    __hip_bfloat16* wt_kqv2 = wtA + 253952;
    __hip_bfloat16* wt_out2 = wtA + 327680;

    dim3 pb(32, 8);
    pack_wt<<<dim3(4, 8, 1), pb, 0, stream>>>(lin_w[0], wt_lin[0], 256, 128);
    pack_wt<<<dim3(4, 4, 1), pb, 0, stream>>>(lin_w[1], wt_lin[1], 128, 128);
    pack_wt<<<dim3(4, 2, 1), pb, 0, stream>>>(lin_w[2], wt_lin[2], 64, 128);
    pack_wt<<<dim3(12, 4, 3), pb, 0, stream>>>(kqv_w1, wt_kqv1, 128, 384);
    pack_wt<<<dim3(4, 4, 3), pb, 0, stream>>>(out_w1, wt_out1, 128, 128);
    pack_wt<<<dim3(6, 4, 3), pb, 0, stream>>>(kqv_w2, wt_kqv2, 128, 192);
    pack_wt<<<dim3(2, 2, 3), pb, 0, stream>>>(out_w2, wt_out2, 64, 64);

    // input projections (ReLU). N=128; paper K=256 keeps generic kernel.
    gemm_mfma<float><<<dim3(2, 782), 128, 0, stream>>>(
        x_paper, wt_lin[0], lin_b[0], xs, 100000, 128, 256, 1, (float*)nullptr, nullptr, 0);
    gemm_mfma_nl<float, 128><<<391, 256, 0, stream>>>(
        x_author, wt_lin[1], lin_b[1], xs + 100000L * 128, 50000, 128, 1,
        (float*)nullptr, nullptr, 0);
    gemm_mfma_nl<float, 64><<<40, 256, 0, stream>>>(
        x_inst, wt_lin[2], lin_b[2], xs + 150000L * 128, 5000, 128, 1,
        (float*)nullptr, nullptr, 0);

    // CSR build (shared by both layers)
    fill_u32<<<(NTOT + 255) / 256, 256, 0, stream>>>((unsigned int*)cursor, 0u, NTOT);
    for (int e = 0; e < 5; e++)
        count_edges<<<(ET_E[e] + 255) / 256, 256, 0, stream>>>(
            ei[e] + ET_E[e], ET_E[e], cursor + TB[ET_dst[e]]);
    {
        int* bsums = (int*)aggB;
        int nb = (NTOT + 1023) / 1024;  // 152
        scan_local<<<nb, 256, 0, stream>>>(cursor, rowptr, bsums, NTOT);
        scan_bsums<<<1, 256, 0, stream>>>(bsums, nb);
        scan_add<<<(NTOT + 255) / 256, 256, 0, stream>>>(rowptr, bsums, NTOT, nb);
    }
    copy_u32<<<(NTOT + 255) / 256, 256, 0, stream>>>(rowptr, cursor, NTOT);
    static const int ET_ETL[5] = {0, 1, 0, 0, 1};
    for (int e = 0; e < 5; e++)
        scatter_edges<<<(ET_E[e] + 255) / 256, 256, 0, stream>>>(
            ei[e], ei[e] + ET_E[e], ET_E[e], cursor + TB[ET_dst[e]], recs,
            (int)NPRE[ET_src[e]], ET_ETL[e]);

    // layer 1 (output in-place over xs; gated skip fused into out-GEMM)
    float* outs1[3] = {xs, xs + 100000L * 128, xs + 150000L * 128};
    hgt_layer_run<float>(stream, ei, xs, kqvB, scB, rowptr, recs, aggB, krelB, vrelB,
                         wt_kqv1, kqv_b1, krel1, vrel1, prel1, wt_out1, out_b1, skip1,
                         8, 128, true, outs1);

    float* out = (float*)d_out;
    float* outs2[3] = {out, out + 100000L * 64, out + 150000L * 64};
    hgt_layer_run<float>(stream, ei, xs, kqvB, scB, rowptr, recs, aggB, krelB, vrelB,
                         wt_kqv2, kqv_b2, krel2, vrel2, prel2, wt_out2, out_b2, skip2,
                         4, 64, false, outs2);
}

// Round 4
// 1706.096 us; speedup vs baseline: 1.1646x; 1.0272x over previous
//
#include <hip/hip_runtime.h>
#include <hip/hip_bf16.h>
#include <math.h>

typedef __attribute__((ext_vector_type(8))) short short8;
typedef __attribute__((ext_vector_type(4))) short short4v;
typedef __attribute__((ext_vector_type(4))) float floatx4;

// ---------- type helpers ----------
__device__ __forceinline__ float ldf(const float* p) { return *p; }
__device__ __forceinline__ float ldf(const __hip_bfloat16* p) { return __bfloat162float(*p); }
__device__ __forceinline__ void stf(float* p, float v) { *p = v; }
__device__ __forceinline__ void stf(__hip_bfloat16* p, float v) { *p = __float2bfloat16(v); }
__device__ __forceinline__ float gelu1(float v) {
    return 0.5f * v * (1.f + erff(v * 0.70710678118654752f));
}
__device__ __forceinline__ short f2bf(float f) {
    unsigned int u = __float_as_uint(f);
    unsigned int r = (u + 0x7FFFu + ((u >> 16) & 1u)) >> 16;
    return (short)r;
}
__device__ __forceinline__ void load16bf(const __hip_bfloat16* p, float* o) {
    const uint4* u = (const uint4*)p;
    uint4 w0 = u[0], w1 = u[1];
    unsigned int ws[8] = {w0.x, w0.y, w0.z, w0.w, w1.x, w1.y, w1.z, w1.w};
    #pragma unroll
    for (int i = 0; i < 8; i++) {
        o[2 * i]     = __uint_as_float(ws[i] << 16);
        o[2 * i + 1] = __uint_as_float(ws[i] & 0xFFFF0000u);
    }
}

// ---------- weight pack: W[K,N] f32 -> Wt[N,K] bf16 (batched over grid.z) ----------
__global__ void pack_wt(const float* __restrict__ W, __hip_bfloat16* __restrict__ Wt,
                        int K, int N) {
    __shared__ float tile[32][33];
    long b = blockIdx.z;
    const float* Wb = W + b * K * N;
    __hip_bfloat16* Wtb = Wt + b * K * N;
    int k0 = blockIdx.y * 32, n0 = blockIdx.x * 32;
    int tx = threadIdx.x, ty = threadIdx.y;  // 32 x 8
    #pragma unroll
    for (int i = 0; i < 32; i += 8) {
        int k = k0 + ty + i, n = n0 + tx;
        tile[ty + i][tx] = (k < K && n < N) ? Wb[(long)k * N + n] : 0.f;
    }
    __syncthreads();
    #pragma unroll
    for (int i = 0; i < 32; i += 8) {
        int n = n0 + ty + i, k = k0 + tx;
        if (n < N && k < K) Wtb[(long)n * K + k] = __float2bfloat16(tile[tx][ty + i]);
    }
}

// ---------- paper projection: M x 128 = A[M,256] @ Bt[128,256], ReLU ----------
// 256 thr (4 waves), BM=128, BN=128 (full N -> A fetched exactly once, no grid.x),
// BK=64. Wave w: rows (w>>1)*64, cols (w&1)*64, 4x4 mfma frags. LDS 36.9KB ->
// 4 blocks/CU = 16 waves/CU (3x the old 2-wave kernel); grid 782 fully resident.
__global__ __launch_bounds__(256)
void gemm_mfma_k256(const float* __restrict__ A, const __hip_bfloat16* __restrict__ Bt,
                    const float* __restrict__ bias, float* __restrict__ C, int M) {
    __shared__ short As[128][72];
    __shared__ short Bs[128][72];
    int tid = threadIdx.x;
    int row0 = blockIdx.x * 128;
    int wave = tid >> 6, lane = tid & 63;
    int rw = (wave >> 1) * 64, cw = (wave & 1) * 64;
    int lm = lane & 15, kg = lane >> 4;
    floatx4 acc[4][4];
    #pragma unroll
    for (int i = 0; i < 4; i++)
        #pragma unroll
        for (int j = 0; j < 4; j++) acc[i][j] = floatx4{0.f, 0.f, 0.f, 0.f};

    for (int k0 = 0; k0 < 256; k0 += 64) {
        #pragma unroll
        for (int p = 0; p < 8; p++) {
            int q = p * 256 + tid;
            int r = q >> 4, c = (q & 15) * 4;
            int grow = row0 + r;
            float4 v = make_float4(0.f, 0.f, 0.f, 0.f);
            if (grow < M) v = *(const float4*)(A + (long)grow * 256 + k0 + c);
            short4v s;
            s.x = f2bf(v.x); s.y = f2bf(v.y); s.z = f2bf(v.z); s.w = f2bf(v.w);
            *(short4v*)&As[r][c] = s;
        }
        #pragma unroll
        for (int p = 0; p < 4; p++) {
            int q = p * 256 + tid;
            int r = q >> 3, c = (q & 7) * 8;
            *(short8*)&Bs[r][c] = *(const short8*)(Bt + (long)r * 256 + k0 + c);
        }
        __syncthreads();
        #pragma unroll
        for (int kk = 0; kk < 2; kk++) {
            int kb = kk * 32 + kg * 8;
            short8 a[4], b[4];
            #pragma unroll
            for (int mt = 0; mt < 4; mt++) a[mt] = *(short8*)&As[rw + mt * 16 + lm][kb];
            #pragma unroll
            for (int nt = 0; nt < 4; nt++) b[nt] = *(short8*)&Bs[cw + nt * 16 + lm][kb];
            #pragma unroll
            for (int mt = 0; mt < 4; mt++)
                #pragma unroll
                for (int nt = 0; nt < 4; nt++)
                    acc[mt][nt] = __builtin_amdgcn_mfma_f32_16x16x32_bf16(
                        a[mt], b[nt], acc[mt][nt], 0, 0, 0);
        }
        __syncthreads();
    }
    int rg = (lane >> 4) * 4;
    #pragma unroll
    for (int mt = 0; mt < 4; mt++) {
        #pragma unroll
        for (int nt = 0; nt < 4; nt++) {
            int col = cw + nt * 16 + lm;
            float bsv = bias[col];
            #pragma unroll
            for (int r = 0; r < 4; r++) {
                int row = row0 + rw + mt * 16 + rg + r;
                if (row < M) C[(long)row * 128 + col] = fmaxf(acc[mt][nt][r] + bsv, 0.f);
            }
        }
    }
}

// ---------- MFMA GEMM, full-K A staged once, N-loop inside block (K<=128) ----------
template <typename TC, int K>
__global__ __launch_bounds__(256)
void gemm_mfma_nl(const float* __restrict__ A, const __hip_bfloat16* __restrict__ Bt,
                  const float* __restrict__ bias, TC* __restrict__ C,
                  int M, int N, int act,
                  const TC* __restrict__ res, const float* __restrict__ skip_arr, int t) {
    constexpr int KP = K + 8;
    __shared__ short As[128][KP];
    __shared__ short Bs[64][KP];
    int tid = threadIdx.x;
    int row0 = blockIdx.x * 128;
    int wave = tid >> 6, lane = tid & 63;
    int rw = (wave >> 1) * 64, cw = (wave & 1) * 32;
    int lm = lane & 15, kg = lane >> 4;
    constexpr int KD4 = K / 4;
    #pragma unroll
    for (int p = 0; p < 128 * KD4 / 256; p++) {
        int q = p * 256 + tid;
        int r = q / KD4, c = (q % KD4) * 4;
        int grow = row0 + r;
        float4 v = make_float4(0.f, 0.f, 0.f, 0.f);
        if (grow < M) v = *(const float4*)(A + (long)grow * K + c);
        short4v s;
        s.x = f2bf(v.x); s.y = f2bf(v.y); s.z = f2bf(v.z); s.w = f2bf(v.w);
        *(short4v*)&As[r][c] = s;
    }
    float aval = 0.f;
    bool do_res = (res != nullptr);
    if (do_res) { float s = skip_arr[t]; aval = 1.f / (1.f + __expf(-s)); }
    int rg = (lane >> 4) * 4;
    constexpr int KD8 = K / 8;

    for (int n0 = 0; n0 < N; n0 += 64) {
        #pragma unroll
        for (int p = 0; p < 64 * KD8 / 256; p++) {
            int q = p * 256 + tid;
            int r = q / KD8, c = (q % KD8) * 8;
            *(short8*)&Bs[r][c] = *(const short8*)(Bt + (long)(n0 + r) * K + c);
        }
        __syncthreads();
        floatx4 acc[4][2];
        #pragma unroll
        for (int i = 0; i < 4; i++)
            #pragma unroll
            for (int j = 0; j < 2; j++) acc[i][j] = floatx4{0.f, 0.f, 0.f, 0.f};
        #pragma unroll
        for (int kk = 0; kk < K / 32; kk++) {
            int kb = kk * 32 + kg * 8;
            short8 a[4], b[2];
            #pragma unroll
            for (int mt = 0; mt < 4; mt++) a[mt] = *(short8*)&As[rw + mt * 16 + lm][kb];
            #pragma unroll
            for (int nt = 0; nt < 2; nt++) b[nt] = *(short8*)&Bs[cw + nt * 16 + lm][kb];
            #pragma unroll
            for (int mt = 0; mt < 4; mt++)
                #pragma unroll
                for (int nt = 0; nt < 2; nt++)
                    acc[mt][nt] = __builtin_amdgcn_mfma_f32_16x16x32_bf16(
                        a[mt], b[nt], acc[mt][nt], 0, 0, 0);
        }
        #pragma unroll
        for (int mt = 0; mt < 4; mt++) {
            #pragma unroll
            for (int nt = 0; nt < 2; nt++) {
                int col = n0 + cw + nt * 16 + lm;
                float bsv = bias[col];
                #pragma unroll
                for (int r = 0; r < 4; r++) {
                    int row = row0 + rw + mt * 16 + rg + r;
                    if (row < M) {
                        float v = acc[mt][nt][r] + bsv;
                        if (act == 1) v = fmaxf(v, 0.f);
                        if (do_res) v = aval * v + (1.f - aval) * ldf(res + (long)row * N + col);
                        stf(C + (long)row * N + col, v);
                    }
                }
            }
        }
        __syncthreads();
    }
}

// ---------- small utils ----------
__global__ void fill_u32(unsigned int* __restrict__ p, unsigned int v, int n) {
    int i = blockIdx.x * blockDim.x + threadIdx.x;
    if (i < n) p[i] = v;
}
__global__ void copy_u32(const int* __restrict__ a, int* __restrict__ b, int n) {
    int i = blockIdx.x * blockDim.x + threadIdx.x;
    if (i < n) b[i] = a[i];
}

// ---------- CSR build ----------
__global__ void count_edges(const int* __restrict__ dst, int E, int* __restrict__ counts) {
    int i = blockIdx.x * blockDim.x + threadIdx.x;
    if (i < E) atomicAdd(&counts[dst[i]], 1);
}

__global__ __launch_bounds__(256) void scan_local(const int* __restrict__ counts,
                                                  int* __restrict__ rowptr,
                                                  int* __restrict__ bsums, int n) {
    __shared__ int sh[256];
    int t = threadIdx.x;
    int base = blockIdx.x * 1024;
    int lv[4]; int s = 0;
    #pragma unroll
    for (int q = 0; q < 4; q++) {
        int i = base + t * 4 + q;
        lv[q] = (i < n) ? counts[i] : 0;
        s += lv[q];
    }
    sh[t] = s;
    __syncthreads();
    #pragma unroll
    for (int off = 1; off < 256; off <<= 1) {
        int add = (t >= off) ? sh[t - off] : 0;
        __syncthreads();
        sh[t] += add;
        __syncthreads();
    }
    int excl = sh[t] - s;
    if (t == 255) bsums[blockIdx.x] = sh[255];
    #pragma unroll
    for (int q = 0; q < 4; q++) {
        int i = base + t * 4 + q;
        if (i < n) rowptr[i] = excl;
        excl += lv[q];
    }
}
__global__ __launch_bounds__(256) void scan_bsums(int* __restrict__ bsums, int nb) {
    __shared__ int sh[256];
    int t = threadIdx.x;
    int v = (t < nb) ? bsums[t] : 0;
    sh[t] = v;
    __syncthreads();
    #pragma unroll
    for (int off = 1; off < 256; off <<= 1) {
        int add = (t >= off) ? sh[t - off] : 0;
        __syncthreads();
        sh[t] += add;
        __syncthreads();
    }
    if (t < nb) bsums[t] = sh[t] - v;
    if (t == nb - 1) bsums[nb] = sh[t];
}
__global__ void scan_add(int* __restrict__ rowptr, const int* __restrict__ bsums,
                         int n, int nb) {
    int i = blockIdx.x * blockDim.x + threadIdx.x;
    if (i < n) rowptr[i] += bsums[i >> 10];
    if (i == 0) rowptr[n] = bsums[nb];
}

__global__ void scatter_edges(const int* __restrict__ src, const int* __restrict__ dst, int E,
                              int* __restrict__ cursor, int2* __restrict__ recs,
                              int srow_base, int etl) {
    int i = blockIdx.x * blockDim.x + threadIdx.x;
    if (i >= E) return;
    int pos = atomicAdd(&cursor[dst[i]], 1);
    recs[pos] = make_int2(srow_base + src[i], (etl << 28) | i);
}

// ---------- relation transform ----------
__global__ void rel_transform(const __hip_bfloat16* __restrict__ in, long in_row_off,
                              int in_stride, int nrows, int H, int fout,
                              const float* __restrict__ rel, const float* __restrict__ prel,
                              float scale, __hip_bfloat16* __restrict__ outp) {
    __shared__ float sR[2048];
    int nl = H * 256;
    for (int i = threadIdx.x; i < nl; i += blockDim.x) {
        float f = (prel != nullptr) ? prel[i >> 8] * scale : 1.f;
        sR[i] = rel[i] * f;
    }
    __syncthreads();
    int per = blockDim.x / fout;
    int slot = threadIdx.x / fout;
    int j = threadIdx.x - slot * fout;
    int h = j >> 4;
    const float* rp = sR + h * 256 + (j & 15);
    for (long d = (long)blockIdx.x * per + slot; d < nrows; d += (long)gridDim.x * per) {
        float xv[16];
        load16bf(in + in_row_off + d * in_stride + h * 16, xv);
        float acc = 0.f;
        #pragma unroll
        for (int i = 0; i < 16; i++) acc = fmaf(xv[i], rp[i * 16], acc);
        outp[d * fout + j] = __float2bfloat16(acc);
    }
}

// ---------- scores from precomputed k_rel ----------
__global__ void edge_score_pre(const __hip_bfloat16* __restrict__ krelbuf, int ro,
                               const __hip_bfloat16* __restrict__ Qdst,
                               int stride, int H, int fout,
                               const int* __restrict__ src, const int* __restrict__ dst, int E,
                               float* __restrict__ sc_out) {
    long tid = blockIdx.x * (long)blockDim.x + threadIdx.x;
    if (tid >= (long)E * H) return;
    int e = (int)(tid / H);
    int h = (int)(tid - (long)e * H);
    float kv[16], qv[16];
    load16bf(krelbuf + ((long)ro + src[e]) * fout + h * 16, kv);
    load16bf(Qdst + (long)dst[e] * stride + h * 16, qv);
    float acc = 0.f;
    #pragma unroll
    for (int i = 0; i < 16; i++) acc = fmaf(kv[i], qv[i], acc);
    sc_out[tid] = acc;
}

// ---------- segment softmax stats: single pass, one thread per (dst, head) ----------
__global__ __launch_bounds__(256)
void edge_alpha(const int2* __restrict__ recs, const int* __restrict__ rowptr,
                int tb, int ndst, int H,
                const float* __restrict__ sc, int sb0, int sb1,
                float2* __restrict__ ml) {
    int per = blockDim.x / H;
    int slot = threadIdx.x / H;
    int h = threadIdx.x - slot * H;
    int d = blockIdx.x * per + slot;
    if (d >= ndst) return;
    int r0 = rowptr[tb + d], r1 = rowptr[tb + d + 1];
    float m = -1e30f, l = 0.f;
    for (int idx = r0; idx < r1; ++idx) {
        int2 rec = recs[idx];
        int etl = rec.y >> 28;
        int ei = rec.y & 0x0FFFFFFF;
        float s = sc[(long)(etl ? sb1 : sb0) + (long)ei * H + h];
        float mn = fmaxf(m, s);
        float r = __expf(m - mn);
        float w = __expf(s - mn);
        l = fmaf(l, r, w);
        m = mn;
    }
    float inv = (l > 0.f) ? 1.f / l : 0.f;
    ml[(long)d * H + h] = make_float2(m, inv);
}

// ---------- gather of precomputed v_rel weighted by alpha = exp(s-m)*inv ----------
__global__ void gather_agg_pre(const __hip_bfloat16* __restrict__ vrelbuf, int H, int fout,
                               const int2* __restrict__ recs, const int* __restrict__ rowptr,
                               int tb, int ndst,
                               const float* __restrict__ sc, int sb0, int sb1,
                               int ro0, int ro1, int nb0, int nb1,
                               const float2* __restrict__ ml,
                               float* __restrict__ agg) {
    int per = blockDim.x / fout;
    int slot = threadIdx.x / fout;
    int j = threadIdx.x - slot * fout;
    int d = blockIdx.x * per + slot;
    if (d >= ndst) return;
    int h = j >> 4;
    float2 mh = ml[(long)d * H + h];
    int r0 = rowptr[tb + d], r1 = rowptr[tb + d + 1];
    float acc0 = 0.f, acc1 = 0.f;
    int idx = r0;
    for (; idx + 1 < r1; idx += 2) {
        int2 ra = recs[idx];
        int2 rb = recs[idx + 1];
        int ea = ra.y >> 28, eb = rb.y >> 28;
        float s0 = sc[(long)(ea ? sb1 : sb0) + (long)(ra.y & 0x0FFFFFFF) * H + h];
        float s1 = sc[(long)(eb ? sb1 : sb0) + (long)(rb.y & 0x0FFFFFFF) * H + h];
        long rowa = (ea ? ro1 : ro0) + (long)(ra.x - (ea ? nb1 : nb0));
        long rowb = (eb ? ro1 : ro0) + (long)(rb.x - (eb ? nb1 : nb0));
        float v0 = ldf(vrelbuf + rowa * fout + j);
        float v1 = ldf(vrelbuf + rowb * fout + j);
        acc0 = fmaf(__expf(s0 - mh.x) * mh.y, v0, acc0);
        acc1 = fmaf(__expf(s1 - mh.x) * mh.y, v1, acc1);
    }
    if (idx < r1) {
        int2 ra = recs[idx];
        int ea = ra.y >> 28;
        float s0 = sc[(long)(ea ? sb1 : sb0) + (long)(ra.y & 0x0FFFFFFF) * H + h];
        long rowa = (ea ? ro1 : ro0) + (long)(ra.x - (ea ? nb1 : nb0));
        acc0 = fmaf(__expf(s0 - mh.x) * mh.y, ldf(vrelbuf + rowa * fout + j), acc0);
    }
    agg[(long)d * fout + j] = gelu1(acc0 + acc1);
}

// ---------- orchestration ----------
static const int ET_src[5] = {1, 0, 0, 1, 2};
static const int ET_dst[5] = {0, 0, 1, 2, 1};
static const int ET_E[5]   = {250000, 250000, 200000, 100000, 100000};
static const int NT[3]     = {100000, 50000, 5000};
static const long NPRE[3]  = {0, 100000, 150000};
static const int TB[3]     = {0, 100000, 150000};
static const int NTOT      = 155000;

template <typename TO>
static void hgt_layer_run(hipStream_t stream, const int* const* ei,
                          const float* xs, __hip_bfloat16* kqvB, float* scB,
                          const int* rowptr, const int2* recs, float* aggB,
                          __hip_bfloat16* krelB, __hip_bfloat16* vrelB,
                          const __hip_bfloat16* wt_kqv, const float* kqv_b,
                          const float* krel, const float* vrel, const float* prel,
                          const __hip_bfloat16* wt_out, const float* out_b,
                          const float* skip_arr,
                          int H, int fout, bool do_skip, TO* const* outs) {
    const int F3 = 3 * fout;
    for (int t = 0; t < 3; t++) {
        int gb = (NT[t] + 127) / 128;
        gemm_mfma_nl<__hip_bfloat16, 128><<<gb, 256, 0, stream>>>(
            xs + NPRE[t] * 128, wt_kqv + (long)t * 128 * F3, kqv_b + t * F3,
            kqvB + NPRE[t] * F3, NT[t], F3, 0,
            (__hip_bfloat16*)nullptr, nullptr, 0);
    }
    for (int t = 0; t < 3; t++) {
        int el[2], ne = 0;
        for (int e = 0; e < 5; e++) if (ET_dst[e] == t) el[ne++] = e;
        long scoff = 0;
        int sb[2] = {0, 0}, ro[2] = {0, 0}, nb[2] = {0, 0};
        int rocur = 0;
        for (int i = 0; i < ne; i++) {
            int e = el[i], ts = ET_src[e];
            int E = ET_E[e];
            long tot = (long)E * H;
            sb[i] = (int)scoff; ro[i] = rocur; nb[i] = (int)NPRE[ts];
            int per = 256 / fout;
            int tg = (NT[ts] + per - 1) / per; if (tg > 2048) tg = 2048;
            rel_transform<<<tg, 256, 0, stream>>>(
                kqvB, NPRE[ts] * F3 + 2 * fout, F3, NT[ts], H, fout,
                vrel + (long)e * H * 256, nullptr, 1.f, vrelB + (long)rocur * fout);
            rel_transform<<<tg, 256, 0, stream>>>(
                kqvB, NPRE[ts] * F3, F3, NT[ts], H, fout,
                krel + (long)e * H * 256, prel + e * H, 0.25f,
                krelB + (long)rocur * fout);
            edge_score_pre<<<(int)((tot + 255) / 256), 256, 0, stream>>>(
                krelB, ro[i], kqvB + NPRE[t] * F3 + fout, F3, H, fout,
                ei[e], ei[e] + E, E, scB + scoff);
            scoff += tot;
            rocur += NT[ts];
        }
        if (ne == 1) { sb[1] = sb[0]; ro[1] = ro[0]; nb[1] = nb[0]; }
        float2* ml = (float2*)krelB;
        int perA = 256 / H;
        edge_alpha<<<(NT[t] + perA - 1) / perA, 256, 0, stream>>>(
            recs, rowptr, TB[t], NT[t], H, scB, sb[0], sb[1], ml);
        int per = 256 / fout;
        gather_agg_pre<<<(NT[t] + per - 1) / per, 256, 0, stream>>>(
            vrelB, H, fout, recs, rowptr, TB[t], NT[t],
            scB, sb[0], sb[1], ro[0], ro[1], nb[0], nb[1], ml, aggB);
        int gb2 = (NT[t] + 127) / 128;
        if (fout == 128)
            gemm_mfma_nl<TO, 128><<<gb2, 256, 0, stream>>>(
                aggB, wt_out + (long)t * fout * fout, out_b + t * fout, outs[t],
                NT[t], fout, 0, do_skip ? outs[t] : (TO*)nullptr, skip_arr, t);
        else
            gemm_mfma_nl<TO, 64><<<gb2, 256, 0, stream>>>(
                aggB, wt_out + (long)t * fout * fout, out_b + t * fout, outs[t],
                NT[t], fout, 0, do_skip ? outs[t] : (TO*)nullptr, skip_arr, t);
    }
}

extern "C" void kernel_launch(void* const* d_in, const int* in_sizes, int n_in,
                              void* d_out, int out_size, void* d_ws, size_t ws_size,
                              hipStream_t stream) {
    const float* x_paper  = (const float*)d_in[0];
    const float* x_author = (const float*)d_in[1];
    const float* x_inst   = (const float*)d_in[2];
    const int* ei[5];
    for (int e = 0; e < 5; e++) ei[e] = (const int*)d_in[3 + e];
    const float* lin_w[3] = {(const float*)d_in[8], (const float*)d_in[10], (const float*)d_in[12]};
    const float* lin_b[3] = {(const float*)d_in[9], (const float*)d_in[11], (const float*)d_in[13]};
    const float* kqv_w1 = (const float*)d_in[14];
    const float* kqv_b1 = (const float*)d_in[15];
    const float* krel1  = (const float*)d_in[16];
    const float* vrel1  = (const float*)d_in[17];
    const float* prel1  = (const float*)d_in[18];
    const float* out_w1 = (const float*)d_in[19];
    const float* out_b1 = (const float*)d_in[20];
    const float* skip1  = (const float*)d_in[21];
    const float* kqv_w2 = (const float*)d_in[22];
    const float* kqv_b2 = (const float*)d_in[23];
    const float* krel2  = (const float*)d_in[24];
    const float* vrel2  = (const float*)d_in[25];
    const float* prel2  = (const float*)d_in[26];
    const float* out_w2 = (const float*)d_in[27];
    const float* out_b2 = (const float*)d_in[28];
    const float* skip2  = (const float*)d_in[29];

    // workspace carve (all offsets 16B-aligned); total 351,520,000 B
    char* p = (char*)d_ws;
    float* xs = (float*)p;                      p += 19840000L * 4;
    __hip_bfloat16* kqvB = (__hip_bfloat16*)p;  p += 59520000L * 2;
    float* scB = (float*)p;                     p += 4000000L * 4;
    float* aggB = (float*)p;                    p += 12800000L * 4;
    int* rowptr = (int*)p;                      p += 155008L * 4;
    int* cursor = (int*)p;                      p += 155008L * 4;
    int2* recs = (int2*)p;                      p += 900000L * 8;
    __hip_bfloat16* vrelB = (__hip_bfloat16*)p; p += 19200000L * 2;
    __hip_bfloat16* krelB = (__hip_bfloat16*)p; p += 19200000L * 2;
    __hip_bfloat16* wtA = (__hip_bfloat16*)p;

    __hip_bfloat16* wt_lin[3] = {wtA, wtA + 32768, wtA + 49152};
    __hip_bfloat16* wt_kqv1 = wtA + 57344;
    __hip_bfloat16* wt_out1 = wtA + 204800;
    __hip_bfloat16* wt_kqv2 = wtA + 253952;
    __hip_bfloat16* wt_out2 = wtA + 327680;

    dim3 pb(32, 8);
    pack_wt<<<dim3(4, 8, 1), pb, 0, stream>>>(lin_w[0], wt_lin[0], 256, 128);
    pack_wt<<<dim3(4, 4, 1), pb, 0, stream>>>(lin_w[1], wt_lin[1], 128, 128);
    pack_wt<<<dim3(4, 2, 1), pb, 0, stream>>>(lin_w[2], wt_lin[2], 64, 128);
    pack_wt<<<dim3(12, 4, 3), pb, 0, stream>>>(kqv_w1, wt_kqv1, 128, 384);
    pack_wt<<<dim3(4, 4, 3), pb, 0, stream>>>(out_w1, wt_out1, 128, 128);
    pack_wt<<<dim3(6, 4, 3), pb, 0, stream>>>(kqv_w2, wt_kqv2, 128, 192);
    pack_wt<<<dim3(2, 2, 3), pb, 0, stream>>>(out_w2, wt_out2, 64, 64);

    // input projections (ReLU). N=128; paper uses dedicated K=256 BN=128 kernel.
    gemm_mfma_k256<<<782, 256, 0, stream>>>(x_paper, wt_lin[0], lin_b[0], xs, 100000);
    gemm_mfma_nl<float, 128><<<391, 256, 0, stream>>>(
        x_author, wt_lin[1], lin_b[1], xs + 100000L * 128, 50000, 128, 1,
        (float*)nullptr, nullptr, 0);
    gemm_mfma_nl<float, 64><<<40, 256, 0, stream>>>(
        x_inst, wt_lin[2], lin_b[2], xs + 150000L * 128, 5000, 128, 1,
        (float*)nullptr, nullptr, 0);

    // CSR build (shared by both layers)
    fill_u32<<<(NTOT + 255) / 256, 256, 0, stream>>>((unsigned int*)cursor, 0u, NTOT);
    for (int e = 0; e < 5; e++)
        count_edges<<<(ET_E[e] + 255) / 256, 256, 0, stream>>>(
            ei[e] + ET_E[e], ET_E[e], cursor + TB[ET_dst[e]]);
    {
        int* bsums = (int*)aggB;
        int nb = (NTOT + 1023) / 1024;  // 152
        scan_local<<<nb, 256, 0, stream>>>(cursor, rowptr, bsums, NTOT);
        scan_bsums<<<1, 256, 0, stream>>>(bsums, nb);
        scan_add<<<(NTOT + 255) / 256, 256, 0, stream>>>(rowptr, bsums, NTOT, nb);
    }
    copy_u32<<<(NTOT + 255) / 256, 256, 0, stream>>>(rowptr, cursor, NTOT);
    static const int ET_ETL[5] = {0, 1, 0, 0, 1};
    for (int e = 0; e < 5; e++)
        scatter_edges<<<(ET_E[e] + 255) / 256, 256, 0, stream>>>(
            ei[e], ei[e] + ET_E[e], ET_E[e], cursor + TB[ET_dst[e]], recs,
            (int)NPRE[ET_src[e]], ET_ETL[e]);

    // layer 1 (output in-place over xs; gated skip fused into out-GEMM)
    float* outs1[3] = {xs, xs + 100000L * 128, xs + 150000L * 128};
    hgt_layer_run<float>(stream, ei, xs, kqvB, scB, rowptr, recs, aggB, krelB, vrelB,
                         wt_kqv1, kqv_b1, krel1, vrel1, prel1, wt_out1, out_b1, skip1,
                         8, 128, true, outs1);

    float* out = (float*)d_out;
    float* outs2[3] = {out, out + 100000L * 64, out + 150000L * 64};
    hgt_layer_run<float>(stream, ei, xs, kqvB, scB, rowptr, recs, aggB, krelB, vrelB,
                         wt_kqv2, kqv_b2, krel2, vrel2, prel2, wt_out2, out_b2, skip2,
                         4, 64, false, outs2);
}

// Round 5
// 1483.141 us; speedup vs baseline: 1.3397x; 1.1503x over previous
//
#include <hip/hip_runtime.h>
#include <hip/hip_bf16.h>
#include <math.h>

typedef __attribute__((ext_vector_type(8))) short short8;
typedef __attribute__((ext_vector_type(4))) short short4v;
typedef __attribute__((ext_vector_type(4))) float floatx4;

// ---------- type helpers ----------
__device__ __forceinline__ float ldf(const float* p) { return *p; }
__device__ __forceinline__ float ldf(const __hip_bfloat16* p) { return __bfloat162float(*p); }
__device__ __forceinline__ void stf(float* p, float v) { *p = v; }
__device__ __forceinline__ void stf(__hip_bfloat16* p, float v) { *p = __float2bfloat16(v); }
__device__ __forceinline__ float gelu1(float v) {
    return 0.5f * v * (1.f + erff(v * 0.70710678118654752f));
}
__device__ __forceinline__ short f2bf(float f) {
    unsigned int u = __float_as_uint(f);
    unsigned int r = (u + 0x7FFFu + ((u >> 16) & 1u)) >> 16;
    return (short)r;
}
__device__ __forceinline__ float bflo(unsigned int u) { return __uint_as_float(u << 16); }
__device__ __forceinline__ float bfhi(unsigned int u) { return __uint_as_float(u & 0xFFFF0000u); }
__device__ __forceinline__ void load16bf(const __hip_bfloat16* p, float* o) {
    const uint4* u = (const uint4*)p;
    uint4 w0 = u[0], w1 = u[1];
    unsigned int ws[8] = {w0.x, w0.y, w0.z, w0.w, w1.x, w1.y, w1.z, w1.w};
    #pragma unroll
    for (int i = 0; i < 8; i++) {
        o[2 * i]     = bflo(ws[i]);
        o[2 * i + 1] = bfhi(ws[i]);
    }
}

// ---------- weight pack: W[K,N] f32 -> Wt[N,K] bf16 (batched over grid.z) ----------
__global__ void pack_wt(const float* __restrict__ W, __hip_bfloat16* __restrict__ Wt,
                        int K, int N) {
    __shared__ float tile[32][33];
    long b = blockIdx.z;
    const float* Wb = W + b * K * N;
    __hip_bfloat16* Wtb = Wt + b * K * N;
    int k0 = blockIdx.y * 32, n0 = blockIdx.x * 32;
    int tx = threadIdx.x, ty = threadIdx.y;  // 32 x 8
    #pragma unroll
    for (int i = 0; i < 32; i += 8) {
        int k = k0 + ty + i, n = n0 + tx;
        tile[ty + i][tx] = (k < K && n < N) ? Wb[(long)k * N + n] : 0.f;
    }
    __syncthreads();
    #pragma unroll
    for (int i = 0; i < 32; i += 8) {
        int n = n0 + ty + i, k = k0 + tx;
        if (n < N && k < K) Wtb[(long)n * K + k] = __float2bfloat16(tile[tx][ty + i]);
    }
}

// ---------- paper projection: M x 128 = A[M,256] @ Bt[128,256], ReLU ----------
__global__ __launch_bounds__(256)
void gemm_mfma_k256(const float* __restrict__ A, const __hip_bfloat16* __restrict__ Bt,
                    const float* __restrict__ bias, float* __restrict__ C, int M) {
    __shared__ short As[128][72];
    __shared__ short Bs[128][72];
    int tid = threadIdx.x;
    int row0 = blockIdx.x * 128;
    int wave = tid >> 6, lane = tid & 63;
    int rw = (wave >> 1) * 64, cw = (wave & 1) * 64;
    int lm = lane & 15, kg = lane >> 4;
    floatx4 acc[4][4];
    #pragma unroll
    for (int i = 0; i < 4; i++)
        #pragma unroll
        for (int j = 0; j < 4; j++) acc[i][j] = floatx4{0.f, 0.f, 0.f, 0.f};

    for (int k0 = 0; k0 < 256; k0 += 64) {
        #pragma unroll
        for (int p = 0; p < 8; p++) {
            int q = p * 256 + tid;
            int r = q >> 4, c = (q & 15) * 4;
            int grow = row0 + r;
            float4 v = make_float4(0.f, 0.f, 0.f, 0.f);
            if (grow < M) v = *(const float4*)(A + (long)grow * 256 + k0 + c);
            short4v s;
            s.x = f2bf(v.x); s.y = f2bf(v.y); s.z = f2bf(v.z); s.w = f2bf(v.w);
            *(short4v*)&As[r][c] = s;
        }
        #pragma unroll
        for (int p = 0; p < 4; p++) {
            int q = p * 256 + tid;
            int r = q >> 3, c = (q & 7) * 8;
            *(short8*)&Bs[r][c] = *(const short8*)(Bt + (long)r * 256 + k0 + c);
        }
        __syncthreads();
        #pragma unroll
        for (int kk = 0; kk < 2; kk++) {
            int kb = kk * 32 + kg * 8;
            short8 a[4], b[4];
            #pragma unroll
            for (int mt = 0; mt < 4; mt++) a[mt] = *(short8*)&As[rw + mt * 16 + lm][kb];
            #pragma unroll
            for (int nt = 0; nt < 4; nt++) b[nt] = *(short8*)&Bs[cw + nt * 16 + lm][kb];
            #pragma unroll
            for (int mt = 0; mt < 4; mt++)
                #pragma unroll
                for (int nt = 0; nt < 4; nt++)
                    acc[mt][nt] = __builtin_amdgcn_mfma_f32_16x16x32_bf16(
                        a[mt], b[nt], acc[mt][nt], 0, 0, 0);
        }
        __syncthreads();
    }
    int rg = (lane >> 4) * 4;
    #pragma unroll
    for (int mt = 0; mt < 4; mt++) {
        #pragma unroll
        for (int nt = 0; nt < 4; nt++) {
            int col = cw + nt * 16 + lm;
            float bsv = bias[col];
            #pragma unroll
            for (int r = 0; r < 4; r++) {
                int row = row0 + rw + mt * 16 + rg + r;
                if (row < M) C[(long)row * 128 + col] = fmaxf(acc[mt][nt][r] + bsv, 0.f);
            }
        }
    }
}

// ---------- MFMA GEMM, full-K A staged once, N-loop inside block (K<=128) ----------
template <typename TC, int K>
__global__ __launch_bounds__(256)
void gemm_mfma_nl(const float* __restrict__ A, const __hip_bfloat16* __restrict__ Bt,
                  const float* __restrict__ bias, TC* __restrict__ C,
                  int M, int N, int act,
                  const TC* __restrict__ res, const float* __restrict__ skip_arr, int t) {
    constexpr int KP = K + 8;
    __shared__ short As[128][KP];
    __shared__ short Bs[64][KP];
    int tid = threadIdx.x;
    int row0 = blockIdx.x * 128;
    int wave = tid >> 6, lane = tid & 63;
    int rw = (wave >> 1) * 64, cw = (wave & 1) * 32;
    int lm = lane & 15, kg = lane >> 4;
    constexpr int KD4 = K / 4;
    #pragma unroll
    for (int p = 0; p < 128 * KD4 / 256; p++) {
        int q = p * 256 + tid;
        int r = q / KD4, c = (q % KD4) * 4;
        int grow = row0 + r;
        float4 v = make_float4(0.f, 0.f, 0.f, 0.f);
        if (grow < M) v = *(const float4*)(A + (long)grow * K + c);
        short4v s;
        s.x = f2bf(v.x); s.y = f2bf(v.y); s.z = f2bf(v.z); s.w = f2bf(v.w);
        *(short4v*)&As[r][c] = s;
    }
    float aval = 0.f;
    bool do_res = (res != nullptr);
    if (do_res) { float s = skip_arr[t]; aval = 1.f / (1.f + __expf(-s)); }
    int rg = (lane >> 4) * 4;
    constexpr int KD8 = K / 8;

    for (int n0 = 0; n0 < N; n0 += 64) {
        #pragma unroll
        for (int p = 0; p < 64 * KD8 / 256; p++) {
            int q = p * 256 + tid;
            int r = q / KD8, c = (q % KD8) * 8;
            *(short8*)&Bs[r][c] = *(const short8*)(Bt + (long)(n0 + r) * K + c);
        }
        __syncthreads();
        floatx4 acc[4][2];
        #pragma unroll
        for (int i = 0; i < 4; i++)
            #pragma unroll
            for (int j = 0; j < 2; j++) acc[i][j] = floatx4{0.f, 0.f, 0.f, 0.f};
        #pragma unroll
        for (int kk = 0; kk < K / 32; kk++) {
            int kb = kk * 32 + kg * 8;
            short8 a[4], b[2];
            #pragma unroll
            for (int mt = 0; mt < 4; mt++) a[mt] = *(short8*)&As[rw + mt * 16 + lm][kb];
            #pragma unroll
            for (int nt = 0; nt < 2; nt++) b[nt] = *(short8*)&Bs[cw + nt * 16 + lm][kb];
            #pragma unroll
            for (int mt = 0; mt < 4; mt++)
                #pragma unroll
                for (int nt = 0; nt < 2; nt++)
                    acc[mt][nt] = __builtin_amdgcn_mfma_f32_16x16x32_bf16(
                        a[mt], b[nt], acc[mt][nt], 0, 0, 0);
        }
        #pragma unroll
        for (int mt = 0; mt < 4; mt++) {
            #pragma unroll
            for (int nt = 0; nt < 2; nt++) {
                int col = n0 + cw + nt * 16 + lm;
                float bsv = bias[col];
                #pragma unroll
                for (int r = 0; r < 4; r++) {
                    int row = row0 + rw + mt * 16 + rg + r;
                    if (row < M) {
                        float v = acc[mt][nt][r] + bsv;
                        if (act == 1) v = fmaxf(v, 0.f);
                        if (do_res) v = aval * v + (1.f - aval) * ldf(res + (long)row * N + col);
                        stf(C + (long)row * N + col, v);
                    }
                }
            }
        }
        __syncthreads();
    }
}

// ---------- small utils ----------
__global__ void fill_u32(unsigned int* __restrict__ p, unsigned int v, int n) {
    int i = blockIdx.x * blockDim.x + threadIdx.x;
    if (i < n) p[i] = v;
}
__global__ void copy_u32(const int* __restrict__ a, int* __restrict__ b, int n) {
    int i = blockIdx.x * blockDim.x + threadIdx.x;
    if (i < n) b[i] = a[i];
}

// ---------- CSR build ----------
__global__ void count_edges(const int* __restrict__ dst, int E, int* __restrict__ counts) {
    int i = blockIdx.x * blockDim.x + threadIdx.x;
    if (i < E) atomicAdd(&counts[dst[i]], 1);
}

__global__ __launch_bounds__(256) void scan_local(const int* __restrict__ counts,
                                                  int* __restrict__ rowptr,
                                                  int* __restrict__ bsums, int n) {
    __shared__ int sh[256];
    int t = threadIdx.x;
    int base = blockIdx.x * 1024;
    int lv[4]; int s = 0;
    #pragma unroll
    for (int q = 0; q < 4; q++) {
        int i = base + t * 4 + q;
        lv[q] = (i < n) ? counts[i] : 0;
        s += lv[q];
    }
    sh[t] = s;
    __syncthreads();
    #pragma unroll
    for (int off = 1; off < 256; off <<= 1) {
        int add = (t >= off) ? sh[t - off] : 0;
        __syncthreads();
        sh[t] += add;
        __syncthreads();
    }
    int excl = sh[t] - s;
    if (t == 255) bsums[blockIdx.x] = sh[255];
    #pragma unroll
    for (int q = 0; q < 4; q++) {
        int i = base + t * 4 + q;
        if (i < n) rowptr[i] = excl;
        excl += lv[q];
    }
}
__global__ __launch_bounds__(256) void scan_bsums(int* __restrict__ bsums, int nb) {
    __shared__ int sh[256];
    int t = threadIdx.x;
    int v = (t < nb) ? bsums[t] : 0;
    sh[t] = v;
    __syncthreads();
    #pragma unroll
    for (int off = 1; off < 256; off <<= 1) {
        int add = (t >= off) ? sh[t - off] : 0;
        __syncthreads();
        sh[t] += add;
        __syncthreads();
    }
    if (t < nb) bsums[t] = sh[t] - v;
    if (t == nb - 1) bsums[nb] = sh[t];
}
__global__ void scan_add(int* __restrict__ rowptr, const int* __restrict__ bsums,
                         int n, int nb) {
    int i = blockIdx.x * blockDim.x + threadIdx.x;
    if (i < n) rowptr[i] += bsums[i >> 10];
    if (i == 0) rowptr[n] = bsums[nb];
}

// rec = (vrow, dst): vrow = per-edge-type row base in krelB/vrelB (layer-invariant
// rocur layout) + local src index. No etl/ei decode needed downstream; scores are
// stored in CSR-slot order.
__global__ void scatter_edges(const int* __restrict__ src, const int* __restrict__ dst, int E,
                              int* __restrict__ cursor, int2* __restrict__ recs,
                              int vrow_base) {
    int i = blockIdx.x * blockDim.x + threadIdx.x;
    if (i >= E) return;
    int pos = atomicAdd(&cursor[dst[i]], 1);
    recs[pos] = make_int2(vrow_base + src[i], dst[i]);
}

// ---------- relation transform ----------
__global__ void rel_transform(const __hip_bfloat16* __restrict__ in, long in_row_off,
                              int in_stride, int nrows, int H, int fout,
                              const float* __restrict__ rel, const float* __restrict__ prel,
                              float scale, __hip_bfloat16* __restrict__ outp) {
    __shared__ float sR[2048];
    int nl = H * 256;
    for (int i = threadIdx.x; i < nl; i += blockDim.x) {
        float f = (prel != nullptr) ? prel[i >> 8] * scale : 1.f;
        sR[i] = rel[i] * f;
    }
    __syncthreads();
    int per = blockDim.x / fout;
    int slot = threadIdx.x / fout;
    int j = threadIdx.x - slot * fout;
    int h = j >> 4;
    const float* rp = sR + h * 256 + (j & 15);
    for (long d = (long)blockIdx.x * per + slot; d < nrows; d += (long)gridDim.x * per) {
        float xv[16];
        load16bf(in + in_row_off + d * in_stride + h * 16, xv);
        float acc = 0.f;
        #pragma unroll
        for (int i = 0; i < 16; i++) acc = fmaf(xv[i], rp[i * 16], acc);
        outp[d * fout + j] = __float2bfloat16(acc);
    }
}

// ---------- scores in CSR-slot order: sc[(slot-base)*H + h] ----------
template <int H>
__global__ void edge_score_csr(const __hip_bfloat16* __restrict__ krelbuf,
                               const __hip_bfloat16* __restrict__ Qdst, int stride,
                               const int2* __restrict__ recs, const int* __restrict__ rowptr,
                               int tb, long nwork, float* __restrict__ sc_out) {
    long tid = blockIdx.x * (long)blockDim.x + threadIdx.x;
    if (tid >= nwork) return;
    constexpr int FOUT = H * 16;
    int sl = (int)(tid / H);
    int h = (int)(tid - (long)sl * H);
    int base = rowptr[tb];
    int2 rec = recs[base + sl];
    float kv[16], qv[16];
    load16bf(krelbuf + (long)rec.x * FOUT + h * 16, kv);
    load16bf(Qdst + (long)rec.y * stride + h * 16, qv);
    float acc = 0.f;
    #pragma unroll
    for (int i = 0; i < 16; i++) acc = fmaf(kv[i], qv[i], acc);
    sc_out[tid] = acc;
}

// ---------- segment softmax stats: sequential CSR-ordered score reads ----------
template <int H>
__global__ __launch_bounds__(256)
void edge_alpha_csr(const int* __restrict__ rowptr, int tb, int ndst,
                    const float* __restrict__ sc, float2* __restrict__ ml) {
    constexpr int PER = 256 / H;
    int slot = threadIdx.x / H;
    int h = threadIdx.x - slot * H;
    int d = blockIdx.x * PER + slot;
    if (d >= ndst) return;
    int base = rowptr[tb];
    int r0 = rowptr[tb + d], r1 = rowptr[tb + d + 1];
    const float* scp = sc + (long)(r0 - base) * H + h;
    float m = -1e30f, l = 0.f;
    for (int n = r1 - r0; n > 0; --n, scp += H) {
        float s = *scp;
        float mn = fmaxf(m, s);
        float r = __expf(m - mn);
        float w = __expf(s - mn);
        l = fmaf(l, r, w);
        m = mn;
    }
    float inv = (l > 0.f) ? 1.f / l : 0.f;
    ml[(long)d * H + h] = make_float2(m, inv);
}

// ---------- gather: 4 channels/thread, sequential sc, precomputed vrow ----------
template <int FOUT, int H>
__global__ void gather_agg_csr(const __hip_bfloat16* __restrict__ vrelbuf,
                               const int2* __restrict__ recs, const int* __restrict__ rowptr,
                               int tb, int ndst,
                               const float* __restrict__ sc,
                               const float2* __restrict__ ml,
                               float* __restrict__ agg) {
    constexpr int TPD = FOUT / 4;       // threads per dst
    constexpr int PER = 256 / TPD;
    int slot = threadIdx.x / TPD;
    int jj = threadIdx.x - slot * TPD;
    int j4 = jj * 4;
    int d = blockIdx.x * PER + slot;
    if (d >= ndst) return;
    int h = j4 >> 4;
    float2 mh = ml[(long)d * H + h];
    int base = rowptr[tb];
    int r0 = rowptr[tb + d], r1 = rowptr[tb + d + 1];
    const float* scp = sc + (long)(r0 - base) * H + h;
    const int2* rp = recs + r0;
    int n = r1 - r0;
    float a0[4] = {0.f, 0.f, 0.f, 0.f}, a1[4] = {0.f, 0.f, 0.f, 0.f};
    int i = 0;
    for (; i + 1 < n; i += 2) {
        int2 ra = rp[i], rb = rp[i + 1];
        float s0 = scp[(long)i * H], s1 = scp[(long)(i + 1) * H];
        float w0 = __expf(s0 - mh.x) * mh.y;
        float w1 = __expf(s1 - mh.x) * mh.y;
        uint2 va = *(const uint2*)(vrelbuf + (long)ra.x * FOUT + j4);
        uint2 vb = *(const uint2*)(vrelbuf + (long)rb.x * FOUT + j4);
        a0[0] = fmaf(w0, bflo(va.x), a0[0]);
        a0[1] = fmaf(w0, bfhi(va.x), a0[1]);
        a0[2] = fmaf(w0, bflo(va.y), a0[2]);
        a0[3] = fmaf(w0, bfhi(va.y), a0[3]);
        a1[0] = fmaf(w1, bflo(vb.x), a1[0]);
        a1[1] = fmaf(w1, bfhi(vb.x), a1[1]);
        a1[2] = fmaf(w1, bflo(vb.y), a1[2]);
        a1[3] = fmaf(w1, bfhi(vb.y), a1[3]);
    }
    if (i < n) {
        int2 ra = rp[i];
        float w0 = __expf(scp[(long)i * H] - mh.x) * mh.y;
        uint2 va = *(const uint2*)(vrelbuf + (long)ra.x * FOUT + j4);
        a0[0] = fmaf(w0, bflo(va.x), a0[0]);
        a0[1] = fmaf(w0, bfhi(va.x), a0[1]);
        a0[2] = fmaf(w0, bflo(va.y), a0[2]);
        a0[3] = fmaf(w0, bfhi(va.y), a0[3]);
    }
    float4 o;
    o.x = gelu1(a0[0] + a1[0]);
    o.y = gelu1(a0[1] + a1[1]);
    o.z = gelu1(a0[2] + a1[2]);
    o.w = gelu1(a0[3] + a1[3]);
    *(float4*)(agg + (long)d * FOUT + j4) = o;
}

// ---------- orchestration ----------
static const int ET_src[5] = {1, 0, 0, 1, 2};
static const int ET_dst[5] = {0, 0, 1, 2, 1};
static const int ET_E[5]   = {250000, 250000, 200000, 100000, 100000};
static const int ET_RO[5]  = {0, 50000, 0, 0, 100000};  // vrow base (rocur layout)
static const int NT[3]     = {100000, 50000, 5000};
static const long NPRE[3]  = {0, 100000, 150000};
static const int TB[3]     = {0, 100000, 150000};
static const int SL[3]     = {500000, 300000, 100000};  // incoming edges per dst type
static const int NTOT      = 155000;

template <typename TO, int H>
static void hgt_layer_run(hipStream_t stream,
                          const float* xs, __hip_bfloat16* kqvB, float* scB,
                          const int* rowptr, const int2* recs, float* aggB,
                          __hip_bfloat16* krelB, __hip_bfloat16* vrelB,
                          const __hip_bfloat16* wt_kqv, const float* kqv_b,
                          const float* krel, const float* vrel, const float* prel,
                          const __hip_bfloat16* wt_out, const float* out_b,
                          const float* skip_arr,
                          bool do_skip, TO* const* outs) {
    constexpr int FOUT = H * 16;
    const int F3 = 3 * FOUT;
    for (int t = 0; t < 3; t++) {
        int gb = (NT[t] + 127) / 128;
        gemm_mfma_nl<__hip_bfloat16, 128><<<gb, 256, 0, stream>>>(
            xs + NPRE[t] * 128, wt_kqv + (long)t * 128 * F3, kqv_b + t * F3,
            kqvB + NPRE[t] * F3, NT[t], F3, 0,
            (__hip_bfloat16*)nullptr, nullptr, 0);
    }
    for (int t = 0; t < 3; t++) {
        int rocur = 0;
        for (int e = 0; e < 5; e++) {
            if (ET_dst[e] != t) continue;
            int ts = ET_src[e];
            int per = 256 / FOUT;
            int tg = (NT[ts] + per - 1) / per; if (tg > 2048) tg = 2048;
            rel_transform<<<tg, 256, 0, stream>>>(
                kqvB, NPRE[ts] * F3 + 2 * FOUT, F3, NT[ts], H, FOUT,
                vrel + (long)e * H * 256, nullptr, 1.f, vrelB + (long)rocur * FOUT);
            rel_transform<<<tg, 256, 0, stream>>>(
                kqvB, NPRE[ts] * F3, F3, NT[ts], H, FOUT,
                krel + (long)e * H * 256, prel + e * H, 0.25f,
                krelB + (long)rocur * FOUT);
            rocur += NT[ts];
        }
        long nwork = (long)SL[t] * H;
        edge_score_csr<H><<<(int)((nwork + 255) / 256), 256, 0, stream>>>(
            krelB, kqvB + NPRE[t] * F3 + FOUT, F3, recs, rowptr, TB[t], nwork, scB);
        // (m, 1/l) per (dst,h); buffer aliases krelB (dead after edge_score_csr)
        float2* ml = (float2*)krelB;
        constexpr int PERA = 256 / H;
        edge_alpha_csr<H><<<(NT[t] + PERA - 1) / PERA, 256, 0, stream>>>(
            rowptr, TB[t], NT[t], scB, ml);
        constexpr int PERG = 256 / (FOUT / 4);
        gather_agg_csr<FOUT, H><<<(NT[t] + PERG - 1) / PERG, 256, 0, stream>>>(
            vrelB, recs, rowptr, TB[t], NT[t], scB, ml, aggB);
        int gb2 = (NT[t] + 127) / 128;
        gemm_mfma_nl<TO, FOUT><<<gb2, 256, 0, stream>>>(
            aggB, wt_out + (long)t * FOUT * FOUT, out_b + t * FOUT, outs[t],
            NT[t], FOUT, 0, do_skip ? outs[t] : (TO*)nullptr, skip_arr, t);
    }
}

extern "C" void kernel_launch(void* const* d_in, const int* in_sizes, int n_in,
                              void* d_out, int out_size, void* d_ws, size_t ws_size,
                              hipStream_t stream) {
    const float* x_paper  = (const float*)d_in[0];
    const float* x_author = (const float*)d_in[1];
    const float* x_inst   = (const float*)d_in[2];
    const int* ei[5];
    for (int e = 0; e < 5; e++) ei[e] = (const int*)d_in[3 + e];
    const float* lin_w[3] = {(const float*)d_in[8], (const float*)d_in[10], (const float*)d_in[12]};
    const float* lin_b[3] = {(const float*)d_in[9], (const float*)d_in[11], (const float*)d_in[13]};
    const float* kqv_w1 = (const float*)d_in[14];
    const float* kqv_b1 = (const float*)d_in[15];
    const float* krel1  = (const float*)d_in[16];
    const float* vrel1  = (const float*)d_in[17];
    const float* prel1  = (const float*)d_in[18];
    const float* out_w1 = (const float*)d_in[19];
    const float* out_b1 = (const float*)d_in[20];
    const float* skip1  = (const float*)d_in[21];
    const float* kqv_w2 = (const float*)d_in[22];
    const float* kqv_b2 = (const float*)d_in[23];
    const float* krel2  = (const float*)d_in[24];
    const float* vrel2  = (const float*)d_in[25];
    const float* prel2  = (const float*)d_in[26];
    const float* out_w2 = (const float*)d_in[27];
    const float* out_b2 = (const float*)d_in[28];
    const float* skip2  = (const float*)d_in[29];

    // workspace carve (all offsets 16B-aligned); total 351,520,000 B
    char* p = (char*)d_ws;
    float* xs = (float*)p;                      p += 19840000L * 4;
    __hip_bfloat16* kqvB = (__hip_bfloat16*)p;  p += 59520000L * 2;
    float* scB = (float*)p;                     p += 4000000L * 4;
    float* aggB = (float*)p;                    p += 12800000L * 4;
    int* rowptr = (int*)p;                      p += 155008L * 4;
    int* cursor = (int*)p;                      p += 155008L * 4;
    int2* recs = (int2*)p;                      p += 900000L * 8;
    __hip_bfloat16* vrelB = (__hip_bfloat16*)p; p += 19200000L * 2;
    __hip_bfloat16* krelB = (__hip_bfloat16*)p; p += 19200000L * 2;
    __hip_bfloat16* wtA = (__hip_bfloat16*)p;

    __hip_bfloat16* wt_lin[3] = {wtA, wtA + 32768, wtA + 49152};
    __hip_bfloat16* wt_kqv1 = wtA + 57344;
    __hip_bfloat16* wt_out1 = wtA + 204800;
    __hip_bfloat16* wt_kqv2 = wtA + 253952;
    __hip_bfloat16* wt_out2 = wtA + 327680;

    dim3 pb(32, 8);
    pack_wt<<<dim3(4, 8, 1), pb, 0, stream>>>(lin_w[0], wt_lin[0], 256, 128);
    pack_wt<<<dim3(4, 4, 1), pb, 0, stream>>>(lin_w[1], wt_lin[1], 128, 128);
    pack_wt<<<dim3(4, 2, 1), pb, 0, stream>>>(lin_w[2], wt_lin[2], 64, 128);
    pack_wt<<<dim3(12, 4, 3), pb, 0, stream>>>(kqv_w1, wt_kqv1, 128, 384);
    pack_wt<<<dim3(4, 4, 3), pb, 0, stream>>>(out_w1, wt_out1, 128, 128);
    pack_wt<<<dim3(6, 4, 3), pb, 0, stream>>>(kqv_w2, wt_kqv2, 128, 192);
    pack_wt<<<dim3(2, 2, 3), pb, 0, stream>>>(out_w2, wt_out2, 64, 64);

    // input projections (ReLU). N=128; paper uses dedicated K=256 BN=128 kernel.
    gemm_mfma_k256<<<782, 256, 0, stream>>>(x_paper, wt_lin[0], lin_b[0], xs, 100000);
    gemm_mfma_nl<float, 128><<<391, 256, 0, stream>>>(
        x_author, wt_lin[1], lin_b[1], xs + 100000L * 128, 50000, 128, 1,
        (float*)nullptr, nullptr, 0);
    gemm_mfma_nl<float, 64><<<40, 256, 0, stream>>>(
        x_inst, wt_lin[2], lin_b[2], xs + 150000L * 128, 5000, 128, 1,
        (float*)nullptr, nullptr, 0);

    // CSR build (shared by both layers)
    fill_u32<<<(NTOT + 255) / 256, 256, 0, stream>>>((unsigned int*)cursor, 0u, NTOT);
    for (int e = 0; e < 5; e++)
        count_edges<<<(ET_E[e] + 255) / 256, 256, 0, stream>>>(
            ei[e] + ET_E[e], ET_E[e], cursor + TB[ET_dst[e]]);
    {
        int* bsums = (int*)aggB;
        int nb = (NTOT + 1023) / 1024;  // 152
        scan_local<<<nb, 256, 0, stream>>>(cursor, rowptr, bsums, NTOT);
        scan_bsums<<<1, 256, 0, stream>>>(bsums, nb);
        scan_add<<<(NTOT + 255) / 256, 256, 0, stream>>>(rowptr, bsums, NTOT, nb);
    }
    copy_u32<<<(NTOT + 255) / 256, 256, 0, stream>>>(rowptr, cursor, NTOT);
    for (int e = 0; e < 5; e++)
        scatter_edges<<<(ET_E[e] + 255) / 256, 256, 0, stream>>>(
            ei[e], ei[e] + ET_E[e], ET_E[e], cursor + TB[ET_dst[e]], recs, ET_RO[e]);

    // layer 1 (output in-place over xs; gated skip fused into out-GEMM)
    float* outs1[3] = {xs, xs + 100000L * 128, xs + 150000L * 128};
    hgt_layer_run<float, 8>(stream, xs, kqvB, scB, rowptr, recs, aggB, krelB, vrelB,
                            wt_kqv1, kqv_b1, krel1, vrel1, prel1, wt_out1, out_b1, skip1,
                            true, outs1);

    float* out = (float*)d_out;
    float* outs2[3] = {out, out + 100000L * 64, out + 150000L * 64};
    hgt_layer_run<float, 4>(stream, xs, kqvB, scB, rowptr, recs, aggB, krelB, vrelB,
                            wt_kqv2, kqv_b2, krel2, vrel2, prel2, wt_out2, out_b2, skip2,
                            false, outs2);
}

// Round 6
// 1409.193 us; speedup vs baseline: 1.4100x; 1.0525x over previous
//
#include <hip/hip_runtime.h>
#include <hip/hip_bf16.h>
#include <math.h>

typedef __attribute__((ext_vector_type(8))) short short8;
typedef __attribute__((ext_vector_type(4))) short short4v;
typedef __attribute__((ext_vector_type(4))) float floatx4;

// ---------- type helpers ----------
__device__ __forceinline__ float ldf(const float* p) { return *p; }
__device__ __forceinline__ float ldf(const __hip_bfloat16* p) { return __bfloat162float(*p); }
__device__ __forceinline__ void stf(float* p, float v) { *p = v; }
__device__ __forceinline__ void stf(__hip_bfloat16* p, float v) { *p = __float2bfloat16(v); }
__device__ __forceinline__ float gelu1(float v) {
    return 0.5f * v * (1.f + erff(v * 0.70710678118654752f));
}
__device__ __forceinline__ short f2bf(float f) {
    unsigned int u = __float_as_uint(f);
    unsigned int r = (u + 0x7FFFu + ((u >> 16) & 1u)) >> 16;
    return (short)r;
}
__device__ __forceinline__ float bflo(unsigned int u) { return __uint_as_float(u << 16); }
__device__ __forceinline__ float bfhi(unsigned int u) { return __uint_as_float(u & 0xFFFF0000u); }
__device__ __forceinline__ void load16bf(const __hip_bfloat16* p, float* o) {
    const uint4* u = (const uint4*)p;
    uint4 w0 = u[0], w1 = u[1];
    unsigned int ws[8] = {w0.x, w0.y, w0.z, w0.w, w1.x, w1.y, w1.z, w1.w};
    #pragma unroll
    for (int i = 0; i < 8; i++) {
        o[2 * i]     = bflo(ws[i]);
        o[2 * i + 1] = bfhi(ws[i]);
    }
}

// ---------- weight pack: W[K,N] f32 -> Wt[N,K] bf16 (batched over grid.z) ----------
__global__ void pack_wt(const float* __restrict__ W, __hip_bfloat16* __restrict__ Wt,
                        int K, int N) {
    __shared__ float tile[32][33];
    long b = blockIdx.z;
    const float* Wb = W + b * K * N;
    __hip_bfloat16* Wtb = Wt + b * K * N;
    int k0 = blockIdx.y * 32, n0 = blockIdx.x * 32;
    int tx = threadIdx.x, ty = threadIdx.y;  // 32 x 8
    #pragma unroll
    for (int i = 0; i < 32; i += 8) {
        int k = k0 + ty + i, n = n0 + tx;
        tile[ty + i][tx] = (k < K && n < N) ? Wb[(long)k * N + n] : 0.f;
    }
    __syncthreads();
    #pragma unroll
    for (int i = 0; i < 32; i += 8) {
        int n = n0 + ty + i, k = k0 + tx;
        if (n < N && k < K) Wtb[(long)n * K + k] = __float2bfloat16(tile[tx][ty + i]);
    }
}

// ---------- GEMM body: A staged in LDS (full K), B direct from global (L2-resident
// weights), ONE barrier total (after A-stage), N-loop chunks of 64, no Bs buffer.
// BM=128: waves 2x2 (rw=(w>>1)*64, cw=(w&1)*32, 2 col tiles); BM=64: 1x4 (cw=w*16).
template <typename TC, int K, int BM>
__device__ __forceinline__
void gemm_nl_body(const float* __restrict__ A, const __hip_bfloat16* __restrict__ Bt,
                  const float* __restrict__ bias, TC* __restrict__ C,
                  int M, int N, int act, const TC* __restrict__ res, float aval,
                  int row0, short (*As)[K + 8]) {
    int tid = threadIdx.x;
    int wave = tid >> 6, lane = tid & 63;
    constexpr int NTT = (BM == 128) ? 2 : 1;
    int rw = (BM == 128) ? (wave >> 1) * 64 : 0;
    int cw = (BM == 128) ? (wave & 1) * 32 : wave * 16;
    int lm = lane & 15, kg = lane >> 4;
    constexpr int KD4 = K / 4;
    constexpr int NLD = BM * KD4 / 256;
    #pragma unroll
    for (int p = 0; p < NLD; p++) {
        int q = p * 256 + tid;
        int r = q / KD4, c = (q % KD4) * 4;
        int grow = row0 + r;
        float4 v = make_float4(0.f, 0.f, 0.f, 0.f);
        if (grow < M) v = *(const float4*)(A + (long)grow * K + c);
        short4v s;
        s.x = f2bf(v.x); s.y = f2bf(v.y); s.z = f2bf(v.z); s.w = f2bf(v.w);
        *(short4v*)&As[r][c] = s;
    }
    __syncthreads();
    bool do_res = (res != nullptr);
    int rg = kg * 4;
    for (int n0 = 0; n0 < N; n0 += 64) {
        floatx4 acc[4][NTT];
        #pragma unroll
        for (int i = 0; i < 4; i++)
            #pragma unroll
            for (int j = 0; j < NTT; j++) acc[i][j] = floatx4{0.f, 0.f, 0.f, 0.f};
        #pragma unroll
        for (int kk = 0; kk < K / 32; kk++) {
            int kb = kk * 32 + kg * 8;
            short8 a[4], b[NTT];
            #pragma unroll
            for (int mt = 0; mt < 4; mt++) a[mt] = *(short8*)&As[rw + mt * 16 + lm][kb];
            #pragma unroll
            for (int nt = 0; nt < NTT; nt++)
                b[nt] = *(const short8*)(Bt + (long)(n0 + cw + nt * 16 + lm) * K + kb);
            #pragma unroll
            for (int mt = 0; mt < 4; mt++)
                #pragma unroll
                for (int nt = 0; nt < NTT; nt++)
                    acc[mt][nt] = __builtin_amdgcn_mfma_f32_16x16x32_bf16(
                        a[mt], b[nt], acc[mt][nt], 0, 0, 0);
        }
        #pragma unroll
        for (int mt = 0; mt < 4; mt++) {
            #pragma unroll
            for (int nt = 0; nt < NTT; nt++) {
                int col = n0 + cw + nt * 16 + lm;
                float bsv = bias[col];
                #pragma unroll
                for (int r = 0; r < 4; r++) {
                    int row = row0 + rw + mt * 16 + rg + r;
                    if (row < M) {
                        float v = acc[mt][nt][r] + bsv;
                        if (act == 1) v = fmaxf(v, 0.f);
                        if (do_res) v = aval * v + (1.f - aval) * ldf(res + (long)row * N + col);
                        stf(C + (long)row * N + col, v);
                    }
                }
            }
        }
    }
}

template <typename TC, int K, int BM>
__global__ __launch_bounds__(256)
void gemm_nl(const float* __restrict__ A, const __hip_bfloat16* __restrict__ Bt,
             const float* __restrict__ bias, TC* __restrict__ C,
             int M, int N, int act,
             const TC* __restrict__ res, const float* __restrict__ skip_arr, int t) {
    __shared__ short As[BM][K + 8];
    float aval = 0.f;
    if (res != nullptr) { float s = skip_arr[t]; aval = 1.f / (1.f + __expf(-s)); }
    gemm_nl_body<TC, K, BM>(A, Bt, bias, C, M, N, act, res, aval, blockIdx.x * BM, As);
}

// ---------- fused per-type kqv GEMM: one dispatch for all 3 node types ----------
// Blocks [0,782) papers, [782,1173) authors, [1173,1213) institutions.
template <int FOUT>
__global__ __launch_bounds__(256)
void gemm_kqv_fused(const float* __restrict__ xs, const __hip_bfloat16* __restrict__ wt,
                    const float* __restrict__ kqv_b, __hip_bfloat16* __restrict__ kqvB) {
    constexpr int F3 = 3 * FOUT;
    __shared__ short As[128][136];
    int b = blockIdx.x;
    int tsel, brel, mt;
    long npre;
    if (b < 782)       { tsel = 0; brel = b;        npre = 0;      mt = 100000; }
    else if (b < 1173) { tsel = 1; brel = b - 782;  npre = 100000; mt = 50000; }
    else               { tsel = 2; brel = b - 1173; npre = 150000; mt = 5000; }
    gemm_nl_body<__hip_bfloat16, 128, 128>(
        xs + npre * 128, wt + (long)tsel * 128 * F3, kqv_b + tsel * F3,
        kqvB + npre * F3, mt, F3, 0, (const __hip_bfloat16*)nullptr, 0.f,
        brel * 128, As);
}

// ---------- small utils ----------
__global__ void fill_u32(unsigned int* __restrict__ p, unsigned int v, int n) {
    int i = blockIdx.x * blockDim.x + threadIdx.x;
    if (i < n) p[i] = v;
}
__global__ void copy_u32(const int* __restrict__ a, int* __restrict__ b, int n) {
    int i = blockIdx.x * blockDim.x + threadIdx.x;
    if (i < n) b[i] = a[i];
}

// ---------- CSR build ----------
__global__ void count_edges(const int* __restrict__ dst, int E, int* __restrict__ counts) {
    int i = blockIdx.x * blockDim.x + threadIdx.x;
    if (i < E) atomicAdd(&counts[dst[i]], 1);
}

__global__ __launch_bounds__(256) void scan_local(const int* __restrict__ counts,
                                                  int* __restrict__ rowptr,
                                                  int* __restrict__ bsums, int n) {
    __shared__ int sh[256];
    int t = threadIdx.x;
    int base = blockIdx.x * 1024;
    int lv[4]; int s = 0;
    #pragma unroll
    for (int q = 0; q < 4; q++) {
        int i = base + t * 4 + q;
        lv[q] = (i < n) ? counts[i] : 0;
        s += lv[q];
    }
    sh[t] = s;
    __syncthreads();
    #pragma unroll
    for (int off = 1; off < 256; off <<= 1) {
        int add = (t >= off) ? sh[t - off] : 0;
        __syncthreads();
        sh[t] += add;
        __syncthreads();
    }
    int excl = sh[t] - s;
    if (t == 255) bsums[blockIdx.x] = sh[255];
    #pragma unroll
    for (int q = 0; q < 4; q++) {
        int i = base + t * 4 + q;
        if (i < n) rowptr[i] = excl;
        excl += lv[q];
    }
}
__global__ __launch_bounds__(256) void scan_bsums(int* __restrict__ bsums, int nb) {
    __shared__ int sh[256];
    int t = threadIdx.x;
    int v = (t < nb) ? bsums[t] : 0;
    sh[t] = v;
    __syncthreads();
    #pragma unroll
    for (int off = 1; off < 256; off <<= 1) {
        int add = (t >= off) ? sh[t - off] : 0;
        __syncthreads();
        sh[t] += add;
        __syncthreads();
    }
    if (t < nb) bsums[t] = sh[t] - v;
    if (t == nb - 1) bsums[nb] = sh[t];
}
__global__ void scan_add(int* __restrict__ rowptr, const int* __restrict__ bsums,
                         int n, int nb) {
    int i = blockIdx.x * blockDim.x + threadIdx.x;
    if (i < n) rowptr[i] += bsums[i >> 10];
    if (i == 0) rowptr[n] = bsums[nb];
}

// rec = (vrow, dst): vrow = per-edge-type row base in krelB/vrelB + local src index.
__global__ void scatter_edges(const int* __restrict__ src, const int* __restrict__ dst, int E,
                              int* __restrict__ cursor, int2* __restrict__ recs,
                              int vrow_base) {
    int i = blockIdx.x * blockDim.x + threadIdx.x;
    if (i >= E) return;
    int pos = atomicAdd(&cursor[dst[i]], 1);
    recs[pos] = make_int2(vrow_base + src[i], dst[i]);
}

// ---------- relation transform ----------
__global__ void rel_transform(const __hip_bfloat16* __restrict__ in, long in_row_off,
                              int in_stride, int nrows, int H, int fout,
                              const float* __restrict__ rel, const float* __restrict__ prel,
                              float scale, __hip_bfloat16* __restrict__ outp) {
    __shared__ float sR[2048];
    int nl = H * 256;
    for (int i = threadIdx.x; i < nl; i += blockDim.x) {
        float f = (prel != nullptr) ? prel[i >> 8] * scale : 1.f;
        sR[i] = rel[i] * f;
    }
    __syncthreads();
    int per = blockDim.x / fout;
    int slot = threadIdx.x / fout;
    int j = threadIdx.x - slot * fout;
    int h = j >> 4;
    const float* rp = sR + h * 256 + (j & 15);
    for (long d = (long)blockIdx.x * per + slot; d < nrows; d += (long)gridDim.x * per) {
        float xv[16];
        load16bf(in + in_row_off + d * in_stride + h * 16, xv);
        float acc = 0.f;
        #pragma unroll
        for (int i = 0; i < 16; i++) acc = fmaf(xv[i], rp[i * 16], acc);
        outp[d * fout + j] = __float2bfloat16(acc);
    }
}

// ---------- scores in CSR-slot order: sc[(slot-base)*H + h] ----------
template <int H>
__global__ void edge_score_csr(const __hip_bfloat16* __restrict__ krelbuf,
                               const __hip_bfloat16* __restrict__ Qdst, int stride,
                               const int2* __restrict__ recs, const int* __restrict__ rowptr,
                               int tb, long nwork, float* __restrict__ sc_out) {
    long tid = blockIdx.x * (long)blockDim.x + threadIdx.x;
    if (tid >= nwork) return;
    constexpr int FOUT = H * 16;
    int sl = (int)(tid / H);
    int h = (int)(tid - (long)sl * H);
    int base = rowptr[tb];
    int2 rec = recs[base + sl];
    float kv[16], qv[16];
    load16bf(krelbuf + (long)rec.x * FOUT + h * 16, kv);
    load16bf(Qdst + (long)rec.y * stride + h * 16, qv);
    float acc = 0.f;
    #pragma unroll
    for (int i = 0; i < 16; i++) acc = fmaf(kv[i], qv[i], acc);
    sc_out[tid] = acc;
}

// ---------- segment softmax stats: sequential CSR-ordered score reads ----------
template <int H>
__global__ __launch_bounds__(256)
void edge_alpha_csr(const int* __restrict__ rowptr, int tb, int ndst,
                    const float* __restrict__ sc, float2* __restrict__ ml) {
    constexpr int PER = 256 / H;
    int slot = threadIdx.x / H;
    int h = threadIdx.x - slot * H;
    int d = blockIdx.x * PER + slot;
    if (d >= ndst) return;
    int base = rowptr[tb];
    int r0 = rowptr[tb + d], r1 = rowptr[tb + d + 1];
    const float* scp = sc + (long)(r0 - base) * H + h;
    float m = -1e30f, l = 0.f;
    for (int n = r1 - r0; n > 0; --n, scp += H) {
        float s = *scp;
        float mn = fmaxf(m, s);
        float r = __expf(m - mn);
        float w = __expf(s - mn);
        l = fmaf(l, r, w);
        m = mn;
    }
    float inv = (l > 0.f) ? 1.f / l : 0.f;
    ml[(long)d * H + h] = make_float2(m, inv);
}

// ---------- gather: 4 channels/thread, sequential sc, precomputed vrow ----------
template <int FOUT, int H>
__global__ void gather_agg_csr(const __hip_bfloat16* __restrict__ vrelbuf,
                               const int2* __restrict__ recs, const int* __restrict__ rowptr,
                               int tb, int ndst,
                               const float* __restrict__ sc,
                               const float2* __restrict__ ml,
                               float* __restrict__ agg) {
    constexpr int TPD = FOUT / 4;       // threads per dst
    constexpr int PER = 256 / TPD;
    int slot = threadIdx.x / TPD;
    int jj = threadIdx.x - slot * TPD;
    int j4 = jj * 4;
    int d = blockIdx.x * PER + slot;
    if (d >= ndst) return;
    int h = j4 >> 4;
    float2 mh = ml[(long)d * H + h];
    int base = rowptr[tb];
    int r0 = rowptr[tb + d], r1 = rowptr[tb + d + 1];
    const float* scp = sc + (long)(r0 - base) * H + h;
    const int2* rp = recs + r0;
    int n = r1 - r0;
    float a0[4] = {0.f, 0.f, 0.f, 0.f}, a1[4] = {0.f, 0.f, 0.f, 0.f};
    int i = 0;
    for (; i + 1 < n; i += 2) {
        int2 ra = rp[i], rb = rp[i + 1];
        float s0 = scp[(long)i * H], s1 = scp[(long)(i + 1) * H];
        float w0 = __expf(s0 - mh.x) * mh.y;
        float w1 = __expf(s1 - mh.x) * mh.y;
        uint2 va = *(const uint2*)(vrelbuf + (long)ra.x * FOUT + j4);
        uint2 vb = *(const uint2*)(vrelbuf + (long)rb.x * FOUT + j4);
        a0[0] = fmaf(w0, bflo(va.x), a0[0]);
        a0[1] = fmaf(w0, bfhi(va.x), a0[1]);
        a0[2] = fmaf(w0, bflo(va.y), a0[2]);
        a0[3] = fmaf(w0, bfhi(va.y), a0[3]);
        a1[0] = fmaf(w1, bflo(vb.x), a1[0]);
        a1[1] = fmaf(w1, bfhi(vb.x), a1[1]);
        a1[2] = fmaf(w1, bflo(vb.y), a1[2]);
        a1[3] = fmaf(w1, bfhi(vb.y), a1[3]);
    }
    if (i < n) {
        int2 ra = rp[i];
        float w0 = __expf(scp[(long)i * H] - mh.x) * mh.y;
        uint2 va = *(const uint2*)(vrelbuf + (long)ra.x * FOUT + j4);
        a0[0] = fmaf(w0, bflo(va.x), a0[0]);
        a0[1] = fmaf(w0, bfhi(va.x), a0[1]);
        a0[2] = fmaf(w0, bflo(va.y), a0[2]);
        a0[3] = fmaf(w0, bfhi(va.y), a0[3]);
    }
    float4 o;
    o.x = gelu1(a0[0] + a1[0]);
    o.y = gelu1(a0[1] + a1[1]);
    o.z = gelu1(a0[2] + a1[2]);
    o.w = gelu1(a0[3] + a1[3]);
    *(float4*)(agg + (long)d * FOUT + j4) = o;
}

// ---------- orchestration ----------
static const int ET_src[5] = {1, 0, 0, 1, 2};
static const int ET_dst[5] = {0, 0, 1, 2, 1};
static const int ET_E[5]   = {250000, 250000, 200000, 100000, 100000};
static const int ET_RO[5]  = {0, 50000, 0, 0, 100000};  // vrow base (rocur layout)
static const int NT[3]     = {100000, 50000, 5000};
static const long NPRE[3]  = {0, 100000, 150000};
static const int TB[3]     = {0, 100000, 150000};
static const int SL[3]     = {500000, 300000, 100000};  // incoming edges per dst type
static const int NTOT      = 155000;

template <typename TO, int H>
static void hgt_layer_run(hipStream_t stream,
                          const float* xs, __hip_bfloat16* kqvB, float* scB,
                          const int* rowptr, const int2* recs, float* aggB,
                          __hip_bfloat16* krelB, __hip_bfloat16* vrelB,
                          const __hip_bfloat16* wt_kqv, const float* kqv_b,
                          const float* krel, const float* vrel, const float* prel,
                          const __hip_bfloat16* wt_out, const float* out_b,
                          const float* skip_arr,
                          bool do_skip, TO* const* outs) {
    constexpr int FOUT = H * 16;
    const int F3 = 3 * FOUT;
    gemm_kqv_fused<FOUT><<<1213, 256, 0, stream>>>(xs, wt_kqv, kqv_b, kqvB);
    for (int t = 0; t < 3; t++) {
        int rocur = 0;
        for (int e = 0; e < 5; e++) {
            if (ET_dst[e] != t) continue;
            int ts = ET_src[e];
            int per = 256 / FOUT;
            int tg = (NT[ts] + per - 1) / per; if (tg > 2048) tg = 2048;
            rel_transform<<<tg, 256, 0, stream>>>(
                kqvB, NPRE[ts] * F3 + 2 * FOUT, F3, NT[ts], H, FOUT,
                vrel + (long)e * H * 256, nullptr, 1.f, vrelB + (long)rocur * FOUT);
            rel_transform<<<tg, 256, 0, stream>>>(
                kqvB, NPRE[ts] * F3, F3, NT[ts], H, FOUT,
                krel + (long)e * H * 256, prel + e * H, 0.25f,
                krelB + (long)rocur * FOUT);
            rocur += NT[ts];
        }
        long nwork = (long)SL[t] * H;
        edge_score_csr<H><<<(int)((nwork + 255) / 256), 256, 0, stream>>>(
            krelB, kqvB + NPRE[t] * F3 + FOUT, F3, recs, rowptr, TB[t], nwork, scB);
        // (m, 1/l) per (dst,h); buffer aliases krelB (dead after edge_score_csr)
        float2* ml = (float2*)krelB;
        constexpr int PERA = 256 / H;
        edge_alpha_csr<H><<<(NT[t] + PERA - 1) / PERA, 256, 0, stream>>>(
            rowptr, TB[t], NT[t], scB, ml);
        constexpr int PERG = 256 / (FOUT / 4);
        gather_agg_csr<FOUT, H><<<(NT[t] + PERG - 1) / PERG, 256, 0, stream>>>(
            vrelB, recs, rowptr, TB[t], NT[t], scB, ml, aggB);
        int gb2 = (NT[t] + 127) / 128;
        gemm_nl<TO, FOUT, 128><<<gb2, 256, 0, stream>>>(
            aggB, wt_out + (long)t * FOUT * FOUT, out_b + t * FOUT, outs[t],
            NT[t], FOUT, 0, do_skip ? outs[t] : (TO*)nullptr, skip_arr, t);
    }
}

extern "C" void kernel_launch(void* const* d_in, const int* in_sizes, int n_in,
                              void* d_out, int out_size, void* d_ws, size_t ws_size,
                              hipStream_t stream) {
    const float* x_paper  = (const float*)d_in[0];
    const float* x_author = (const float*)d_in[1];
    const float* x_inst   = (const float*)d_in[2];
    const int* ei[5];
    for (int e = 0; e < 5; e++) ei[e] = (const int*)d_in[3 + e];
    const float* lin_w[3] = {(const float*)d_in[8], (const float*)d_in[10], (const float*)d_in[12]};
    const float* lin_b[3] = {(const float*)d_in[9], (const float*)d_in[11], (const float*)d_in[13]};
    const float* kqv_w1 = (const float*)d_in[14];
    const float* kqv_b1 = (const float*)d_in[15];
    const float* krel1  = (const float*)d_in[16];
    const float* vrel1  = (const float*)d_in[17];
    const float* prel1  = (const float*)d_in[18];
    const float* out_w1 = (const float*)d_in[19];
    const float* out_b1 = (const float*)d_in[20];
    const float* skip1  = (const float*)d_in[21];
    const float* kqv_w2 = (const float*)d_in[22];
    const float* kqv_b2 = (const float*)d_in[23];
    const float* krel2  = (const float*)d_in[24];
    const float* vrel2  = (const float*)d_in[25];
    const float* prel2  = (const float*)d_in[26];
    const float* out_w2 = (const float*)d_in[27];
    const float* out_b2 = (const float*)d_in[28];
    const float* skip2  = (const float*)d_in[29];

    // workspace carve (all offsets 16B-aligned); total 351,520,000 B
    char* p = (char*)d_ws;
    float* xs = (float*)p;                      p += 19840000L * 4;
    __hip_bfloat16* kqvB = (__hip_bfloat16*)p;  p += 59520000L * 2;
    float* scB = (float*)p;                     p += 4000000L * 4;
    float* aggB = (float*)p;                    p += 12800000L * 4;
    int* rowptr = (int*)p;                      p += 155008L * 4;
    int* cursor = (int*)p;                      p += 155008L * 4;
    int2* recs = (int2*)p;                      p += 900000L * 8;
    __hip_bfloat16* vrelB = (__hip_bfloat16*)p; p += 19200000L * 2;
    __hip_bfloat16* krelB = (__hip_bfloat16*)p; p += 19200000L * 2;
    __hip_bfloat16* wtA = (__hip_bfloat16*)p;

    __hip_bfloat16* wt_lin[3] = {wtA, wtA + 32768, wtA + 49152};
    __hip_bfloat16* wt_kqv1 = wtA + 57344;
    __hip_bfloat16* wt_out1 = wtA + 204800;
    __hip_bfloat16* wt_kqv2 = wtA + 253952;
    __hip_bfloat16* wt_out2 = wtA + 327680;

    dim3 pb(32, 8);
    pack_wt<<<dim3(4, 8, 1), pb, 0, stream>>>(lin_w[0], wt_lin[0], 256, 128);
    pack_wt<<<dim3(4, 4, 1), pb, 0, stream>>>(lin_w[1], wt_lin[1], 128, 128);
    pack_wt<<<dim3(4, 2, 1), pb, 0, stream>>>(lin_w[2], wt_lin[2], 64, 128);
    pack_wt<<<dim3(12, 4, 3), pb, 0, stream>>>(kqv_w1, wt_kqv1, 128, 384);
    pack_wt<<<dim3(4, 4, 3), pb, 0, stream>>>(out_w1, wt_out1, 128, 128);
    pack_wt<<<dim3(6, 4, 3), pb, 0, stream>>>(kqv_w2, wt_kqv2, 128, 192);
    pack_wt<<<dim3(2, 2, 3), pb, 0, stream>>>(out_w2, wt_out2, 64, 64);

    // input projections (ReLU). N=128. paper: K=256 -> BM=64 variant.
    gemm_nl<float, 256, 64><<<1563, 256, 0, stream>>>(
        x_paper, wt_lin[0], lin_b[0], xs, 100000, 128, 1, (float*)nullptr, nullptr, 0);
    gemm_nl<float, 128, 128><<<391, 256, 0, stream>>>(
        x_author, wt_lin[1], lin_b[1], xs + 100000L * 128, 50000, 128, 1,
        (float*)nullptr, nullptr, 0);
    gemm_nl<float, 64, 128><<<40, 256, 0, stream>>>(
        x_inst, wt_lin[2], lin_b[2], xs + 150000L * 128, 5000, 128, 1,
        (float*)nullptr, nullptr, 0);

    // CSR build (shared by both layers)
    fill_u32<<<(NTOT + 255) / 256, 256, 0, stream>>>((unsigned int*)cursor, 0u, NTOT);
    for (int e = 0; e < 5; e++)
        count_edges<<<(ET_E[e] + 255) / 256, 256, 0, stream>>>(
            ei[e] + ET_E[e], ET_E[e], cursor + TB[ET_dst[e]]);
    {
        int* bsums = (int*)aggB;
        int nb = (NTOT + 1023) / 1024;  // 152
        scan_local<<<nb, 256, 0, stream>>>(cursor, rowptr, bsums, NTOT);
        scan_bsums<<<1, 256, 0, stream>>>(bsums, nb);
        scan_add<<<(NTOT + 255) / 256, 256, 0, stream>>>(rowptr, bsums, NTOT, nb);
    }
    copy_u32<<<(NTOT + 255) / 256, 256, 0, stream>>>(rowptr, cursor, NTOT);
    for (int e = 0; e < 5; e++)
        scatter_edges<<<(ET_E[e] + 255) / 256, 256, 0, stream>>>(
            ei[e], ei[e] + ET_E[e], ET_E[e], cursor + TB[ET_dst[e]], recs, ET_RO[e]);

    // layer 1 (output in-place over xs; gated skip fused into out-GEMM)
    float* outs1[3] = {xs, xs + 100000L * 128, xs + 150000L * 128};
    hgt_layer_run<float, 8>(stream, xs, kqvB, scB, rowptr, recs, aggB, krelB, vrelB,
                            wt_kqv1, kqv_b1, krel1, vrel1, prel1, wt_out1, out_b1, skip1,
                            true, outs1);

    float* out = (float*)d_out;
    float* outs2[3] = {out, out + 100000L * 64, out + 150000L * 64};
    hgt_layer_run<float, 4>(stream, xs, kqvB, scB, rowptr, recs, aggB, krelB, vrelB,
                            wt_kqv2, kqv_b2, krel2, vrel2, prel2, wt_out2, out_b2, skip2,
                            false, outs2);
}

// Round 7
// 1278.908 us; speedup vs baseline: 1.5537x; 1.1019x over previous
//
#include <hip/hip_runtime.h>
#include <hip/hip_bf16.h>
#include <math.h>

typedef __attribute__((ext_vector_type(8))) short short8;
typedef __attribute__((ext_vector_type(4))) short short4v;
typedef __attribute__((ext_vector_type(4))) float floatx4;

// ---------- type helpers ----------
__device__ __forceinline__ float ldf(const float* p) { return *p; }
__device__ __forceinline__ float ldf(const __hip_bfloat16* p) { return __bfloat162float(*p); }
__device__ __forceinline__ void stf(float* p, float v) { *p = v; }
__device__ __forceinline__ void stf(__hip_bfloat16* p, float v) { *p = __float2bfloat16(v); }
__device__ __forceinline__ float gelu1(float v) {
    return 0.5f * v * (1.f + erff(v * 0.70710678118654752f));
}
__device__ __forceinline__ short f2bf(float f) {
    unsigned int u = __float_as_uint(f);
    unsigned int r = (u + 0x7FFFu + ((u >> 16) & 1u)) >> 16;
    return (short)r;
}
__device__ __forceinline__ float bflo(unsigned int u) { return __uint_as_float(u << 16); }
__device__ __forceinline__ float bfhi(unsigned int u) { return __uint_as_float(u & 0xFFFF0000u); }
__device__ __forceinline__ void load16bf(const __hip_bfloat16* p, float* o) {
    const uint4* u = (const uint4*)p;
    uint4 w0 = u[0], w1 = u[1];
    unsigned int ws[8] = {w0.x, w0.y, w0.z, w0.w, w1.x, w1.y, w1.z, w1.w};
    #pragma unroll
    for (int i = 0; i < 8; i++) {
        o[2 * i]     = bflo(ws[i]);
        o[2 * i + 1] = bfhi(ws[i]);
    }
}

// ---------- weight pack: W[K,N] f32 -> Wt[N,K] bf16 (batched over grid.z) ----------
__global__ void pack_wt(const float* __restrict__ W, __hip_bfloat16* __restrict__ Wt,
                        int K, int N) {
    __shared__ float tile[32][33];
    long b = blockIdx.z;
    const float* Wb = W + b * K * N;
    __hip_bfloat16* Wtb = Wt + b * K * N;
    int k0 = blockIdx.y * 32, n0 = blockIdx.x * 32;
    int tx = threadIdx.x, ty = threadIdx.y;  // 32 x 8
    #pragma unroll
    for (int i = 0; i < 32; i += 8) {
        int k = k0 + ty + i, n = n0 + tx;
        tile[ty + i][tx] = (k < K && n < N) ? Wb[(long)k * N + n] : 0.f;
    }
    __syncthreads();
    #pragma unroll
    for (int i = 0; i < 32; i += 8) {
        int n = n0 + ty + i, k = k0 + tx;
        if (n < N && k < K) Wtb[(long)n * K + k] = __float2bfloat16(tile[tx][ty + i]);
    }
}

// ---------- paper projection: M x 128 = A[M,256] @ Bt[128,256], ReLU ----------
// Proven R4 kernel: BM=128, BN=128 (A fetched once), both staged, 4 waves.
__global__ __launch_bounds__(256)
void gemm_mfma_k256(const float* __restrict__ A, const __hip_bfloat16* __restrict__ Bt,
                    const float* __restrict__ bias, float* __restrict__ C, int M) {
    __shared__ short As[128][72];
    __shared__ short Bs[128][72];
    int tid = threadIdx.x;
    int row0 = blockIdx.x * 128;
    int wave = tid >> 6, lane = tid & 63;
    int rw = (wave >> 1) * 64, cw = (wave & 1) * 64;
    int lm = lane & 15, kg = lane >> 4;
    floatx4 acc[4][4];
    #pragma unroll
    for (int i = 0; i < 4; i++)
        #pragma unroll
        for (int j = 0; j < 4; j++) acc[i][j] = floatx4{0.f, 0.f, 0.f, 0.f};

    for (int k0 = 0; k0 < 256; k0 += 64) {
        #pragma unroll
        for (int p = 0; p < 8; p++) {
            int q = p * 256 + tid;
            int r = q >> 4, c = (q & 15) * 4;
            int grow = row0 + r;
            float4 v = make_float4(0.f, 0.f, 0.f, 0.f);
            if (grow < M) v = *(const float4*)(A + (long)grow * 256 + k0 + c);
            short4v s;
            s.x = f2bf(v.x); s.y = f2bf(v.y); s.z = f2bf(v.z); s.w = f2bf(v.w);
            *(short4v*)&As[r][c] = s;
        }
        #pragma unroll
        for (int p = 0; p < 4; p++) {
            int q = p * 256 + tid;
            int r = q >> 3, c = (q & 7) * 8;
            *(short8*)&Bs[r][c] = *(const short8*)(Bt + (long)r * 256 + k0 + c);
        }
        __syncthreads();
        #pragma unroll
        for (int kk = 0; kk < 2; kk++) {
            int kb = kk * 32 + kg * 8;
            short8 a[4], b[4];
            #pragma unroll
            for (int mt = 0; mt < 4; mt++) a[mt] = *(short8*)&As[rw + mt * 16 + lm][kb];
            #pragma unroll
            for (int nt = 0; nt < 4; nt++) b[nt] = *(short8*)&Bs[cw + nt * 16 + lm][kb];
            #pragma unroll
            for (int mt = 0; mt < 4; mt++)
                #pragma unroll
                for (int nt = 0; nt < 4; nt++)
                    acc[mt][nt] = __builtin_amdgcn_mfma_f32_16x16x32_bf16(
                        a[mt], b[nt], acc[mt][nt], 0, 0, 0);
        }
        __syncthreads();
    }
    int rg = (lane >> 4) * 4;
    #pragma unroll
    for (int mt = 0; mt < 4; mt++) {
        #pragma unroll
        for (int nt = 0; nt < 4; nt++) {
            int col = cw + nt * 16 + lm;
            float bsv = bias[col];
            #pragma unroll
            for (int r = 0; r < 4; r++) {
                int row = row0 + rw + mt * 16 + rg + r;
                if (row < M) C[(long)row * 128 + col] = fmaxf(acc[mt][nt][r] + bsv, 0.f);
            }
        }
    }
}

// ---------- GEMM body: A staged in LDS (full K), B direct from global, one barrier ----------
template <typename TC, int K, int BM>
__device__ __forceinline__
void gemm_nl_body(const float* __restrict__ A, const __hip_bfloat16* __restrict__ Bt,
                  const float* __restrict__ bias, TC* __restrict__ C,
                  int M, int N, int act, const TC* __restrict__ res, float aval,
                  int row0, short (*As)[K + 8]) {
    int tid = threadIdx.x;
    int wave = tid >> 6, lane = tid & 63;
    constexpr int NTT = (BM == 128) ? 2 : 1;
    int rw = (BM == 128) ? (wave >> 1) * 64 : 0;
    int cw = (BM == 128) ? (wave & 1) * 32 : wave * 16;
    int lm = lane & 15, kg = lane >> 4;
    constexpr int KD4 = K / 4;
    constexpr int NLD = BM * KD4 / 256;
    #pragma unroll
    for (int p = 0; p < NLD; p++) {
        int q = p * 256 + tid;
        int r = q / KD4, c = (q % KD4) * 4;
        int grow = row0 + r;
        float4 v = make_float4(0.f, 0.f, 0.f, 0.f);
        if (grow < M) v = *(const float4*)(A + (long)grow * K + c);
        short4v s;
        s.x = f2bf(v.x); s.y = f2bf(v.y); s.z = f2bf(v.z); s.w = f2bf(v.w);
        *(short4v*)&As[r][c] = s;
    }
    __syncthreads();
    bool do_res = (res != nullptr);
    int rg = kg * 4;
    for (int n0 = 0; n0 < N; n0 += 64) {
        floatx4 acc[4][NTT];
        #pragma unroll
        for (int i = 0; i < 4; i++)
            #pragma unroll
            for (int j = 0; j < NTT; j++) acc[i][j] = floatx4{0.f, 0.f, 0.f, 0.f};
        #pragma unroll
        for (int kk = 0; kk < K / 32; kk++) {
            int kb = kk * 32 + kg * 8;
            short8 a[4], b[NTT];
            #pragma unroll
            for (int mt = 0; mt < 4; mt++) a[mt] = *(short8*)&As[rw + mt * 16 + lm][kb];
            #pragma unroll
            for (int nt = 0; nt < NTT; nt++)
                b[nt] = *(const short8*)(Bt + (long)(n0 + cw + nt * 16 + lm) * K + kb);
            #pragma unroll
            for (int mt = 0; mt < 4; mt++)
                #pragma unroll
                for (int nt = 0; nt < NTT; nt++)
                    acc[mt][nt] = __builtin_amdgcn_mfma_f32_16x16x32_bf16(
                        a[mt], b[nt], acc[mt][nt], 0, 0, 0);
        }
        #pragma unroll
        for (int mt = 0; mt < 4; mt++) {
            #pragma unroll
            for (int nt = 0; nt < NTT; nt++) {
                int col = n0 + cw + nt * 16 + lm;
                float bsv = bias[col];
                #pragma unroll
                for (int r = 0; r < 4; r++) {
                    int row = row0 + rw + mt * 16 + rg + r;
                    if (row < M) {
                        float v = acc[mt][nt][r] + bsv;
                        if (act == 1) v = fmaxf(v, 0.f);
                        if (do_res) v = aval * v + (1.f - aval) * ldf(res + (long)row * N + col);
                        stf(C + (long)row * N + col, v);
                    }
                }
            }
        }
    }
}

template <typename TC, int K, int BM>
__global__ __launch_bounds__(256)
void gemm_nl(const float* __restrict__ A, const __hip_bfloat16* __restrict__ Bt,
             const float* __restrict__ bias, TC* __restrict__ C,
             int M, int N, int act,
             const TC* __restrict__ res, const float* __restrict__ skip_arr, int t) {
    __shared__ short As[BM][K + 8];
    float aval = 0.f;
    if (res != nullptr) { float s = skip_arr[t]; aval = 1.f / (1.f + __expf(-s)); }
    gemm_nl_body<TC, K, BM>(A, Bt, bias, C, M, N, act, res, aval, blockIdx.x * BM, As);
}

// ---------- fused per-type kqv GEMM: one dispatch for all 3 node types ----------
template <int FOUT>
__global__ __launch_bounds__(256)
void gemm_kqv_fused(const float* __restrict__ xs, const __hip_bfloat16* __restrict__ wt,
                    const float* __restrict__ kqv_b, __hip_bfloat16* __restrict__ kqvB) {
    constexpr int F3 = 3 * FOUT;
    __shared__ short As[128][136];
    int b = blockIdx.x;
    int tsel, brel, mt;
    long npre;
    if (b < 782)       { tsel = 0; brel = b;        npre = 0;      mt = 100000; }
    else if (b < 1173) { tsel = 1; brel = b - 782;  npre = 100000; mt = 50000; }
    else               { tsel = 2; brel = b - 1173; npre = 150000; mt = 5000; }
    gemm_nl_body<__hip_bfloat16, 128, 128>(
        xs + npre * 128, wt + (long)tsel * 128 * F3, kqv_b + tsel * F3,
        kqvB + npre * F3, mt, F3, 0, (const __hip_bfloat16*)nullptr, 0.f,
        brel * 128, As);
}

// ---------- out-GEMM with prefetch ordering: B first (L2, oldest in vmcnt queue ->
// MFMA consumes without draining), then res (HBM, stays in flight under compute),
// then MFMA, epilogue uses prefetched regs. N == K (128 or 64). ----------
template <typename TC, int K, bool DORES>
__global__ __launch_bounds__(256)
void gemm_out(const float* __restrict__ A, const __hip_bfloat16* __restrict__ Bt,
              const float* __restrict__ bias, TC* __restrict__ C,
              int M, int N,
              const TC* __restrict__ res, const float* __restrict__ skip_arr, int t) {
    __shared__ short As[128][K + 8];
    int tid = threadIdx.x;
    int row0 = blockIdx.x * 128;
    int wave = tid >> 6, lane = tid & 63;
    int rw = (wave >> 1) * 64, cw = (wave & 1) * 32;
    int lm = lane & 15, kg = lane >> 4;
    constexpr int KD4 = K / 4;
    #pragma unroll
    for (int p = 0; p < 128 * KD4 / 256; p++) {
        int q = p * 256 + tid;
        int r = q / KD4, c = (q % KD4) * 4;
        int grow = row0 + r;
        float4 v = make_float4(0.f, 0.f, 0.f, 0.f);
        if (grow < M) v = *(const float4*)(A + (long)grow * K + c);
        short4v s;
        s.x = f2bf(v.x); s.y = f2bf(v.y); s.z = f2bf(v.z); s.w = f2bf(v.w);
        *(short4v*)&As[r][c] = s;
    }
    float aval = 0.f;
    if (DORES) { float sv = skip_arr[t]; aval = 1.f / (1.f + __expf(-sv)); }
    int rg = kg * 4;
    __syncthreads();
    for (int n0 = 0; n0 < N; n0 += 64) {
        // B preload (issued FIRST: oldest vm ops; compute waits only on these)
        short8 bfr[K / 32][2];
        #pragma unroll
        for (int kk = 0; kk < K / 32; kk++)
            #pragma unroll
            for (int nt = 0; nt < 2; nt++)
                bfr[kk][nt] = *(const short8*)(
                    Bt + (long)(n0 + cw + nt * 16 + lm) * K + kk * 32 + kg * 8);
        float bsv[2];
        #pragma unroll
        for (int nt = 0; nt < 2; nt++) bsv[nt] = bias[n0 + cw + nt * 16 + lm];
        // res preload (HBM): newest vm ops; overlap with the MFMA chain below
        float rv[2][4][4];
        if (DORES) {
            #pragma unroll
            for (int nt = 0; nt < 2; nt++)
                #pragma unroll
                for (int mt = 0; mt < 4; mt++)
                    #pragma unroll
                    for (int r = 0; r < 4; r++) {
                        int row = row0 + rw + mt * 16 + rg + r;
                        rv[nt][mt][r] = (row < M)
                            ? ldf(res + (long)row * N + n0 + cw + nt * 16 + lm) : 0.f;
                    }
        }
        floatx4 acc[4][2];
        #pragma unroll
        for (int i = 0; i < 4; i++)
            #pragma unroll
            for (int j = 0; j < 2; j++) acc[i][j] = floatx4{0.f, 0.f, 0.f, 0.f};
        #pragma unroll
        for (int kk = 0; kk < K / 32; kk++) {
            int kb = kk * 32 + kg * 8;
            short8 a[4];
            #pragma unroll
            for (int mt = 0; mt < 4; mt++) a[mt] = *(short8*)&As[rw + mt * 16 + lm][kb];
            #pragma unroll
            for (int mt = 0; mt < 4; mt++)
                #pragma unroll
                for (int nt = 0; nt < 2; nt++)
                    acc[mt][nt] = __builtin_amdgcn_mfma_f32_16x16x32_bf16(
                        a[mt], bfr[kk][nt], acc[mt][nt], 0, 0, 0);
        }
        #pragma unroll
        for (int mt = 0; mt < 4; mt++) {
            #pragma unroll
            for (int nt = 0; nt < 2; nt++) {
                int col = n0 + cw + nt * 16 + lm;
                #pragma unroll
                for (int r = 0; r < 4; r++) {
                    int row = row0 + rw + mt * 16 + rg + r;
                    if (row < M) {
                        float v = acc[mt][nt][r] + bsv[nt];
                        if (DORES) v = aval * v + (1.f - aval) * rv[nt][mt][r];
                        stf(C + (long)row * N + col, v);
                    }
                }
            }
        }
    }
}

// ---------- small utils ----------
__global__ void fill_u32(unsigned int* __restrict__ p, unsigned int v, int n) {
    int i = blockIdx.x * blockDim.x + threadIdx.x;
    if (i < n) p[i] = v;
}
__global__ void copy_u32(const int* __restrict__ a, int* __restrict__ b, int n) {
    int i = blockIdx.x * blockDim.x + threadIdx.x;
    if (i < n) b[i] = a[i];
}

// ---------- CSR build ----------
__global__ void count_edges(const int* __restrict__ dst, int E, int* __restrict__ counts) {
    int i = blockIdx.x * blockDim.x + threadIdx.x;
    if (i < E) atomicAdd(&counts[dst[i]], 1);
}

__global__ __launch_bounds__(256) void scan_local(const int* __restrict__ counts,
                                                  int* __restrict__ rowptr,
                                                  int* __restrict__ bsums, int n) {
    __shared__ int sh[256];
    int t = threadIdx.x;
    int base = blockIdx.x * 1024;
    int lv[4]; int s = 0;
    #pragma unroll
    for (int q = 0; q < 4; q++) {
        int i = base + t * 4 + q;
        lv[q] = (i < n) ? counts[i] : 0;
        s += lv[q];
    }
    sh[t] = s;
    __syncthreads();
    #pragma unroll
    for (int off = 1; off < 256; off <<= 1) {
        int add = (t >= off) ? sh[t - off] : 0;
        __syncthreads();
        sh[t] += add;
        __syncthreads();
    }
    int excl = sh[t] - s;
    if (t == 255) bsums[blockIdx.x] = sh[255];
    #pragma unroll
    for (int q = 0; q < 4; q++) {
        int i = base + t * 4 + q;
        if (i < n) rowptr[i] = excl;
        excl += lv[q];
    }
}
__global__ __launch_bounds__(256) void scan_bsums(int* __restrict__ bsums, int nb) {
    __shared__ int sh[256];
    int t = threadIdx.x;
    int v = (t < nb) ? bsums[t] : 0;
    sh[t] = v;
    __syncthreads();
    #pragma unroll
    for (int off = 1; off < 256; off <<= 1) {
        int add = (t >= off) ? sh[t - off] : 0;
        __syncthreads();
        sh[t] += add;
        __syncthreads();
    }
    if (t < nb) bsums[t] = sh[t] - v;
    if (t == nb - 1) bsums[nb] = sh[t];
}
__global__ void scan_add(int* __restrict__ rowptr, const int* __restrict__ bsums,
                         int n, int nb) {
    int i = blockIdx.x * blockDim.x + threadIdx.x;
    if (i < n) rowptr[i] += bsums[i >> 10];
    if (i == 0) rowptr[n] = bsums[nb];
}

// rec = (vrow, dst): vrow = per-edge-type row base in krelB/vrelB + local src index.
__global__ void scatter_edges(const int* __restrict__ src, const int* __restrict__ dst, int E,
                              int* __restrict__ cursor, int2* __restrict__ recs,
                              int vrow_base) {
    int i = blockIdx.x * blockDim.x + threadIdx.x;
    if (i >= E) return;
    int pos = atomicAdd(&cursor[dst[i]], 1);
    recs[pos] = make_int2(vrow_base + src[i], dst[i]);
}

// ---------- fused relation transforms: all (edge,k/v) segments of one dst type in
// one dispatch; segment table passed by value; 128 rows per block. ----------
struct RelCfg {
    long in_off[4];
    int rel_off[4], prel_off[4], robase[4], nrows[4], isk[4];
    int blk0[5];
    int nseg;
};

template <int H>
__global__ __launch_bounds__(256)
void rel_fused(const __hip_bfloat16* __restrict__ kqvB,
               const float* __restrict__ krel, const float* __restrict__ vrel,
               const float* __restrict__ prel,
               __hip_bfloat16* __restrict__ krelB, __hip_bfloat16* __restrict__ vrelB,
               RelCfg cfg) {
    constexpr int FOUT = H * 16;
    const int F3 = 3 * FOUT;
    int s = 0;
    while (s + 1 < cfg.nseg && (int)blockIdx.x >= cfg.blk0[s + 1]) s++;
    __shared__ float sR[H * 256];
    int isk = cfg.isk[s];
    const float* rel = (isk ? krel : vrel) + cfg.rel_off[s];
    for (int i = threadIdx.x; i < H * 256; i += 256) {
        float f = isk ? prel[cfg.prel_off[s] + (i >> 8)] * 0.25f : 1.f;
        sR[i] = rel[i] * f;
    }
    __syncthreads();
    constexpr int PER = 256 / FOUT;
    int slot = threadIdx.x / FOUT;
    int j = threadIdx.x - slot * FOUT;
    int h = j >> 4;
    const float* rp = sR + h * 256 + (j & 15);
    __hip_bfloat16* outp = (isk ? krelB : vrelB) + (long)cfg.robase[s] * FOUT;
    const __hip_bfloat16* inp = kqvB + cfg.in_off[s];
    int row0 = (blockIdx.x - cfg.blk0[s]) * 128;
    int rend = min(row0 + 128, cfg.nrows[s]);
    for (int d = row0 + slot; d < rend; d += PER) {
        float xv[16];
        load16bf(inp + (long)d * F3 + h * 16, xv);
        float acc = 0.f;
        #pragma unroll
        for (int i = 0; i < 16; i++) acc = fmaf(xv[i], rp[i * 16], acc);
        outp[(long)d * FOUT + j] = __float2bfloat16(acc);
    }
}

// ---------- scores in CSR-slot order: sc[(slot-base)*H + h] ----------
template <int H>
__global__ void edge_score_csr(const __hip_bfloat16* __restrict__ krelbuf,
                               const __hip_bfloat16* __restrict__ Qdst, int stride,
                               const int2* __restrict__ recs, const int* __restrict__ rowptr,
                               int tb, long nwork, float* __restrict__ sc_out) {
    long tid = blockIdx.x * (long)blockDim.x + threadIdx.x;
    if (tid >= nwork) return;
    constexpr int FOUT = H * 16;
    int sl = (int)(tid / H);
    int h = (int)(tid - (long)sl * H);
    int base = rowptr[tb];
    int2 rec = recs[base + sl];
    float kv[16], qv[16];
    load16bf(krelbuf + (long)rec.x * FOUT + h * 16, kv);
    load16bf(Qdst + (long)rec.y * stride + h * 16, qv);
    float acc = 0.f;
    #pragma unroll
    for (int i = 0; i < 16; i++) acc = fmaf(kv[i], qv[i], acc);
    sc_out[tid] = acc;
}

// ---------- segment softmax stats: sequential CSR-ordered score reads ----------
template <int H>
__global__ __launch_bounds__(256)
void edge_alpha_csr(const int* __restrict__ rowptr, int tb, int ndst,
                    const float* __restrict__ sc, float2* __restrict__ ml) {
    constexpr int PER = 256 / H;
    int slot = threadIdx.x / H;
    int h = threadIdx.x - slot * H;
    int d = blockIdx.x * PER + slot;
    if (d >= ndst) return;
    int base = rowptr[tb];
    int r0 = rowptr[tb + d], r1 = rowptr[tb + d + 1];
    const float* scp = sc + (long)(r0 - base) * H + h;
    float m = -1e30f, l = 0.f;
    for (int n = r1 - r0; n > 0; --n, scp += H) {
        float s = *scp;
        float mn = fmaxf(m, s);
        float r = __expf(m - mn);
        float w = __expf(s - mn);
        l = fmaf(l, r, w);
        m = mn;
    }
    float inv = (l > 0.f) ? 1.f / l : 0.f;
    ml[(long)d * H + h] = make_float2(m, inv);
}

// ---------- gather: 4 channels/thread, sequential sc, precomputed vrow ----------
template <int FOUT, int H>
__global__ void gather_agg_csr(const __hip_bfloat16* __restrict__ vrelbuf,
                               const int2* __restrict__ recs, const int* __restrict__ rowptr,
                               int tb, int ndst,
                               const float* __restrict__ sc,
                               const float2* __restrict__ ml,
                               float* __restrict__ agg) {
    constexpr int TPD = FOUT / 4;       // threads per dst
    constexpr int PER = 256 / TPD;
    int slot = threadIdx.x / TPD;
    int jj = threadIdx.x - slot * TPD;
    int j4 = jj * 4;
    int d = blockIdx.x * PER + slot;
    if (d >= ndst) return;
    int h = j4 >> 4;
    float2 mh = ml[(long)d * H + h];
    int base = rowptr[tb];
    int r0 = rowptr[tb + d], r1 = rowptr[tb + d + 1];
    const float* scp = sc + (long)(r0 - base) * H + h;
    const int2* rp = recs + r0;
    int n = r1 - r0;
    float a0[4] = {0.f, 0.f, 0.f, 0.f}, a1[4] = {0.f, 0.f, 0.f, 0.f};
    int i = 0;
    for (; i + 1 < n; i += 2) {
        int2 ra = rp[i], rb = rp[i + 1];
        float s0 = scp[(long)i * H], s1 = scp[(long)(i + 1) * H];
        float w0 = __expf(s0 - mh.x) * mh.y;
        float w1 = __expf(s1 - mh.x) * mh.y;
        uint2 va = *(const uint2*)(vrelbuf + (long)ra.x * FOUT + j4);
        uint2 vb = *(const uint2*)(vrelbuf + (long)rb.x * FOUT + j4);
        a0[0] = fmaf(w0, bflo(va.x), a0[0]);
        a0[1] = fmaf(w0, bfhi(va.x), a0[1]);
        a0[2] = fmaf(w0, bflo(va.y), a0[2]);
        a0[3] = fmaf(w0, bfhi(va.y), a0[3]);
        a1[0] = fmaf(w1, bflo(vb.x), a1[0]);
        a1[1] = fmaf(w1, bfhi(vb.x), a1[1]);
        a1[2] = fmaf(w1, bflo(vb.y), a1[2]);
        a1[3] = fmaf(w1, bfhi(vb.y), a1[3]);
    }
    if (i < n) {
        int2 ra = rp[i];
        float w0 = __expf(scp[(long)i * H] - mh.x) * mh.y;
        uint2 va = *(const uint2*)(vrelbuf + (long)ra.x * FOUT + j4);
        a0[0] = fmaf(w0, bflo(va.x), a0[0]);
        a0[1] = fmaf(w0, bfhi(va.x), a0[1]);
        a0[2] = fmaf(w0, bflo(va.y), a0[2]);
        a0[3] = fmaf(w0, bfhi(va.y), a0[3]);
    }
    float4 o;
    o.x = gelu1(a0[0] + a1[0]);
    o.y = gelu1(a0[1] + a1[1]);
    o.z = gelu1(a0[2] + a1[2]);
    o.w = gelu1(a0[3] + a1[3]);
    *(float4*)(agg + (long)d * FOUT + j4) = o;
}

// ---------- orchestration ----------
static const int ET_src[5] = {1, 0, 0, 1, 2};
static const int ET_dst[5] = {0, 0, 1, 2, 1};
static const int ET_E[5]   = {250000, 250000, 200000, 100000, 100000};
static const int ET_RO[5]  = {0, 50000, 0, 0, 100000};  // vrow base (rocur layout)
static const int NT[3]     = {100000, 50000, 5000};
static const long NPRE[3]  = {0, 100000, 150000};
static const int TB[3]     = {0, 100000, 150000};
static const int SL[3]     = {500000, 300000, 100000};  // incoming edges per dst type
static const int NTOT      = 155000;

template <typename TO, int H>
static void hgt_layer_run(hipStream_t stream,
                          const float* xs, __hip_bfloat16* kqvB, float* scB,
                          const int* rowptr, const int2* recs, float* aggB,
                          __hip_bfloat16* krelB, __hip_bfloat16* vrelB,
                          const __hip_bfloat16* wt_kqv, const float* kqv_b,
                          const float* krel, const float* vrel, const float* prel,
                          const __hip_bfloat16* wt_out, const float* out_b,
                          const float* skip_arr,
                          TO* const* outs) {
    constexpr int FOUT = H * 16;
    constexpr bool DOSKIP = (H == 8);   // L1 only: fout == hidden
    const int F3 = 3 * FOUT;
    gemm_kqv_fused<FOUT><<<1213, 256, 0, stream>>>(xs, wt_kqv, kqv_b, kqvB);
    for (int t = 0; t < 3; t++) {
        // fused rel transforms for all (edge, k/v) segments of this dst type
        RelCfg cfg;
        int ns = 0, rocur = 0, blks = 0;
        for (int e = 0; e < 5; e++) {
            if (ET_dst[e] != t) continue;
            int ts = ET_src[e];
            cfg.in_off[ns] = NPRE[ts] * F3 + 2 * FOUT;   // v
            cfg.rel_off[ns] = e * H * 256; cfg.prel_off[ns] = 0;
            cfg.robase[ns] = rocur; cfg.nrows[ns] = NT[ts]; cfg.isk[ns] = 0;
            cfg.blk0[ns] = blks; blks += (NT[ts] + 127) / 128; ns++;
            cfg.in_off[ns] = NPRE[ts] * F3;              // k
            cfg.rel_off[ns] = e * H * 256; cfg.prel_off[ns] = e * H;
            cfg.robase[ns] = rocur; cfg.nrows[ns] = NT[ts]; cfg.isk[ns] = 1;
            cfg.blk0[ns] = blks; blks += (NT[ts] + 127) / 128; ns++;
            rocur += NT[ts];
        }
        cfg.blk0[ns] = blks; cfg.nseg = ns;
        rel_fused<H><<<blks, 256, 0, stream>>>(kqvB, krel, vrel, prel, krelB, vrelB, cfg);

        long nwork = (long)SL[t] * H;
        edge_score_csr<H><<<(int)((nwork + 255) / 256), 256, 0, stream>>>(
            krelB, kqvB + NPRE[t] * F3 + FOUT, F3, recs, rowptr, TB[t], nwork, scB);
        // (m, 1/l) per (dst,h); buffer aliases krelB (dead after edge_score_csr)
        float2* ml = (float2*)krelB;
        constexpr int PERA = 256 / H;
        edge_alpha_csr<H><<<(NT[t] + PERA - 1) / PERA, 256, 0, stream>>>(
            rowptr, TB[t], NT[t], scB, ml);
        constexpr int PERG = 256 / (FOUT / 4);
        gather_agg_csr<FOUT, H><<<(NT[t] + PERG - 1) / PERG, 256, 0, stream>>>(
            vrelB, recs, rowptr, TB[t], NT[t], scB, ml, aggB);
        int gb2 = (NT[t] + 127) / 128;
        gemm_out<TO, FOUT, DOSKIP><<<gb2, 256, 0, stream>>>(
            aggB, wt_out + (long)t * FOUT * FOUT, out_b + t * FOUT, outs[t],
            NT[t], FOUT, DOSKIP ? outs[t] : (TO*)nullptr, skip_arr, t);
    }
}

extern "C" void kernel_launch(void* const* d_in, const int* in_sizes, int n_in,
                              void* d_out, int out_size, void* d_ws, size_t ws_size,
                              hipStream_t stream) {
    const float* x_paper  = (const float*)d_in[0];
    const float* x_author = (const float*)d_in[1];
    const float* x_inst   = (const float*)d_in[2];
    const int* ei[5];
    for (int e = 0; e < 5; e++) ei[e] = (const int*)d_in[3 + e];
    const float* lin_w[3] = {(const float*)d_in[8], (const float*)d_in[10], (const float*)d_in[12]};
    const float* lin_b[3] = {(const float*)d_in[9], (const float*)d_in[11], (const float*)d_in[13]};
    const float* kqv_w1 = (const float*)d_in[14];
    const float* kqv_b1 = (const float*)d_in[15];
    const float* krel1  = (const float*)d_in[16];
    const float* vrel1  = (const float*)d_in[17];
    const float* prel1  = (const float*)d_in[18];
    const float* out_w1 = (const float*)d_in[19];
    const float* out_b1 = (const float*)d_in[20];
    const float* skip1  = (const float*)d_in[21];
    const float* kqv_w2 = (const float*)d_in[22];
    const float* kqv_b2 = (const float*)d_in[23];
    const float* krel2  = (const float*)d_in[24];
    const float* vrel2  = (const float*)d_in[25];
    const float* prel2  = (const float*)d_in[26];
    const float* out_w2 = (const float*)d_in[27];
    const float* out_b2 = (const float*)d_in[28];
    const float* skip2  = (const float*)d_in[29];

    // workspace carve (all offsets 16B-aligned); total 351,520,000 B
    char* p = (char*)d_ws;
    float* xs = (float*)p;                      p += 19840000L * 4;
    __hip_bfloat16* kqvB = (__hip_bfloat16*)p;  p += 59520000L * 2;
    float* scB = (float*)p;                     p += 4000000L * 4;
    float* aggB = (float*)p;                    p += 12800000L * 4;
    int* rowptr = (int*)p;                      p += 155008L * 4;
    int* cursor = (int*)p;                      p += 155008L * 4;
    int2* recs = (int2*)p;                      p += 900000L * 8;
    __hip_bfloat16* vrelB = (__hip_bfloat16*)p; p += 19200000L * 2;
    __hip_bfloat16* krelB = (__hip_bfloat16*)p; p += 19200000L * 2;
    __hip_bfloat16* wtA = (__hip_bfloat16*)p;

    __hip_bfloat16* wt_lin[3] = {wtA, wtA + 32768, wtA + 49152};
    __hip_bfloat16* wt_kqv1 = wtA + 57344;
    __hip_bfloat16* wt_out1 = wtA + 204800;
    __hip_bfloat16* wt_kqv2 = wtA + 253952;
    __hip_bfloat16* wt_out2 = wtA + 327680;

    dim3 pb(32, 8);
    pack_wt<<<dim3(4, 8, 1), pb, 0, stream>>>(lin_w[0], wt_lin[0], 256, 128);
    pack_wt<<<dim3(4, 4, 1), pb, 0, stream>>>(lin_w[1], wt_lin[1], 128, 128);
    pack_wt<<<dim3(4, 2, 1), pb, 0, stream>>>(lin_w[2], wt_lin[2], 64, 128);
    pack_wt<<<dim3(12, 4, 3), pb, 0, stream>>>(kqv_w1, wt_kqv1, 128, 384);
    pack_wt<<<dim3(4, 4, 3), pb, 0, stream>>>(out_w1, wt_out1, 128, 128);
    pack_wt<<<dim3(6, 4, 3), pb, 0, stream>>>(kqv_w2, wt_kqv2, 128, 192);
    pack_wt<<<dim3(2, 2, 3), pb, 0, stream>>>(out_w2, wt_out2, 64, 64);

    // input projections (ReLU). N=128. paper: proven dedicated K=256 BN=128 kernel.
    gemm_mfma_k256<<<782, 256, 0, stream>>>(x_paper, wt_lin[0], lin_b[0], xs, 100000);
    gemm_nl<float, 128, 128><<<391, 256, 0, stream>>>(
        x_author, wt_lin[1], lin_b[1], xs + 100000L * 128, 50000, 128, 1,
        (float*)nullptr, nullptr, 0);
    gemm_nl<float, 64, 128><<<40, 256, 0, stream>>>(
        x_inst, wt_lin[2], lin_b[2], xs + 150000L * 128, 5000, 128, 1,
        (float*)nullptr, nullptr, 0);

    // CSR build (shared by both layers)
    fill_u32<<<(NTOT + 255) / 256, 256, 0, stream>>>((unsigned int*)cursor, 0u, NTOT);
    for (int e = 0; e < 5; e++)
        count_edges<<<(ET_E[e] + 255) / 256, 256, 0, stream>>>(
            ei[e] + ET_E[e], ET_E[e], cursor + TB[ET_dst[e]]);
    {
        int* bsums = (int*)aggB;
        int nb = (NTOT + 1023) / 1024;  // 152
        scan_local<<<nb, 256, 0, stream>>>(cursor, rowptr, bsums, NTOT);
        scan_bsums<<<1, 256, 0, stream>>>(bsums, nb);
        scan_add<<<(NTOT + 255) / 256, 256, 0, stream>>>(rowptr, bsums, NTOT, nb);
    }
    copy_u32<<<(NTOT + 255) / 256, 256, 0, stream>>>(rowptr, cursor, NTOT);
    for (int e = 0; e < 5; e++)
        scatter_edges<<<(ET_E[e] + 255) / 256, 256, 0, stream>>>(
            ei[e], ei[e] + ET_E[e], ET_E[e], cursor + TB[ET_dst[e]], recs, ET_RO[e]);

    // layer 1 (output in-place over xs; gated skip fused into out-GEMM)
    float* outs1[3] = {xs, xs + 100000L * 128, xs + 150000L * 128};
    hgt_layer_run<float, 8>(stream, xs, kqvB, scB, rowptr, recs, aggB, krelB, vrelB,
                            wt_kqv1, kqv_b1, krel1, vrel1, prel1, wt_out1, out_b1, skip1,
                            outs1);

    float* out = (float*)d_out;
    float* outs2[3] = {out, out + 100000L * 64, out + 150000L * 64};
    hgt_layer_run<float, 4>(stream, xs, kqvB, scB, rowptr, recs, aggB, krelB, vrelB,
                            wt_kqv2, kqv_b2, krel2, vrel2, prel2, wt_out2, out_b2, skip2,
                            outs2);
}

// Round 8
// 1081.410 us; speedup vs baseline: 1.8374x; 1.1826x over previous
//
#include <hip/hip_runtime.h>
#include <hip/hip_bf16.h>
#include <math.h>

typedef __attribute__((ext_vector_type(8))) short short8;
typedef __attribute__((ext_vector_type(4))) short short4v;
typedef __attribute__((ext_vector_type(4))) float floatx4;

// ---------- type helpers ----------
__device__ __forceinline__ float ldf(const float* p) { return *p; }
__device__ __forceinline__ float ldf(const __hip_bfloat16* p) { return __bfloat162float(*p); }
__device__ __forceinline__ void stf(float* p, float v) { *p = v; }
__device__ __forceinline__ void stf(__hip_bfloat16* p, float v) { *p = __float2bfloat16(v); }
__device__ __forceinline__ float gelu1(float v) {
    return 0.5f * v * (1.f + erff(v * 0.70710678118654752f));
}
__device__ __forceinline__ short f2bf(float f) {
    unsigned int u = __float_as_uint(f);
    unsigned int r = (u + 0x7FFFu + ((u >> 16) & 1u)) >> 16;
    return (short)r;
}
__device__ __forceinline__ float bflo(unsigned int u) { return __uint_as_float(u << 16); }
__device__ __forceinline__ float bfhi(unsigned int u) { return __uint_as_float(u & 0xFFFF0000u); }
__device__ __forceinline__ void load16bf(const __hip_bfloat16* p, float* o) {
    const uint4* u = (const uint4*)p;
    uint4 w0 = u[0], w1 = u[1];
    unsigned int ws[8] = {w0.x, w0.y, w0.z, w0.w, w1.x, w1.y, w1.z, w1.w};
    #pragma unroll
    for (int i = 0; i < 8; i++) {
        o[2 * i]     = bflo(ws[i]);
        o[2 * i + 1] = bfhi(ws[i]);
    }
}

// ---------- weight pack: W[K,N] f32 -> Wt[N,K] bf16 (batched over grid.z) ----------
__global__ void pack_wt(const float* __restrict__ W, __hip_bfloat16* __restrict__ Wt,
                        int K, int N) {
    __shared__ float tile[32][33];
    long b = blockIdx.z;
    const float* Wb = W + b * K * N;
    __hip_bfloat16* Wtb = Wt + b * K * N;
    int k0 = blockIdx.y * 32, n0 = blockIdx.x * 32;
    int tx = threadIdx.x, ty = threadIdx.y;  // 32 x 8
    #pragma unroll
    for (int i = 0; i < 32; i += 8) {
        int k = k0 + ty + i, n = n0 + tx;
        tile[ty + i][tx] = (k < K && n < N) ? Wb[(long)k * N + n] : 0.f;
    }
    __syncthreads();
    #pragma unroll
    for (int i = 0; i < 32; i += 8) {
        int n = n0 + ty + i, k = k0 + tx;
        if (n < N && k < K) Wtb[(long)n * K + k] = __float2bfloat16(tile[tx][ty + i]);
    }
}

// ---------- compose kqv' weights: fold relation transforms into kqv GEMM ----------
// k_rel = x @ (W_k @ bdiag(Rk)·prel·0.25) + b_k @ bdiag(Rk)·...  (all linear).
// 13 FOUT-col blocks: ts0:[q,kR_e1,vR_e1,kR_e2,vR_e2] ts1:[q,kR_e0,vR_e0,kR_e3,vR_e3]
// ts2:[q,kR_e4,vR_e4]. Wt' layout: [blk][col][k=128] bf16; bias' f32 per col.
template <int H>
__global__ __launch_bounds__(256)
void compose_kqv(const float* __restrict__ kqv_w, const float* __restrict__ kqv_b,
                 const float* __restrict__ krel, const float* __restrict__ vrel,
                 const float* __restrict__ prel,
                 __hip_bfloat16* __restrict__ wt, float* __restrict__ biasB) {
    constexpr int FOUT = H * 16;
    constexpr int F3 = 3 * FOUT;
    const int TS[13]   = {0,0,0,0,0, 1,1,1,1,1, 2,2,2};
    const int MODE[13] = {0,1,2,1,2, 0,1,2,1,2, 0,1,2};  // 0=q copy, 1=kR, 2=vR
    const int EDG[13]  = {0,1,1,2,2, 0,0,0,3,3, 0,4,4};
    long g = blockIdx.x * 256L + threadIdx.x;
    constexpr long PER = (long)FOUT * 128;
    int blk = (int)(g / PER);
    if (blk >= 13) return;
    int idx = (int)(g - blk * PER);
    int c = idx >> 7, k = idx & 127;
    int ts = TS[blk], mode = MODE[blk], e = EDG[blk];
    const float* W = kqv_w + (long)ts * 128 * F3 + (long)k * F3;
    const float* Bv = kqv_b + ts * F3;
    float outw, outb;
    if (mode == 0) {
        outw = W[FOUT + c];          // q is the middle third (split order: k,q,v)
        outb = Bv[FOUT + c];
    } else {
        int h = c >> 4, eo = c & 15;
        int srcb = (mode == 1) ? 0 : 2 * FOUT;
        const float* R = ((mode == 1) ? krel : vrel) + ((long)e * H + h) * 256 + eo;
        float scale = (mode == 1) ? prel[e * H + h] * 0.25f : 1.f;
        float aw = 0.f, ab = 0.f;
        #pragma unroll
        for (int i = 0; i < 16; i++) {
            float r = R[i * 16];
            aw = fmaf(W[srcb + h * 16 + i], r, aw);
            ab = fmaf(Bv[srcb + h * 16 + i], r, ab);
        }
        outw = aw * scale; outb = ab * scale;
    }
    wt[blk * PER + (long)c * 128 + k] = __float2bfloat16(outw);
    if (k == 0) biasB[blk * FOUT + c] = outb;
}

// ---------- paper projection: M x 128 = A[M,256] @ Bt[128,256], ReLU ----------
__global__ __launch_bounds__(256)
void gemm_mfma_k256(const float* __restrict__ A, const __hip_bfloat16* __restrict__ Bt,
                    const float* __restrict__ bias, float* __restrict__ C, int M) {
    __shared__ short As[128][72];
    __shared__ short Bs[128][72];
    int tid = threadIdx.x;
    int row0 = blockIdx.x * 128;
    int wave = tid >> 6, lane = tid & 63;
    int rw = (wave >> 1) * 64, cw = (wave & 1) * 64;
    int lm = lane & 15, kg = lane >> 4;
    floatx4 acc[4][4];
    #pragma unroll
    for (int i = 0; i < 4; i++)
        #pragma unroll
        for (int j = 0; j < 4; j++) acc[i][j] = floatx4{0.f, 0.f, 0.f, 0.f};

    for (int k0 = 0; k0 < 256; k0 += 64) {
        #pragma unroll
        for (int p = 0; p < 8; p++) {
            int q = p * 256 + tid;
            int r = q >> 4, c = (q & 15) * 4;
            int grow = row0 + r;
            float4 v = make_float4(0.f, 0.f, 0.f, 0.f);
            if (grow < M) v = *(const float4*)(A + (long)grow * 256 + k0 + c);
            short4v s;
            s.x = f2bf(v.x); s.y = f2bf(v.y); s.z = f2bf(v.z); s.w = f2bf(v.w);
            *(short4v*)&As[r][c] = s;
        }
        #pragma unroll
        for (int p = 0; p < 4; p++) {
            int q = p * 256 + tid;
            int r = q >> 3, c = (q & 7) * 8;
            *(short8*)&Bs[r][c] = *(const short8*)(Bt + (long)r * 256 + k0 + c);
        }
        __syncthreads();
        #pragma unroll
        for (int kk = 0; kk < 2; kk++) {
            int kb = kk * 32 + kg * 8;
            short8 a[4], b[4];
            #pragma unroll
            for (int mt = 0; mt < 4; mt++) a[mt] = *(short8*)&As[rw + mt * 16 + lm][kb];
            #pragma unroll
            for (int nt = 0; nt < 4; nt++) b[nt] = *(short8*)&Bs[cw + nt * 16 + lm][kb];
            #pragma unroll
            for (int mt = 0; mt < 4; mt++)
                #pragma unroll
                for (int nt = 0; nt < 4; nt++)
                    acc[mt][nt] = __builtin_amdgcn_mfma_f32_16x16x32_bf16(
                        a[mt], b[nt], acc[mt][nt], 0, 0, 0);
        }
        __syncthreads();
    }
    int rg = (lane >> 4) * 4;
    #pragma unroll
    for (int mt = 0; mt < 4; mt++) {
        #pragma unroll
        for (int nt = 0; nt < 4; nt++) {
            int col = cw + nt * 16 + lm;
            float bsv = bias[col];
            #pragma unroll
            for (int r = 0; r < 4; r++) {
                int row = row0 + rw + mt * 16 + rg + r;
                if (row < M) C[(long)row * 128 + col] = fmaxf(acc[mt][nt][r] + bsv, 0.f);
            }
        }
    }
}

// ---------- GEMM body: A staged in LDS (full K), B direct from global, one barrier ----------
template <typename TC, int K, int BM>
__device__ __forceinline__
void gemm_nl_body(const float* __restrict__ A, const __hip_bfloat16* __restrict__ Bt,
                  const float* __restrict__ bias, TC* __restrict__ C,
                  int M, int N, int act, const TC* __restrict__ res, float aval,
                  int row0, short (*As)[K + 8]) {
    int tid = threadIdx.x;
    int wave = tid >> 6, lane = tid & 63;
    constexpr int NTT = (BM == 128) ? 2 : 1;
    int rw = (BM == 128) ? (wave >> 1) * 64 : 0;
    int cw = (BM == 128) ? (wave & 1) * 32 : wave * 16;
    int lm = lane & 15, kg = lane >> 4;
    constexpr int KD4 = K / 4;
    constexpr int NLD = BM * KD4 / 256;
    #pragma unroll
    for (int p = 0; p < NLD; p++) {
        int q = p * 256 + tid;
        int r = q / KD4, c = (q % KD4) * 4;
        int grow = row0 + r;
        float4 v = make_float4(0.f, 0.f, 0.f, 0.f);
        if (grow < M) v = *(const float4*)(A + (long)grow * K + c);
        short4v s;
        s.x = f2bf(v.x); s.y = f2bf(v.y); s.z = f2bf(v.z); s.w = f2bf(v.w);
        *(short4v*)&As[r][c] = s;
    }
    __syncthreads();
    bool do_res = (res != nullptr);
    int rg = kg * 4;
    for (int n0 = 0; n0 < N; n0 += 64) {
        floatx4 acc[4][NTT];
        #pragma unroll
        for (int i = 0; i < 4; i++)
            #pragma unroll
            for (int j = 0; j < NTT; j++) acc[i][j] = floatx4{0.f, 0.f, 0.f, 0.f};
        #pragma unroll
        for (int kk = 0; kk < K / 32; kk++) {
            int kb = kk * 32 + kg * 8;
            short8 a[4], b[NTT];
            #pragma unroll
            for (int mt = 0; mt < 4; mt++) a[mt] = *(short8*)&As[rw + mt * 16 + lm][kb];
            #pragma unroll
            for (int nt = 0; nt < NTT; nt++)
                b[nt] = *(const short8*)(Bt + (long)(n0 + cw + nt * 16 + lm) * K + kb);
            #pragma unroll
            for (int mt = 0; mt < 4; mt++)
                #pragma unroll
                for (int nt = 0; nt < NTT; nt++)
                    acc[mt][nt] = __builtin_amdgcn_mfma_f32_16x16x32_bf16(
                        a[mt], b[nt], acc[mt][nt], 0, 0, 0);
        }
        #pragma unroll
        for (int mt = 0; mt < 4; mt++) {
            #pragma unroll
            for (int nt = 0; nt < NTT; nt++) {
                int col = n0 + cw + nt * 16 + lm;
                float bsv = bias[col];
                #pragma unroll
                for (int r = 0; r < 4; r++) {
                    int row = row0 + rw + mt * 16 + rg + r;
                    if (row < M) {
                        float v = acc[mt][nt][r] + bsv;
                        if (act == 1) v = fmaxf(v, 0.f);
                        if (do_res) v = aval * v + (1.f - aval) * ldf(res + (long)row * N + col);
                        stf(C + (long)row * N + col, v);
                    }
                }
            }
        }
    }
}

template <typename TC, int K, int BM>
__global__ __launch_bounds__(256)
void gemm_nl(const float* __restrict__ A, const __hip_bfloat16* __restrict__ Bt,
             const float* __restrict__ bias, TC* __restrict__ C,
             int M, int N, int act,
             const TC* __restrict__ res, const float* __restrict__ skip_arr, int t) {
    __shared__ short As[BM][K + 8];
    float aval = 0.f;
    if (res != nullptr) { float s = skip_arr[t]; aval = 1.f / (1.f + __expf(-s)); }
    gemm_nl_body<TC, K, BM>(A, Bt, bias, C, M, N, act, res, aval, blockIdx.x * BM, As);
}

// ---------- fused kqv' GEMM: emits [q | kR,vR per edge type] per source node ----------
// Slot layout (FOUT units): paper rows 5 cols @slot 0, author 5 @500K, inst 3 @750K.
template <int FOUT>
__global__ __launch_bounds__(256)
void gemm_kqv_fused(const float* __restrict__ xs, const __hip_bfloat16* __restrict__ wt,
                    const float* __restrict__ biasB, __hip_bfloat16* __restrict__ kqvB) {
    __shared__ short As[128][136];
    int b = blockIdx.x;
    int tsel, brel, mt, ncols, blkbase;
    long npre, slotbase;
    if (b < 782)       { tsel = 0; brel = b;        npre = 0;      mt = 100000; ncols = 5; blkbase = 0;  slotbase = 0; }
    else if (b < 1173) { tsel = 1; brel = b - 782;  npre = 100000; mt = 50000;  ncols = 5; blkbase = 5;  slotbase = 500000; }
    else               { tsel = 2; brel = b - 1173; npre = 150000; mt = 5000;   ncols = 3; blkbase = 10; slotbase = 750000; }
    gemm_nl_body<__hip_bfloat16, 128, 128>(
        xs + npre * 128, wt + (long)blkbase * FOUT * 128, biasB + blkbase * FOUT,
        kqvB + slotbase * FOUT, mt, ncols * FOUT, 0,
        (const __hip_bfloat16*)nullptr, 0.f, brel * 128, As);
}

// ---------- out-GEMM with prefetch ordering (TA = bf16 aggB or f32) ----------
template <typename TA, typename TC, int K, bool DORES>
__global__ __launch_bounds__(256)
void gemm_out(const TA* __restrict__ A, const __hip_bfloat16* __restrict__ Bt,
              const float* __restrict__ bias, TC* __restrict__ C,
              int M, int N,
              const TC* __restrict__ res, const float* __restrict__ skip_arr, int t) {
    __shared__ short As[128][K + 8];
    int tid = threadIdx.x;
    int row0 = blockIdx.x * 128;
    int wave = tid >> 6, lane = tid & 63;
    int rw = (wave >> 1) * 64, cw = (wave & 1) * 32;
    int lm = lane & 15, kg = lane >> 4;
    if constexpr (sizeof(TA) == 2) {
        constexpr int KD8 = K / 8;
        #pragma unroll
        for (int p = 0; p < 128 * KD8 / 256; p++) {
            int q = p * 256 + tid;
            int r = q / KD8, c = (q % KD8) * 8;
            int grow = row0 + r;
            short8 v = short8{0, 0, 0, 0, 0, 0, 0, 0};
            if (grow < M) v = *(const short8*)((const short*)A + (long)grow * K + c);
            *(short8*)&As[r][c] = v;
        }
    } else {
        constexpr int KD4 = K / 4;
        #pragma unroll
        for (int p = 0; p < 128 * KD4 / 256; p++) {
            int q = p * 256 + tid;
            int r = q / KD4, c = (q % KD4) * 4;
            int grow = row0 + r;
            float4 v = make_float4(0.f, 0.f, 0.f, 0.f);
            if (grow < M) v = *(const float4*)((const float*)A + (long)grow * K + c);
            short4v s;
            s.x = f2bf(v.x); s.y = f2bf(v.y); s.z = f2bf(v.z); s.w = f2bf(v.w);
            *(short4v*)&As[r][c] = s;
        }
    }
    float aval = 0.f;
    if (DORES) { float sv = skip_arr[t]; aval = 1.f / (1.f + __expf(-sv)); }
    int rg = kg * 4;
    __syncthreads();
    for (int n0 = 0; n0 < N; n0 += 64) {
        short8 bfr[K / 32][2];
        #pragma unroll
        for (int kk = 0; kk < K / 32; kk++)
            #pragma unroll
            for (int nt = 0; nt < 2; nt++)
                bfr[kk][nt] = *(const short8*)(
                    Bt + (long)(n0 + cw + nt * 16 + lm) * K + kk * 32 + kg * 8);
        float bsv[2];
        #pragma unroll
        for (int nt = 0; nt < 2; nt++) bsv[nt] = bias[n0 + cw + nt * 16 + lm];
        float rv[2][4][4];
        if (DORES) {
            #pragma unroll
            for (int nt = 0; nt < 2; nt++)
                #pragma unroll
                for (int mt = 0; mt < 4; mt++)
                    #pragma unroll
                    for (int r = 0; r < 4; r++) {
                        int row = row0 + rw + mt * 16 + rg + r;
                        rv[nt][mt][r] = (row < M)
                            ? ldf(res + (long)row * N + n0 + cw + nt * 16 + lm) : 0.f;
                    }
        }
        floatx4 acc[4][2];
        #pragma unroll
        for (int i = 0; i < 4; i++)
            #pragma unroll
            for (int j = 0; j < 2; j++) acc[i][j] = floatx4{0.f, 0.f, 0.f, 0.f};
        #pragma unroll
        for (int kk = 0; kk < K / 32; kk++) {
            int kb = kk * 32 + kg * 8;
            short8 a[4];
            #pragma unroll
            for (int mt = 0; mt < 4; mt++) a[mt] = *(short8*)&As[rw + mt * 16 + lm][kb];
            #pragma unroll
            for (int mt = 0; mt < 4; mt++)
                #pragma unroll
                for (int nt = 0; nt < 2; nt++)
                    acc[mt][nt] = __builtin_amdgcn_mfma_f32_16x16x32_bf16(
                        a[mt], bfr[kk][nt], acc[mt][nt], 0, 0, 0);
        }
        #pragma unroll
        for (int mt = 0; mt < 4; mt++) {
            #pragma unroll
            for (int nt = 0; nt < 2; nt++) {
                int col = n0 + cw + nt * 16 + lm;
                #pragma unroll
                for (int r = 0; r < 4; r++) {
                    int row = row0 + rw + mt * 16 + rg + r;
                    if (row < M) {
                        float v = acc[mt][nt][r] + bsv[nt];
                        if (DORES) v = aval * v + (1.f - aval) * rv[nt][mt][r];
                        stf(C + (long)row * N + col, v);
                    }
                }
            }
        }
    }
}

// ---------- small utils ----------
__global__ void fill_u32(unsigned int* __restrict__ p, unsigned int v, int n) {
    int i = blockIdx.x * blockDim.x + threadIdx.x;
    if (i < n) p[i] = v;
}
__global__ void copy_u32(const int* __restrict__ a, int* __restrict__ b, int n) {
    int i = blockIdx.x * blockDim.x + threadIdx.x;
    if (i < n) b[i] = a[i];
}

// ---------- CSR build ----------
__global__ void count_edges(const int* __restrict__ dst, int E, int* __restrict__ counts) {
    int i = blockIdx.x * blockDim.x + threadIdx.x;
    if (i < E) atomicAdd(&counts[dst[i]], 1);
}

__global__ __launch_bounds__(256) void scan_local(const int* __restrict__ counts,
                                                  int* __restrict__ rowptr,
                                                  int* __restrict__ bsums, int n) {
    __shared__ int sh[256];
    int t = threadIdx.x;
    int base = blockIdx.x * 1024;
    int lv[4]; int s = 0;
    #pragma unroll
    for (int q = 0; q < 4; q++) {
        int i = base + t * 4 + q;
        lv[q] = (i < n) ? counts[i] : 0;
        s += lv[q];
    }
    sh[t] = s;
    __syncthreads();
    #pragma unroll
    for (int off = 1; off < 256; off <<= 1) {
        int add = (t >= off) ? sh[t - off] : 0;
        __syncthreads();
        sh[t] += add;
        __syncthreads();
    }
    int excl = sh[t] - s;
    if (t == 255) bsums[blockIdx.x] = sh[255];
    #pragma unroll
    for (int q = 0; q < 4; q++) {
        int i = base + t * 4 + q;
        if (i < n) rowptr[i] = excl;
        excl += lv[q];
    }
}
__global__ __launch_bounds__(256) void scan_bsums(int* __restrict__ bsums, int nb) {
    __shared__ int sh[256];
    int t = threadIdx.x;
    int v = (t < nb) ? bsums[t] : 0;
    sh[t] = v;
    __syncthreads();
    #pragma unroll
    for (int off = 1; off < 256; off <<= 1) {
        int add = (t >= off) ? sh[t - off] : 0;
        __syncthreads();
        sh[t] += add;
        __syncthreads();
    }
    if (t < nb) bsums[t] = sh[t] - v;
    if (t == nb - 1) bsums[nb] = sh[t];
}
__global__ void scan_add(int* __restrict__ rowptr, const int* __restrict__ bsums,
                         int n, int nb) {
    int i = blockIdx.x * blockDim.x + threadIdx.x;
    if (i < n) rowptr[i] += bsums[i >> 10];
    if (i == 0) rowptr[n] = bsums[nb];
}

// rec = (kslot, dst): kslot = slotbase + src*ncols + kcol (FOUT-unit slots; v = kslot+1)
__global__ void scatter_edges(const int* __restrict__ src, const int* __restrict__ dst, int E,
                              int* __restrict__ cursor, int2* __restrict__ recs,
                              int slotbase, int ncols, int kcol) {
    int i = blockIdx.x * blockDim.x + threadIdx.x;
    if (i >= E) return;
    int pos = atomicAdd(&cursor[dst[i]], 1);
    recs[pos] = make_int2(slotbase + src[i] * ncols + kcol, dst[i]);
}

// ---------- scores in CSR-slot order: sc[(slot-base)*H + h] ----------
template <int H>
__global__ void edge_score_csr(const __hip_bfloat16* __restrict__ kqvB,
                               long qbase, int qncols,
                               const int2* __restrict__ recs, const int* __restrict__ rowptr,
                               int tb, long nwork, float* __restrict__ sc_out) {
    long tid = blockIdx.x * (long)blockDim.x + threadIdx.x;
    if (tid >= nwork) return;
    constexpr int FOUT = H * 16;
    int sl = (int)(tid / H);
    int h = (int)(tid - (long)sl * H);
    int base = rowptr[tb];
    int2 rec = recs[base + sl];
    float kv[16], qv[16];
    load16bf(kqvB + (long)rec.x * FOUT + h * 16, kv);
    load16bf(kqvB + (qbase + (long)rec.y * qncols) * FOUT + h * 16, qv);
    float acc = 0.f;
    #pragma unroll
    for (int i = 0; i < 16; i++) acc = fmaf(kv[i], qv[i], acc);
    sc_out[tid] = acc;
}

// ---------- segment softmax stats: sequential CSR-ordered score reads ----------
template <int H>
__global__ __launch_bounds__(256)
void edge_alpha_csr(const int* __restrict__ rowptr, int tb, int ndst,
                    const float* __restrict__ sc, float2* __restrict__ ml) {
    constexpr int PER = 256 / H;
    int slot = threadIdx.x / H;
    int h = threadIdx.x - slot * H;
    int d = blockIdx.x * PER + slot;
    if (d >= ndst) return;
    int base = rowptr[tb];
    int r0 = rowptr[tb + d], r1 = rowptr[tb + d + 1];
    const float* scp = sc + (long)(r0 - base) * H + h;
    float m = -1e30f, l = 0.f;
    for (int n = r1 - r0; n > 0; --n, scp += H) {
        float s = *scp;
        float mn = fmaxf(m, s);
        float r = __expf(m - mn);
        float w = __expf(s - mn);
        l = fmaf(l, r, w);
        m = mn;
    }
    float inv = (l > 0.f) ? 1.f / l : 0.f;
    ml[(long)d * H + h] = make_float2(m, inv);
}

// ---------- gather: 4 channels/thread, v rows read from kqvB slot rec.x+1 ----------
template <int FOUT, int H>
__global__ void gather_agg_csr(const __hip_bfloat16* __restrict__ kqvB,
                               const int2* __restrict__ recs, const int* __restrict__ rowptr,
                               int tb, int ndst,
                               const float* __restrict__ sc,
                               const float2* __restrict__ ml,
                               __hip_bfloat16* __restrict__ agg) {
    constexpr int TPD = FOUT / 4;
    constexpr int PER = 256 / TPD;
    int slot = threadIdx.x / TPD;
    int jj = threadIdx.x - slot * TPD;
    int j4 = jj * 4;
    int d = blockIdx.x * PER + slot;
    if (d >= ndst) return;
    int h = j4 >> 4;
    float2 mh = ml[(long)d * H + h];
    int base = rowptr[tb];
    int r0 = rowptr[tb + d], r1 = rowptr[tb + d + 1];
    const float* scp = sc + (long)(r0 - base) * H + h;
    const int2* rp = recs + r0;
    int n = r1 - r0;
    float a0[4] = {0.f, 0.f, 0.f, 0.f}, a1[4] = {0.f, 0.f, 0.f, 0.f};
    int i = 0;
    for (; i + 1 < n; i += 2) {
        int2 ra = rp[i], rb = rp[i + 1];
        float s0 = scp[(long)i * H], s1 = scp[(long)(i + 1) * H];
        float w0 = __expf(s0 - mh.x) * mh.y;
        float w1 = __expf(s1 - mh.x) * mh.y;
        uint2 va = *(const uint2*)(kqvB + ((long)ra.x + 1) * FOUT + j4);
        uint2 vb = *(const uint2*)(kqvB + ((long)rb.x + 1) * FOUT + j4);
        a0[0] = fmaf(w0, bflo(va.x), a0[0]);
        a0[1] = fmaf(w0, bfhi(va.x), a0[1]);
        a0[2] = fmaf(w0, bflo(va.y), a0[2]);
        a0[3] = fmaf(w0, bfhi(va.y), a0[3]);
        a1[0] = fmaf(w1, bflo(vb.x), a1[0]);
        a1[1] = fmaf(w1, bfhi(vb.x), a1[1]);
        a1[2] = fmaf(w1, bflo(vb.y), a1[2]);
        a1[3] = fmaf(w1, bfhi(vb.y), a1[3]);
    }
    if (i < n) {
        int2 ra = rp[i];
        float w0 = __expf(scp[(long)i * H] - mh.x) * mh.y;
        uint2 va = *(const uint2*)(kqvB + ((long)ra.x + 1) * FOUT + j4);
        a0[0] = fmaf(w0, bflo(va.x), a0[0]);
        a0[1] = fmaf(w0, bfhi(va.x), a0[1]);
        a0[2] = fmaf(w0, bflo(va.y), a0[2]);
        a0[3] = fmaf(w0, bfhi(va.y), a0[3]);
    }
    short4v o;
    o.x = f2bf(gelu1(a0[0] + a1[0]));
    o.y = f2bf(gelu1(a0[1] + a1[1]));
    o.z = f2bf(gelu1(a0[2] + a1[2]));
    o.w = f2bf(gelu1(a0[3] + a1[3]));
    *(short4v*)((short*)agg + (long)d * FOUT + j4) = o;
}

// ---------- orchestration ----------
static const int ET_src[5]  = {1, 0, 0, 1, 2};
static const int ET_dst[5]  = {0, 0, 1, 2, 1};
static const int ET_E[5]    = {250000, 250000, 200000, 100000, 100000};
static const int KCOL[5]    = {1, 1, 3, 3, 1};  // k-slot col within source row
static const long SLOTB[3]  = {0, 500000, 750000};
static const int NCOLS[3]   = {5, 5, 3};
static const int NT[3]      = {100000, 50000, 5000};
static const long NPRE[3]   = {0, 100000, 150000};
static const int TB[3]      = {0, 100000, 150000};
static const int SL[3]      = {500000, 300000, 100000};
static const int NTOT       = 155000;

template <typename TO, int H>
static void hgt_layer_run(hipStream_t stream,
                          const float* xs, __hip_bfloat16* kqvB, float* scB,
                          const int* rowptr, const int2* recs, __hip_bfloat16* aggB,
                          float2* ml, __hip_bfloat16* wtP, float* biasB,
                          const float* kqv_w, const float* kqv_b,
                          const float* krel, const float* vrel, const float* prel,
                          const __hip_bfloat16* wt_out, const float* out_b,
                          const float* skip_arr,
                          TO* const* outs) {
    constexpr int FOUT = H * 16;
    constexpr bool DOSKIP = (H == 8);   // L1 only: fout == hidden
    compose_kqv<H><<<(13 * FOUT * 128 + 255) / 256, 256, 0, stream>>>(
        kqv_w, kqv_b, krel, vrel, prel, wtP, biasB);
    gemm_kqv_fused<FOUT><<<1213, 256, 0, stream>>>(xs, wtP, biasB, kqvB);
    for (int t = 0; t < 3; t++) {
        long nwork = (long)SL[t] * H;
        edge_score_csr<H><<<(int)((nwork + 255) / 256), 256, 0, stream>>>(
            kqvB, SLOTB[t], NCOLS[t], recs, rowptr, TB[t], nwork, scB);
        constexpr int PERA = 256 / H;
        edge_alpha_csr<H><<<(NT[t] + PERA - 1) / PERA, 256, 0, stream>>>(
            rowptr, TB[t], NT[t], scB, ml);
        constexpr int PERG = 256 / (FOUT / 4);
        gather_agg_csr<FOUT, H><<<(NT[t] + PERG - 1) / PERG, 256, 0, stream>>>(
            kqvB, recs, rowptr, TB[t], NT[t], scB, ml, aggB);
        int gb2 = (NT[t] + 127) / 128;
        gemm_out<__hip_bfloat16, TO, FOUT, DOSKIP><<<gb2, 256, 0, stream>>>(
            aggB, wt_out + (long)t * FOUT * FOUT, out_b + t * FOUT, outs[t],
            NT[t], FOUT, DOSKIP ? outs[t] : (TO*)nullptr, skip_arr, t);
    }
}

extern "C" void kernel_launch(void* const* d_in, const int* in_sizes, int n_in,
                              void* d_out, int out_size, void* d_ws, size_t ws_size,
                              hipStream_t stream) {
    const float* x_paper  = (const float*)d_in[0];
    const float* x_author = (const float*)d_in[1];
    const float* x_inst   = (const float*)d_in[2];
    const int* ei[5];
    for (int e = 0; e < 5; e++) ei[e] = (const int*)d_in[3 + e];
    const float* lin_w[3] = {(const float*)d_in[8], (const float*)d_in[10], (const float*)d_in[12]};
    const float* lin_b[3] = {(const float*)d_in[9], (const float*)d_in[11], (const float*)d_in[13]};
    const float* kqv_w1 = (const float*)d_in[14];
    const float* kqv_b1 = (const float*)d_in[15];
    const float* krel1  = (const float*)d_in[16];
    const float* vrel1  = (const float*)d_in[17];
    const float* prel1  = (const float*)d_in[18];
    const float* out_w1 = (const float*)d_in[19];
    const float* out_b1 = (const float*)d_in[20];
    const float* skip1  = (const float*)d_in[21];
    const float* kqv_w2 = (const float*)d_in[22];
    const float* kqv_b2 = (const float*)d_in[23];
    const float* krel2  = (const float*)d_in[24];
    const float* vrel2  = (const float*)d_in[25];
    const float* prel2  = (const float*)d_in[26];
    const float* out_w2 = (const float*)d_in[27];
    const float* out_b2 = (const float*)d_in[28];
    const float* skip2  = (const float*)d_in[29];

    // workspace carve (16B-aligned); total ~332.4 MB (< the 351.5 MB prior budget)
    char* p = (char*)d_ws;
    float* xs = (float*)p;                      p += 19840000L * 4;    // 79.36 MB
    __hip_bfloat16* kqvB = (__hip_bfloat16*)p;  p += 97920000L * 2;    // 195.84 MB (765K slots x 128)
    float* scB = (float*)p;                     p += 4000000L * 4;     // 16 MB
    __hip_bfloat16* aggB = (__hip_bfloat16*)p;  p += 12800000L * 2;    // 25.6 MB
    float2* ml = (float2*)p;                    p += 800000L * 8;      // 6.4 MB
    int* rowptr = (int*)p;                      p += 155008L * 4;
    int* cursor = (int*)p;                      p += 155008L * 4;
    int2* recs = (int2*)p;                      p += 900000L * 8;
    float* biasB = (float*)p;                   p += 2048L * 4;
    __hip_bfloat16* wtA = (__hip_bfloat16*)p;

    __hip_bfloat16* wt_lin[3] = {wtA, wtA + 32768, wtA + 49152};
    __hip_bfloat16* wt_out1 = wtA + 57344;
    __hip_bfloat16* wt_out2 = wtA + 106496;
    __hip_bfloat16* wtP = wtA + 118784;   // composed kqv' (max 13*128*128 = 212992)

    dim3 pb(32, 8);
    pack_wt<<<dim3(4, 8, 1), pb, 0, stream>>>(lin_w[0], wt_lin[0], 256, 128);
    pack_wt<<<dim3(4, 4, 1), pb, 0, stream>>>(lin_w[1], wt_lin[1], 128, 128);
    pack_wt<<<dim3(4, 2, 1), pb, 0, stream>>>(lin_w[2], wt_lin[2], 64, 128);
    pack_wt<<<dim3(4, 4, 3), pb, 0, stream>>>(out_w1, wt_out1, 128, 128);
    pack_wt<<<dim3(2, 2, 3), pb, 0, stream>>>(out_w2, wt_out2, 64, 64);

    // input projections (ReLU). N=128. paper: proven dedicated K=256 BN=128 kernel.
    gemm_mfma_k256<<<782, 256, 0, stream>>>(x_paper, wt_lin[0], lin_b[0], xs, 100000);
    gemm_nl<float, 128, 128><<<391, 256, 0, stream>>>(
        x_author, wt_lin[1], lin_b[1], xs + 100000L * 128, 50000, 128, 1,
        (float*)nullptr, nullptr, 0);
    gemm_nl<float, 64, 128><<<40, 256, 0, stream>>>(
        x_inst, wt_lin[2], lin_b[2], xs + 150000L * 128, 5000, 128, 1,
        (float*)nullptr, nullptr, 0);

    // CSR build (shared by both layers)
    fill_u32<<<(NTOT + 255) / 256, 256, 0, stream>>>((unsigned int*)cursor, 0u, NTOT);
    for (int e = 0; e < 5; e++)
        count_edges<<<(ET_E[e] + 255) / 256, 256, 0, stream>>>(
            ei[e] + ET_E[e], ET_E[e], cursor + TB[ET_dst[e]]);
    {
        int* bsums = (int*)scB;  // scB dead during CSR build
        int nb = (NTOT + 1023) / 1024;  // 152
        scan_local<<<nb, 256, 0, stream>>>(cursor, rowptr, bsums, NTOT);
        scan_bsums<<<1, 256, 0, stream>>>(bsums, nb);
        scan_add<<<(NTOT + 255) / 256, 256, 0, stream>>>(rowptr, bsums, NTOT, nb);
    }
    copy_u32<<<(NTOT + 255) / 256, 256, 0, stream>>>(rowptr, cursor, NTOT);
    for (int e = 0; e < 5; e++) {
        int ts = ET_src[e];
        scatter_edges<<<(ET_E[e] + 255) / 256, 256, 0, stream>>>(
            ei[e], ei[e] + ET_E[e], ET_E[e], cursor + TB[ET_dst[e]], recs,
            (int)SLOTB[ts], NCOLS[ts], KCOL[e]);
    }

    // layer 1 (output in-place over xs; gated skip fused into out-GEMM)
    float* outs1[3] = {xs, xs + 100000L * 128, xs + 150000L * 128};
    hgt_layer_run<float, 8>(stream, xs, kqvB, scB, rowptr, recs, aggB, ml, wtP, biasB,
                            kqv_w1, kqv_b1, krel1, vrel1, prel1, wt_out1, out_b1, skip1,
                            outs1);

    float* out = (float*)d_out;
    float* outs2[3] = {out, out + 100000L * 64, out + 150000L * 64};
    hgt_layer_run<float, 4>(stream, xs, kqvB, scB, rowptr, recs, aggB, ml, wtP, biasB,
                            kqv_w2, kqv_b2, krel2, vrel2, prel2, wt_out2, out_b2, skip2,
                            outs2);
}

// Round 9
// 939.735 us; speedup vs baseline: 2.1144x; 1.1508x over previous
//
#include <hip/hip_runtime.h>
#include <hip/hip_bf16.h>
#include <math.h>

typedef __attribute__((ext_vector_type(8))) short short8;
typedef __attribute__((ext_vector_type(4))) short short4v;
typedef __attribute__((ext_vector_type(4))) float floatx4;

// ---------- type helpers ----------
__device__ __forceinline__ float ldf(const float* p) { return *p; }
__device__ __forceinline__ float ldf(const __hip_bfloat16* p) { return __bfloat162float(*p); }
__device__ __forceinline__ void stf(float* p, float v) { *p = v; }
__device__ __forceinline__ void stf(__hip_bfloat16* p, float v) { *p = __float2bfloat16(v); }
__device__ __forceinline__ float gelu1(float v) {
    return 0.5f * v * (1.f + erff(v * 0.70710678118654752f));
}
__device__ __forceinline__ short f2bf(float f) {
    unsigned int u = __float_as_uint(f);
    unsigned int r = (u + 0x7FFFu + ((u >> 16) & 1u)) >> 16;
    return (short)r;
}
__device__ __forceinline__ float bflo(unsigned int u) { return __uint_as_float(u << 16); }
__device__ __forceinline__ float bfhi(unsigned int u) { return __uint_as_float(u & 0xFFFF0000u); }
__device__ __forceinline__ void load16bf(const __hip_bfloat16* p, float* o) {
    const uint4* u = (const uint4*)p;
    uint4 w0 = u[0], w1 = u[1];
    unsigned int ws[8] = {w0.x, w0.y, w0.z, w0.w, w1.x, w1.y, w1.z, w1.w};
    #pragma unroll
    for (int i = 0; i < 8; i++) {
        o[2 * i]     = bflo(ws[i]);
        o[2 * i + 1] = bfhi(ws[i]);
    }
}

// ---------- weight pack: W[K,N] f32 -> Wt[N,K] bf16 (batched over grid.z) ----------
__global__ void pack_wt(const float* __restrict__ W, __hip_bfloat16* __restrict__ Wt,
                        int K, int N) {
    __shared__ float tile[32][33];
    long b = blockIdx.z;
    const float* Wb = W + b * K * N;
    __hip_bfloat16* Wtb = Wt + b * K * N;
    int k0 = blockIdx.y * 32, n0 = blockIdx.x * 32;
    int tx = threadIdx.x, ty = threadIdx.y;  // 32 x 8
    #pragma unroll
    for (int i = 0; i < 32; i += 8) {
        int k = k0 + ty + i, n = n0 + tx;
        tile[ty + i][tx] = (k < K && n < N) ? Wb[(long)k * N + n] : 0.f;
    }
    __syncthreads();
    #pragma unroll
    for (int i = 0; i < 32; i += 8) {
        int n = n0 + ty + i, k = k0 + tx;
        if (n < N && k < K) Wtb[(long)n * K + k] = __float2bfloat16(tile[tx][ty + i]);
    }
}

// ---------- compose kqv' weights: fold relation transforms into kqv GEMM ----------
template <int H>
__global__ __launch_bounds__(256)
void compose_kqv(const float* __restrict__ kqv_w, const float* __restrict__ kqv_b,
                 const float* __restrict__ krel, const float* __restrict__ vrel,
                 const float* __restrict__ prel,
                 __hip_bfloat16* __restrict__ wt, float* __restrict__ biasB) {
    constexpr int FOUT = H * 16;
    constexpr int F3 = 3 * FOUT;
    const int TS[13]   = {0,0,0,0,0, 1,1,1,1,1, 2,2,2};
    const int MODE[13] = {0,1,2,1,2, 0,1,2,1,2, 0,1,2};  // 0=q copy, 1=kR, 2=vR
    const int EDG[13]  = {0,1,1,2,2, 0,0,0,3,3, 0,4,4};
    long g = blockIdx.x * 256L + threadIdx.x;
    constexpr long PER = (long)FOUT * 128;
    int blk = (int)(g / PER);
    if (blk >= 13) return;
    int idx = (int)(g - blk * PER);
    int c = idx >> 7, k = idx & 127;
    int ts = TS[blk], mode = MODE[blk], e = EDG[blk];
    const float* W = kqv_w + (long)ts * 128 * F3 + (long)k * F3;
    const float* Bv = kqv_b + ts * F3;
    float outw, outb;
    if (mode == 0) {
        outw = W[FOUT + c];          // q is the middle third (split order: k,q,v)
        outb = Bv[FOUT + c];
    } else {
        int h = c >> 4, eo = c & 15;
        int srcb = (mode == 1) ? 0 : 2 * FOUT;
        const float* R = ((mode == 1) ? krel : vrel) + ((long)e * H + h) * 256 + eo;
        float scale = (mode == 1) ? prel[e * H + h] * 0.25f : 1.f;
        float aw = 0.f, ab = 0.f;
        #pragma unroll
        for (int i = 0; i < 16; i++) {
            float r = R[i * 16];
            aw = fmaf(W[srcb + h * 16 + i], r, aw);
            ab = fmaf(Bv[srcb + h * 16 + i], r, ab);
        }
        outw = aw * scale; outb = ab * scale;
    }
    wt[blk * PER + (long)c * 128 + k] = __float2bfloat16(outw);
    if (k == 0) biasB[blk * FOUT + c] = outb;
}

// ---------- paper projection: M x 128 = A[M,256] @ Bt[128,256], ReLU ----------
// Swapped-operand MFMA: lane holds 4 consecutive cols of one row -> float4 stores.
__global__ __launch_bounds__(256)
void gemm_mfma_k256(const float* __restrict__ A, const __hip_bfloat16* __restrict__ Bt,
                    const float* __restrict__ bias, float* __restrict__ C, int M) {
    __shared__ short As[128][72];
    __shared__ short Bs[128][72];
    int tid = threadIdx.x;
    int row0 = blockIdx.x * 128;
    int wave = tid >> 6, lane = tid & 63;
    int rw = (wave >> 1) * 64, cw = (wave & 1) * 64;
    int lm = lane & 15, kg = lane >> 4;
    floatx4 acc[4][4];
    #pragma unroll
    for (int i = 0; i < 4; i++)
        #pragma unroll
        for (int j = 0; j < 4; j++) acc[i][j] = floatx4{0.f, 0.f, 0.f, 0.f};

    for (int k0 = 0; k0 < 256; k0 += 64) {
        #pragma unroll
        for (int p = 0; p < 8; p++) {
            int q = p * 256 + tid;
            int r = q >> 4, c = (q & 15) * 4;
            int grow = row0 + r;
            float4 v = make_float4(0.f, 0.f, 0.f, 0.f);
            if (grow < M) v = *(const float4*)(A + (long)grow * 256 + k0 + c);
            short4v s;
            s.x = f2bf(v.x); s.y = f2bf(v.y); s.z = f2bf(v.z); s.w = f2bf(v.w);
            *(short4v*)&As[r][c] = s;
        }
        #pragma unroll
        for (int p = 0; p < 4; p++) {
            int q = p * 256 + tid;
            int r = q >> 3, c = (q & 7) * 8;
            *(short8*)&Bs[r][c] = *(const short8*)(Bt + (long)r * 256 + k0 + c);
        }
        __syncthreads();
        #pragma unroll
        for (int kk = 0; kk < 2; kk++) {
            int kb = kk * 32 + kg * 8;
            short8 a[4], b[4];
            #pragma unroll
            for (int mt = 0; mt < 4; mt++) a[mt] = *(short8*)&As[rw + mt * 16 + lm][kb];
            #pragma unroll
            for (int nt = 0; nt < 4; nt++) b[nt] = *(short8*)&Bs[cw + nt * 16 + lm][kb];
            #pragma unroll
            for (int mt = 0; mt < 4; mt++)
                #pragma unroll
                for (int nt = 0; nt < 4; nt++)
                    acc[mt][nt] = __builtin_amdgcn_mfma_f32_16x16x32_bf16(
                        b[nt], a[mt], acc[mt][nt], 0, 0, 0);   // swapped -> C^T tile
        }
        __syncthreads();
    }
    int rg = (lane >> 4) * 4;
    #pragma unroll
    for (int mt = 0; mt < 4; mt++) {
        int row = row0 + rw + mt * 16 + lm;
        if (row < M) {
            #pragma unroll
            for (int nt = 0; nt < 4; nt++) {
                int colb = cw + nt * 16 + rg;
                float4 b4 = *(const float4*)(bias + colb);
                float4 o;
                o.x = fmaxf(acc[mt][nt][0] + b4.x, 0.f);
                o.y = fmaxf(acc[mt][nt][1] + b4.y, 0.f);
                o.z = fmaxf(acc[mt][nt][2] + b4.z, 0.f);
                o.w = fmaxf(acc[mt][nt][3] + b4.w, 0.f);
                *(float4*)(C + (long)row * 128 + colb) = o;
            }
        }
    }
}

// ---------- GEMM body: A staged in LDS (full K), B direct from global, one barrier,
// swapped-operand MFMA -> packed stores (8B bf16 / 16B f32). No res path. ----------
template <typename TC, int K, int BM>
__device__ __forceinline__
void gemm_nl_body(const float* __restrict__ A, const __hip_bfloat16* __restrict__ Bt,
                  const float* __restrict__ bias, TC* __restrict__ C,
                  int M, int N, int act, int row0, short (*As)[K + 8]) {
    int tid = threadIdx.x;
    int wave = tid >> 6, lane = tid & 63;
    constexpr int NTT = (BM == 128) ? 2 : 1;
    int rw = (BM == 128) ? (wave >> 1) * 64 : 0;
    int cw = (BM == 128) ? (wave & 1) * 32 : wave * 16;
    int lm = lane & 15, kg = lane >> 4;
    constexpr int KD4 = K / 4;
    constexpr int NLD = BM * KD4 / 256;
    #pragma unroll
    for (int p = 0; p < NLD; p++) {
        int q = p * 256 + tid;
        int r = q / KD4, c = (q % KD4) * 4;
        int grow = row0 + r;
        float4 v = make_float4(0.f, 0.f, 0.f, 0.f);
        if (grow < M) v = *(const float4*)(A + (long)grow * K + c);
        short4v s;
        s.x = f2bf(v.x); s.y = f2bf(v.y); s.z = f2bf(v.z); s.w = f2bf(v.w);
        *(short4v*)&As[r][c] = s;
    }
    __syncthreads();
    int rg = kg * 4;
    for (int n0 = 0; n0 < N; n0 += 64) {
        floatx4 acc[4][NTT];
        #pragma unroll
        for (int i = 0; i < 4; i++)
            #pragma unroll
            for (int j = 0; j < NTT; j++) acc[i][j] = floatx4{0.f, 0.f, 0.f, 0.f};
        #pragma unroll
        for (int kk = 0; kk < K / 32; kk++) {
            int kb = kk * 32 + kg * 8;
            short8 a[4], b[NTT];
            #pragma unroll
            for (int mt = 0; mt < 4; mt++) a[mt] = *(short8*)&As[rw + mt * 16 + lm][kb];
            #pragma unroll
            for (int nt = 0; nt < NTT; nt++)
                b[nt] = *(const short8*)(Bt + (long)(n0 + cw + nt * 16 + lm) * K + kb);
            #pragma unroll
            for (int mt = 0; mt < 4; mt++)
                #pragma unroll
                for (int nt = 0; nt < NTT; nt++)
                    acc[mt][nt] = __builtin_amdgcn_mfma_f32_16x16x32_bf16(
                        b[nt], a[mt], acc[mt][nt], 0, 0, 0);   // swapped -> C^T tile
        }
        #pragma unroll
        for (int mt = 0; mt < 4; mt++) {
            int row = row0 + rw + mt * 16 + lm;
            if (row < M) {
                #pragma unroll
                for (int nt = 0; nt < NTT; nt++) {
                    int colb = n0 + cw + nt * 16 + rg;
                    float4 b4 = *(const float4*)(bias + colb);
                    float v0 = acc[mt][nt][0] + b4.x;
                    float v1 = acc[mt][nt][1] + b4.y;
                    float v2 = acc[mt][nt][2] + b4.z;
                    float v3 = acc[mt][nt][3] + b4.w;
                    if (act == 1) {
                        v0 = fmaxf(v0, 0.f); v1 = fmaxf(v1, 0.f);
                        v2 = fmaxf(v2, 0.f); v3 = fmaxf(v3, 0.f);
                    }
                    if constexpr (sizeof(TC) == 2) {
                        short4v o;
                        o.x = f2bf(v0); o.y = f2bf(v1); o.z = f2bf(v2); o.w = f2bf(v3);
                        *(short4v*)((short*)C + (long)row * N + colb) = o;
                    } else {
                        *(float4*)((float*)C + (long)row * N + colb) =
                            make_float4(v0, v1, v2, v3);
                    }
                }
            }
        }
    }
}

template <typename TC, int K, int BM>
__global__ __launch_bounds__(256)
void gemm_nl(const float* __restrict__ A, const __hip_bfloat16* __restrict__ Bt,
             const float* __restrict__ bias, TC* __restrict__ C,
             int M, int N, int act) {
    __shared__ short As[BM][K + 8];
    gemm_nl_body<TC, K, BM>(A, Bt, bias, C, M, N, act, blockIdx.x * BM, As);
}

// ---------- fused kqv' GEMM: emits [q | kR,vR per edge type] per source node ----------
template <int FOUT>
__global__ __launch_bounds__(256)
void gemm_kqv_fused(const float* __restrict__ xs, const __hip_bfloat16* __restrict__ wt,
                    const float* __restrict__ biasB, __hip_bfloat16* __restrict__ kqvB) {
    __shared__ short As[128][136];
    int b = blockIdx.x;
    int tsel, brel, mt, ncols, blkbase;
    long npre, slotbase;
    if (b < 782)       { tsel = 0; brel = b;        npre = 0;      mt = 100000; ncols = 5; blkbase = 0;  slotbase = 0; }
    else if (b < 1173) { tsel = 1; brel = b - 782;  npre = 100000; mt = 50000;  ncols = 5; blkbase = 5;  slotbase = 500000; }
    else               { tsel = 2; brel = b - 1173; npre = 150000; mt = 5000;   ncols = 3; blkbase = 10; slotbase = 750000; }
    (void)tsel;
    gemm_nl_body<__hip_bfloat16, 128, 128>(
        xs + npre * 128, wt + (long)blkbase * FOUT * 128, biasB + blkbase * FOUT,
        kqvB + slotbase * FOUT, mt, ncols * FOUT, 0, brel * 128, As);
}

// ---------- out-GEMM: B preload first, res float4 preload under MFMA, packed stores ----------
template <typename TA, typename TC, int K, bool DORES>
__global__ __launch_bounds__(256)
void gemm_out(const TA* __restrict__ A, const __hip_bfloat16* __restrict__ Bt,
              const float* __restrict__ bias, TC* __restrict__ C,
              int M, int N,
              const TC* __restrict__ res, const float* __restrict__ skip_arr, int t) {
    __shared__ short As[128][K + 8];
    int tid = threadIdx.x;
    int row0 = blockIdx.x * 128;
    int wave = tid >> 6, lane = tid & 63;
    int rw = (wave >> 1) * 64, cw = (wave & 1) * 32;
    int lm = lane & 15, kg = lane >> 4;
    if constexpr (sizeof(TA) == 2) {
        constexpr int KD8 = K / 8;
        #pragma unroll
        for (int p = 0; p < 128 * KD8 / 256; p++) {
            int q = p * 256 + tid;
            int r = q / KD8, c = (q % KD8) * 8;
            int grow = row0 + r;
            short8 v = short8{0, 0, 0, 0, 0, 0, 0, 0};
            if (grow < M) v = *(const short8*)((const short*)A + (long)grow * K + c);
            *(short8*)&As[r][c] = v;
        }
    } else {
        constexpr int KD4 = K / 4;
        #pragma unroll
        for (int p = 0; p < 128 * KD4 / 256; p++) {
            int q = p * 256 + tid;
            int r = q / KD4, c = (q % KD4) * 4;
            int grow = row0 + r;
            float4 v = make_float4(0.f, 0.f, 0.f, 0.f);
            if (grow < M) v = *(const float4*)((const float*)A + (long)grow * K + c);
            short4v s;
            s.x = f2bf(v.x); s.y = f2bf(v.y); s.z = f2bf(v.z); s.w = f2bf(v.w);
            *(short4v*)&As[r][c] = s;
        }
    }
    float aval = 0.f;
    if (DORES) { float sv = skip_arr[t]; aval = 1.f / (1.f + __expf(-sv)); }
    int rg = kg * 4;
    __syncthreads();
    for (int n0 = 0; n0 < N; n0 += 64) {
        // B preload (oldest vm ops; MFMA waits only on these)
        short8 bfr[K / 32][2];
        #pragma unroll
        for (int kk = 0; kk < K / 32; kk++)
            #pragma unroll
            for (int nt = 0; nt < 2; nt++)
                bfr[kk][nt] = *(const short8*)(
                    Bt + (long)(n0 + cw + nt * 16 + lm) * K + kk * 32 + kg * 8);
        float4 bsv[2];
        #pragma unroll
        for (int nt = 0; nt < 2; nt++)
            bsv[nt] = *(const float4*)(bias + n0 + cw + nt * 16 + rg);
        // res preload (HBM, packed float4): newest vm ops; overlap with MFMA chain
        float4 rv[4][2];
        if (DORES) {
            #pragma unroll
            for (int mt = 0; mt < 4; mt++) {
                int row = row0 + rw + mt * 16 + lm;
                #pragma unroll
                for (int nt = 0; nt < 2; nt++)
                    rv[mt][nt] = (row < M)
                        ? *(const float4*)((const float*)res + (long)row * N + n0 + cw + nt * 16 + rg)
                        : make_float4(0.f, 0.f, 0.f, 0.f);
            }
        }
        floatx4 acc[4][2];
        #pragma unroll
        for (int i = 0; i < 4; i++)
            #pragma unroll
            for (int j = 0; j < 2; j++) acc[i][j] = floatx4{0.f, 0.f, 0.f, 0.f};
        #pragma unroll
        for (int kk = 0; kk < K / 32; kk++) {
            int kb = kk * 32 + kg * 8;
            short8 a[4];
            #pragma unroll
            for (int mt = 0; mt < 4; mt++) a[mt] = *(short8*)&As[rw + mt * 16 + lm][kb];
            #pragma unroll
            for (int mt = 0; mt < 4; mt++)
                #pragma unroll
                for (int nt = 0; nt < 2; nt++)
                    acc[mt][nt] = __builtin_amdgcn_mfma_f32_16x16x32_bf16(
                        bfr[kk][nt], a[mt], acc[mt][nt], 0, 0, 0);  // swapped -> C^T tile
        }
        #pragma unroll
        for (int mt = 0; mt < 4; mt++) {
            int row = row0 + rw + mt * 16 + lm;
            if (row < M) {
                #pragma unroll
                for (int nt = 0; nt < 2; nt++) {
                    int colb = n0 + cw + nt * 16 + rg;
                    float v0 = acc[mt][nt][0] + bsv[nt].x;
                    float v1 = acc[mt][nt][1] + bsv[nt].y;
                    float v2 = acc[mt][nt][2] + bsv[nt].z;
                    float v3 = acc[mt][nt][3] + bsv[nt].w;
                    if (DORES) {
                        v0 = aval * v0 + (1.f - aval) * rv[mt][nt].x;
                        v1 = aval * v1 + (1.f - aval) * rv[mt][nt].y;
                        v2 = aval * v2 + (1.f - aval) * rv[mt][nt].z;
                        v3 = aval * v3 + (1.f - aval) * rv[mt][nt].w;
                    }
                    *(float4*)((float*)C + (long)row * N + colb) =
                        make_float4(v0, v1, v2, v3);
                }
            }
        }
    }
}

// ---------- small utils ----------
__global__ void fill_u32(unsigned int* __restrict__ p, unsigned int v, int n) {
    int i = blockIdx.x * blockDim.x + threadIdx.x;
    if (i < n) p[i] = v;
}
__global__ void copy_u32(const int* __restrict__ a, int* __restrict__ b, int n) {
    int i = blockIdx.x * blockDim.x + threadIdx.x;
    if (i < n) b[i] = a[i];
}

// ---------- CSR build ----------
__global__ void count_edges(const int* __restrict__ dst, int E, int* __restrict__ counts) {
    int i = blockIdx.x * blockDim.x + threadIdx.x;
    if (i < E) atomicAdd(&counts[dst[i]], 1);
}

__global__ __launch_bounds__(256) void scan_local(const int* __restrict__ counts,
                                                  int* __restrict__ rowptr,
                                                  int* __restrict__ bsums, int n) {
    __shared__ int sh[256];
    int t = threadIdx.x;
    int base = blockIdx.x * 1024;
    int lv[4]; int s = 0;
    #pragma unroll
    for (int q = 0; q < 4; q++) {
        int i = base + t * 4 + q;
        lv[q] = (i < n) ? counts[i] : 0;
        s += lv[q];
    }
    sh[t] = s;
    __syncthreads();
    #pragma unroll
    for (int off = 1; off < 256; off <<= 1) {
        int add = (t >= off) ? sh[t - off] : 0;
        __syncthreads();
        sh[t] += add;
        __syncthreads();
    }
    int excl = sh[t] - s;
    if (t == 255) bsums[blockIdx.x] = sh[255];
    #pragma unroll
    for (int q = 0; q < 4; q++) {
        int i = base + t * 4 + q;
        if (i < n) rowptr[i] = excl;
        excl += lv[q];
    }
}
__global__ __launch_bounds__(256) void scan_bsums(int* __restrict__ bsums, int nb) {
    __shared__ int sh[256];
    int t = threadIdx.x;
    int v = (t < nb) ? bsums[t] : 0;
    sh[t] = v;
    __syncthreads();
    #pragma unroll
    for (int off = 1; off < 256; off <<= 1) {
        int add = (t >= off) ? sh[t - off] : 0;
        __syncthreads();
        sh[t] += add;
        __syncthreads();
    }
    if (t < nb) bsums[t] = sh[t] - v;
    if (t == nb - 1) bsums[nb] = sh[t];
}
__global__ void scan_add(int* __restrict__ rowptr, const int* __restrict__ bsums,
                         int n, int nb) {
    int i = blockIdx.x * blockDim.x + threadIdx.x;
    if (i < n) rowptr[i] += bsums[i >> 10];
    if (i == 0) rowptr[n] = bsums[nb];
}

// rec = (kslot, dst): kslot = slotbase + src*ncols + kcol (FOUT-unit slots; v = kslot+1)
__global__ void scatter_edges(const int* __restrict__ src, const int* __restrict__ dst, int E,
                              int* __restrict__ cursor, int2* __restrict__ recs,
                              int slotbase, int ncols, int kcol) {
    int i = blockIdx.x * blockDim.x + threadIdx.x;
    if (i >= E) return;
    int pos = atomicAdd(&cursor[dst[i]], 1);
    recs[pos] = make_int2(slotbase + src[i] * ncols + kcol, dst[i]);
}

// ---------- scores in CSR-slot order: sc[(slot-base)*H + h] ----------
template <int H>
__global__ void edge_score_csr(const __hip_bfloat16* __restrict__ kqvB,
                               long qbase, int qncols,
                               const int2* __restrict__ recs, const int* __restrict__ rowptr,
                               int tb, long nwork, float* __restrict__ sc_out) {
    long tid = blockIdx.x * (long)blockDim.x + threadIdx.x;
    if (tid >= nwork) return;
    constexpr int FOUT = H * 16;
    int sl = (int)(tid / H);
    int h = (int)(tid - (long)sl * H);
    int base = rowptr[tb];
    int2 rec = recs[base + sl];
    float kv[16], qv[16];
    load16bf(kqvB + (long)rec.x * FOUT + h * 16, kv);
    load16bf(kqvB + (qbase + (long)rec.y * qncols) * FOUT + h * 16, qv);
    float acc = 0.f;
    #pragma unroll
    for (int i = 0; i < 16; i++) acc = fmaf(kv[i], qv[i], acc);
    sc_out[tid] = acc;
}

// ---------- segment softmax stats: sequential CSR-ordered score reads ----------
template <int H>
__global__ __launch_bounds__(256)
void edge_alpha_csr(const int* __restrict__ rowptr, int tb, int ndst,
                    const float* __restrict__ sc, float2* __restrict__ ml) {
    constexpr int PER = 256 / H;
    int slot = threadIdx.x / H;
    int h = threadIdx.x - slot * H;
    int d = blockIdx.x * PER + slot;
    if (d >= ndst) return;
    int base = rowptr[tb];
    int r0 = rowptr[tb + d], r1 = rowptr[tb + d + 1];
    const float* scp = sc + (long)(r0 - base) * H + h;
    float m = -1e30f, l = 0.f;
    for (int n = r1 - r0; n > 0; --n, scp += H) {
        float s = *scp;
        float mn = fmaxf(m, s);
        float r = __expf(m - mn);
        float w = __expf(s - mn);
        l = fmaf(l, r, w);
        m = mn;
    }
    float inv = (l > 0.f) ? 1.f / l : 0.f;
    ml[(long)d * H + h] = make_float2(m, inv);
}

// ---------- gather: 4 channels/thread, v rows read from kqvB slot rec.x+1 ----------
template <int FOUT, int H>
__global__ void gather_agg_csr(const __hip_bfloat16* __restrict__ kqvB,
                               const int2* __restrict__ recs, const int* __restrict__ rowptr,
                               int tb, int ndst,
                               const float* __restrict__ sc,
                               const float2* __restrict__ ml,
                               __hip_bfloat16* __restrict__ agg) {
    constexpr int TPD = FOUT / 4;
    constexpr int PER = 256 / TPD;
    int slot = threadIdx.x / TPD;
    int jj = threadIdx.x - slot * TPD;
    int j4 = jj * 4;
    int d = blockIdx.x * PER + slot;
    if (d >= ndst) return;
    int h = j4 >> 4;
    float2 mh = ml[(long)d * H + h];
    int base = rowptr[tb];
    int r0 = rowptr[tb + d], r1 = rowptr[tb + d + 1];
    const float* scp = sc + (long)(r0 - base) * H + h;
    const int2* rp = recs + r0;
    int n = r1 - r0;
    float a0[4] = {0.f, 0.f, 0.f, 0.f}, a1[4] = {0.f, 0.f, 0.f, 0.f};
    int i = 0;
    for (; i + 1 < n; i += 2) {
        int2 ra = rp[i], rb = rp[i + 1];
        float s0 = scp[(long)i * H], s1 = scp[(long)(i + 1) * H];
        float w0 = __expf(s0 - mh.x) * mh.y;
        float w1 = __expf(s1 - mh.x) * mh.y;
        uint2 va = *(const uint2*)(kqvB + ((long)ra.x + 1) * FOUT + j4);
        uint2 vb = *(const uint2*)(kqvB + ((long)rb.x + 1) * FOUT + j4);
        a0[0] = fmaf(w0, bflo(va.x), a0[0]);
        a0[1] = fmaf(w0, bfhi(va.x), a0[1]);
        a0[2] = fmaf(w0, bflo(va.y), a0[2]);
        a0[3] = fmaf(w0, bfhi(va.y), a0[3]);
        a1[0] = fmaf(w1, bflo(vb.x), a1[0]);
        a1[1] = fmaf(w1, bfhi(vb.x), a1[1]);
        a1[2] = fmaf(w1, bflo(vb.y), a1[2]);
        a1[3] = fmaf(w1, bfhi(vb.y), a1[3]);
    }
    if (i < n) {
        int2 ra = rp[i];
        float w0 = __expf(scp[(long)i * H] - mh.x) * mh.y;
        uint2 va = *(const uint2*)(kqvB + ((long)ra.x + 1) * FOUT + j4);
        a0[0] = fmaf(w0, bflo(va.x), a0[0]);
        a0[1] = fmaf(w0, bfhi(va.x), a0[1]);
        a0[2] = fmaf(w0, bflo(va.y), a0[2]);
        a0[3] = fmaf(w0, bfhi(va.y), a0[3]);
    }
    short4v o;
    o.x = f2bf(gelu1(a0[0] + a1[0]));
    o.y = f2bf(gelu1(a0[1] + a1[1]));
    o.z = f2bf(gelu1(a0[2] + a1[2]));
    o.w = f2bf(gelu1(a0[3] + a1[3]));
    *(short4v*)((short*)agg + (long)d * FOUT + j4) = o;
}

// ---------- orchestration ----------
static const int ET_src[5]  = {1, 0, 0, 1, 2};
static const int ET_dst[5]  = {0, 0, 1, 2, 1};
static const int ET_E[5]    = {250000, 250000, 200000, 100000, 100000};
static const int KCOL[5]    = {1, 1, 3, 3, 1};  // k-slot col within source row
static const long SLOTB[3]  = {0, 500000, 750000};
static const int NCOLS[3]   = {5, 5, 3};
static const int NT[3]      = {100000, 50000, 5000};
static const long NPRE[3]   = {0, 100000, 150000};
static const int TB[3]      = {0, 100000, 150000};
static const int SL[3]      = {500000, 300000, 100000};
static const int NTOT       = 155000;

template <typename TO, int H>
static void hgt_layer_run(hipStream_t stream,
                          const float* xs, __hip_bfloat16* kqvB, float* scB,
                          const int* rowptr, const int2* recs, __hip_bfloat16* aggB,
                          float2* ml, __hip_bfloat16* wtP, float* biasB,
                          const float* kqv_w, const float* kqv_b,
                          const float* krel, const float* vrel, const float* prel,
                          const __hip_bfloat16* wt_out, const float* out_b,
                          const float* skip_arr,
                          TO* const* outs) {
    constexpr int FOUT = H * 16;
    constexpr bool DOSKIP = (H == 8);   // L1 only: fout == hidden
    compose_kqv<H><<<(13 * FOUT * 128 + 255) / 256, 256, 0, stream>>>(
        kqv_w, kqv_b, krel, vrel, prel, wtP, biasB);
    gemm_kqv_fused<FOUT><<<1213, 256, 0, stream>>>(xs, wtP, biasB, kqvB);
    for (int t = 0; t < 3; t++) {
        long nwork = (long)SL[t] * H;
        edge_score_csr<H><<<(int)((nwork + 255) / 256), 256, 0, stream>>>(
            kqvB, SLOTB[t], NCOLS[t], recs, rowptr, TB[t], nwork, scB);
        constexpr int PERA = 256 / H;
        edge_alpha_csr<H><<<(NT[t] + PERA - 1) / PERA, 256, 0, stream>>>(
            rowptr, TB[t], NT[t], scB, ml);
        constexpr int PERG = 256 / (FOUT / 4);
        gather_agg_csr<FOUT, H><<<(NT[t] + PERG - 1) / PERG, 256, 0, stream>>>(
            kqvB, recs, rowptr, TB[t], NT[t], scB, ml, aggB);
        int gb2 = (NT[t] + 127) / 128;
        gemm_out<__hip_bfloat16, TO, FOUT, DOSKIP><<<gb2, 256, 0, stream>>>(
            aggB, wt_out + (long)t * FOUT * FOUT, out_b + t * FOUT, outs[t],
            NT[t], FOUT, DOSKIP ? outs[t] : (TO*)nullptr, skip_arr, t);
    }
}

extern "C" void kernel_launch(void* const* d_in, const int* in_sizes, int n_in,
                              void* d_out, int out_size, void* d_ws, size_t ws_size,
                              hipStream_t stream) {
    const float* x_paper  = (const float*)d_in[0];
    const float* x_author = (const float*)d_in[1];
    const float* x_inst   = (const float*)d_in[2];
    const int* ei[5];
    for (int e = 0; e < 5; e++) ei[e] = (const int*)d_in[3 + e];
    const float* lin_w[3] = {(const float*)d_in[8], (const float*)d_in[10], (const float*)d_in[12]};
    const float* lin_b[3] = {(const float*)d_in[9], (const float*)d_in[11], (const float*)d_in[13]};
    const float* kqv_w1 = (const float*)d_in[14];
    const float* kqv_b1 = (const float*)d_in[15];
    const float* krel1  = (const float*)d_in[16];
    const float* vrel1  = (const float*)d_in[17];
    const float* prel1  = (const float*)d_in[18];
    const float* out_w1 = (const float*)d_in[19];
    const float* out_b1 = (const float*)d_in[20];
    const float* skip1  = (const float*)d_in[21];
    const float* kqv_w2 = (const float*)d_in[22];
    const float* kqv_b2 = (const float*)d_in[23];
    const float* krel2  = (const float*)d_in[24];
    const float* vrel2  = (const float*)d_in[25];
    const float* prel2  = (const float*)d_in[26];
    const float* out_w2 = (const float*)d_in[27];
    const float* out_b2 = (const float*)d_in[28];
    const float* skip2  = (const float*)d_in[29];

    // workspace carve (16B-aligned); total ~332.4 MB
    char* p = (char*)d_ws;
    float* xs = (float*)p;                      p += 19840000L * 4;    // 79.36 MB
    __hip_bfloat16* kqvB = (__hip_bfloat16*)p;  p += 97920000L * 2;    // 195.84 MB (765K slots x 128)
    float* scB = (float*)p;                     p += 4000000L * 4;     // 16 MB
    __hip_bfloat16* aggB = (__hip_bfloat16*)p;  p += 12800000L * 2;    // 25.6 MB
    float2* ml = (float2*)p;                    p += 800000L * 8;      // 6.4 MB
    int* rowptr = (int*)p;                      p += 155008L * 4;
    int* cursor = (int*)p;                      p += 155008L * 4;
    int2* recs = (int2*)p;                      p += 900000L * 8;
    float* biasB = (float*)p;                   p += 2048L * 4;
    __hip_bfloat16* wtA = (__hip_bfloat16*)p;

    __hip_bfloat16* wt_lin[3] = {wtA, wtA + 32768, wtA + 49152};
    __hip_bfloat16* wt_out1 = wtA + 57344;
    __hip_bfloat16* wt_out2 = wtA + 106496;
    __hip_bfloat16* wtP = wtA + 118784;   // composed kqv' (max 13*128*128 = 212992)

    dim3 pb(32, 8);
    pack_wt<<<dim3(4, 8, 1), pb, 0, stream>>>(lin_w[0], wt_lin[0], 256, 128);
    pack_wt<<<dim3(4, 4, 1), pb, 0, stream>>>(lin_w[1], wt_lin[1], 128, 128);
    pack_wt<<<dim3(4, 2, 1), pb, 0, stream>>>(lin_w[2], wt_lin[2], 64, 128);
    pack_wt<<<dim3(4, 4, 3), pb, 0, stream>>>(out_w1, wt_out1, 128, 128);
    pack_wt<<<dim3(2, 2, 3), pb, 0, stream>>>(out_w2, wt_out2, 64, 64);

    // input projections (ReLU). N=128. paper: dedicated K=256 BN=128 kernel.
    gemm_mfma_k256<<<782, 256, 0, stream>>>(x_paper, wt_lin[0], lin_b[0], xs, 100000);
    gemm_nl<float, 128, 128><<<391, 256, 0, stream>>>(
        x_author, wt_lin[1], lin_b[1], xs + 100000L * 128, 50000, 128, 1);
    gemm_nl<float, 64, 128><<<40, 256, 0, stream>>>(
        x_inst, wt_lin[2], lin_b[2], xs + 150000L * 128, 5000, 128, 1);

    // CSR build (shared by both layers)
    fill_u32<<<(NTOT + 255) / 256, 256, 0, stream>>>((unsigned int*)cursor, 0u, NTOT);
    for (int e = 0; e < 5; e++)
        count_edges<<<(ET_E[e] + 255) / 256, 256, 0, stream>>>(
            ei[e] + ET_E[e], ET_E[e], cursor + TB[ET_dst[e]]);
    {
        int* bsums = (int*)scB;  // scB dead during CSR build
        int nb = (NTOT + 1023) / 1024;  // 152
        scan_local<<<nb, 256, 0, stream>>>(cursor, rowptr, bsums, NTOT);
        scan_bsums<<<1, 256, 0, stream>>>(bsums, nb);
        scan_add<<<(NTOT + 255) / 256, 256, 0, stream>>>(rowptr, bsums, NTOT, nb);
    }
    copy_u32<<<(NTOT + 255) / 256, 256, 0, stream>>>(rowptr, cursor, NTOT);
    for (int e = 0; e < 5; e++) {
        int ts = ET_src[e];
        scatter_edges<<<(ET_E[e] + 255) / 256, 256, 0, stream>>>(
            ei[e], ei[e] + ET_E[e], ET_E[e], cursor + TB[ET_dst[e]], recs,
            (int)SLOTB[ts], NCOLS[ts], KCOL[e]);
    }

    // layer 1 (output in-place over xs; gated skip fused into out-GEMM)
    float* outs1[3] = {xs, xs + 100000L * 128, xs + 150000L * 128};
    hgt_layer_run<float, 8>(stream, xs, kqvB, scB, rowptr, recs, aggB, ml, wtP, biasB,
                            kqv_w1, kqv_b1, krel1, vrel1, prel1, wt_out1, out_b1, skip1,
                            outs1);

    float* out = (float*)d_out;
    float* outs2[3] = {out, out + 100000L * 64, out + 150000L * 64};
    hgt_layer_run<float, 4>(stream, xs, kqvB, scB, rowptr, recs, aggB, ml, wtP, biasB,
                            kqv_w2, kqv_b2, krel2, vrel2, prel2, wt_out2, out_b2, skip2,
                            outs2);
}